// Round 2
// baseline (5884.537 us; speedup 1.0000x reference)
//
#include <hip/hip_runtime.h>
#include <hip/hip_bf16.h>

#define NC 100000
#define NP 200000
#define NE 1000000

typedef unsigned short u16;
typedef unsigned int u32;

__device__ __forceinline__ float bf2f(u16 v) {
    union { u32 u; float f; } c; c.u = ((u32)v) << 16; return c.f;
}
__device__ __forceinline__ u16 f2bf(float f) {
    union { float f; u32 u; } c; c.f = f;
    u32 u = c.u;
    return (u16)((u + 0x7FFFu + ((u >> 16) & 1u)) >> 16); // RNE
}

// ---------------- projection + fused per-head logits ----------------
// h[N,128] = x[N,64] @ W[64,128] + b (stored bf16); l_j[n,h] = sum_d h*a_j
__global__ __launch_bounds__(256) void proj_kernel(
    const float* __restrict__ x, const float* __restrict__ W, const float* __restrict__ b,
    const float* __restrict__ a0, const float* __restrict__ a1, const float* __restrict__ a2,
    u16* __restrict__ h, float* __restrict__ l0, float* __restrict__ l1, float* __restrict__ l2)
{
    __shared__ float sW[64][128];   // 32 KB
    __shared__ float sx[16][64];    // 4 KB
    int t = threadIdx.x;
    for (int i = t; i < 64 * 128; i += 256) sW[i >> 7][i & 127] = W[i];
    size_t row0 = (size_t)blockIdx.x * 16;
    for (int i = t; i < 16 * 64; i += 256) {
        int r = i >> 6, c = i & 63;
        sx[r][c] = x[(row0 + r) * 64 + c];
    }
    __syncthreads();
    int col = t & 127;
    int rr = t >> 7;
    int head = col >> 4;
    float bias = b[col];
    float av0 = a0[col];
    float av1 = a1 ? a1[col] : 0.f;
    float av2 = a2 ? a2[col] : 0.f;
    for (int r = rr; r < 16; r += 2) {
        float acc = bias;
#pragma unroll
        for (int k = 0; k < 64; ++k) acc = fmaf(sx[r][k], sW[k][col], acc);
        size_t gr = row0 + r;
        h[gr * 128 + col] = f2bf(acc);
        float p0 = acc * av0, p1 = acc * av1, p2 = acc * av2;
#pragma unroll
        for (int off = 8; off >= 1; off >>= 1) {
            p0 += __shfl_xor(p0, off, 64);
            p1 += __shfl_xor(p1, off, 64);
            p2 += __shfl_xor(p2, off, 64);
        }
        if ((col & 15) == 0) {
            l0[gr * 8 + head] = p0;
            if (l1) l1[gr * 8 + head] = p1;
            if (l2) l2[gr * 8 + head] = p2;
        }
    }
}

// ---------------- edge pass 1: softmax denominators ----------------
__global__ __launch_bounds__(256) void edge_pass1(
    const int* __restrict__ esrc, const int* __restrict__ edst,
    const float* __restrict__ als, const float* __restrict__ ald,
    float* __restrict__ s)
{
    int e = blockIdx.x * 256 + threadIdx.x;
    if (e >= NE) return;
    int src = esrc[e], dst = edst[e];
    const float4* ps = (const float4*)(als + (size_t)src * 8);
    const float4* pd = (const float4*)(ald + (size_t)dst * 8);
    float4 s0 = ps[0], s1 = ps[1], d0 = pd[0], d1 = pd[1];
    float al[8] = {s0.x + d0.x, s0.y + d0.y, s0.z + d0.z, s0.w + d0.w,
                   s1.x + d1.x, s1.y + d1.y, s1.z + d1.z, s1.w + d1.w};
    float* sp = s + (size_t)dst * 8;
#pragma unroll
    for (int hh = 0; hh < 8; ++hh) {
        float a = al[hh];
        a = a >= 0.f ? a : 0.2f * a;
        atomicAdd(sp + hh, __expf(a));
    }
}

// ---------------- edge pass 2: weighted message scatter (bf16 h) ----------------
__global__ __launch_bounds__(256) void edge_pass2(
    const int* __restrict__ esrc, const int* __restrict__ edst,
    const float* __restrict__ als, const float* __restrict__ ald,
    const float* __restrict__ s, const u16* __restrict__ hs,
    float* __restrict__ out)
{
    long long gid = (long long)blockIdx.x * 256 + threadIdx.x;
    int e = (int)(gid >> 5);
    if (e >= NE) return;
    int lane = (int)(gid & 31);
    int src = esrc[e], dst = edst[e];
    int head = lane >> 2;
    float a = als[(size_t)src * 8 + head] + ald[(size_t)dst * 8 + head];
    a = a >= 0.f ? a : 0.2f * a;
    float alpha = __expf(a) / (s[(size_t)dst * 8 + head] + 1e-16f);
    ushort4 u = *(const ushort4*)(hs + (size_t)src * 128 + lane * 4);
    float* op = out + (size_t)dst * 128 + lane * 4;
    atomicAdd(op + 0, bf2f(u.x) * alpha);
    atomicAdd(op + 1, bf2f(u.y) * alpha);
    atomicAdd(op + 2, bf2f(u.z) * alpha);
    atomicAdd(op + 3, bf2f(u.w) * alpha);
}

// ---------------- convert relu(outF) -> bf16, and zero outF ----------------
__global__ __launch_bounds__(256) void conv_relu_zero(
    float* __restrict__ outF, u16* __restrict__ r)
{
    size_t i = ((size_t)blockIdx.x * 256 + threadIdx.x) * 4;
    float4 v = *(const float4*)(outF + i);
    ushort4 o;
    o.x = f2bf(fmaxf(v.x, 0.f));
    o.y = f2bf(fmaxf(v.y, 0.f));
    o.z = f2bf(fmaxf(v.z, 0.f));
    o.w = f2bf(fmaxf(v.w, 0.f));
    *(ushort4*)(r + i) = o;
    *(float4*)(outF + i) = make_float4(0.f, 0.f, 0.f, 0.f);
}

// ---------------- semantic attention ksum[m][c] = sum_n tanh(out_m @ Wk + bk) ----------------
// blockIdx.y==0: cp from f32 outF (relu applied); ==1: pp from bf16 rpp (already relu'd)
__global__ __launch_bounds__(256) void sem_kernel(
    const float* __restrict__ outF, const u16* __restrict__ rpp,
    const float* __restrict__ Wk, const float* __restrict__ bk,
    float* __restrict__ ksum)
{
    __shared__ float sW[64][128];   // 32 KB
    __shared__ float tile[16][64];  // 4 KB
    __shared__ float red[128];
    int t = threadIdx.x;
    size_t row0 = (size_t)blockIdx.x * 16;
    int col = t & 127, rr = t >> 7;
    float bias = bk[col];
    float acc[8];
#pragma unroll
    for (int i = 0; i < 8; ++i) acc[i] = bias;
    for (int half = 0; half < 2; ++half) {
        for (int i = t; i < 64 * 128; i += 256)
            sW[i >> 7][i & 127] = Wk[(half * 64 + (i >> 7)) * 128 + (i & 127)];
        for (int i = t; i < 16 * 64; i += 256) {
            int r = i >> 6, c = i & 63;
            size_t idx = (row0 + r) * 128 + half * 64 + c;
            float v;
            if (blockIdx.y) v = bf2f(rpp[idx]);
            else { v = outF[idx]; v = v > 0.f ? v : 0.f; }
            tile[r][c] = v;
        }
        __syncthreads();
#pragma unroll
        for (int ri = 0; ri < 8; ++ri) {
            int r = rr + ri * 2;
            float a = acc[ri];
#pragma unroll
            for (int k = 0; k < 64; ++k) a = fmaf(tile[r][k], sW[k][col], a);
            acc[ri] = a;
        }
        __syncthreads();
    }
    float lsum = 0.f;
#pragma unroll
    for (int ri = 0; ri < 8; ++ri) lsum += tanhf(acc[ri]);
    if (rr == 1) red[col] = lsum;
    __syncthreads();
    if (rr == 0) atomicAdd(&ksum[blockIdx.y * 128 + col], lsum + red[col]);
}

// ---------------- semantic softmax (2 metapaths) ----------------
__global__ void attn_kernel(const float* __restrict__ ksum, const float* __restrict__ q,
                            float* __restrict__ attn)
{
    int t = threadIdx.x; // 64 threads
    float inv = 1.f / (float)NP;
    float v0 = (ksum[t] * inv) * q[t] + (ksum[64 + t] * inv) * q[64 + t];
    float v1 = (ksum[128 + t] * inv) * q[t] + (ksum[192 + t] * inv) * q[64 + t];
#pragma unroll
    for (int off = 32; off >= 1; off >>= 1) {
        v0 += __shfl_xor(v0, off, 64);
        v1 += __shfl_xor(v1, off, 64);
    }
    if (t == 0) {
        float mx = fmaxf(v0, v1);
        float e0 = __expf(v0 - mx), e1 = __expf(v1 - mx);
        float is = 1.f / (e0 + e1);
        attn[0] = e0 * is;
        attn[1] = e1 * is;
    }
}

// ---------------- MLP1: z1 = (a0*relu(out_cp) + a1*r_pp) @ W1 + b1 (+ col stats) ----------------
__global__ __launch_bounds__(256) void mlp1_kernel(
    const float* __restrict__ outF, const u16* __restrict__ rpp, const float* __restrict__ attn,
    const float* __restrict__ W1, const float* __restrict__ b1,
    u16* __restrict__ z1, float* __restrict__ sum1, float* __restrict__ sq1)
{
    __shared__ float sW[64][128];
    __shared__ float tile[16][64];
    __shared__ float rs[128], rq[128];
    int t = threadIdx.x;
    float a0 = attn[0], a1 = attn[1];
    size_t row0 = (size_t)blockIdx.x * 16;
    int col = t & 127, rr = t >> 7;
    float bias = b1[col];
    float acc[8];
#pragma unroll
    for (int i = 0; i < 8; ++i) acc[i] = bias;
    for (int half = 0; half < 2; ++half) {
        for (int i = t; i < 64 * 128; i += 256)
            sW[i >> 7][i & 127] = W1[(half * 64 + (i >> 7)) * 128 + (i & 127)];
        for (int i = t; i < 16 * 64; i += 256) {
            int r = i >> 6, c = i & 63;
            size_t idx = (row0 + r) * 128 + half * 64 + c;
            float vc = outF[idx]; vc = vc > 0.f ? vc : 0.f;
            float vp = bf2f(rpp[idx]);
            tile[r][c] = a0 * vc + a1 * vp;
        }
        __syncthreads();
#pragma unroll
        for (int ri = 0; ri < 8; ++ri) {
            int r = rr + ri * 2;
            float a = acc[ri];
#pragma unroll
            for (int k = 0; k < 64; ++k) a = fmaf(tile[r][k], sW[k][col], a);
            acc[ri] = a;
        }
        __syncthreads();
    }
    float ls = 0.f, lq = 0.f;
#pragma unroll
    for (int ri = 0; ri < 8; ++ri) {
        int r = rr + ri * 2;
        float a = acc[ri];
        z1[(row0 + r) * 128 + col] = f2bf(a);
        ls += a; lq += a * a;
    }
    if (rr == 1) { rs[col] = ls; rq[col] = lq; }
    __syncthreads();
    if (rr == 0) {
        atomicAdd(&sum1[col], ls + rs[col]);
        atomicAdd(&sq1[col], lq + rq[col]);
    }
}

// ---------------- BN finalize ----------------
__global__ void bn_fin(const float* __restrict__ sum, const float* __restrict__ sq,
                       const float* __restrict__ g, const float* __restrict__ be,
                       float* __restrict__ scale, float* __restrict__ shift, int C, float invN)
{
    int c = threadIdx.x;
    if (c >= C) return;
    float mu = sum[c] * invN;
    float var = sq[c] * invN - mu * mu;
    float sc = g[c] * rsqrtf(var + 1e-5f);
    scale[c] = sc;
    shift[c] = be[c] - mu * sc;
}

// ---------------- MLP2: z2 = relu(bn(z1)) @ W2 + b2 (+ col stats) ----------------
__global__ __launch_bounds__(256) void mlp2_kernel(
    const u16* __restrict__ z1, const float* __restrict__ scale1, const float* __restrict__ shift1,
    const float* __restrict__ W2, const float* __restrict__ b2,
    float* __restrict__ z2, float* __restrict__ sum2, float* __restrict__ sq2)
{
    __shared__ float sW[128][64];   // 32 KB
    __shared__ float tile[16][128]; // 8 KB
    __shared__ float rs[4][64], rq[4][64];
    int t = threadIdx.x;
    for (int i = t; i < 128 * 64; i += 256) sW[i >> 6][i & 63] = W2[i];
    size_t row0 = (size_t)blockIdx.x * 16;
    for (int i = t; i < 16 * 128; i += 256) {
        int r = i >> 7, c = i & 127;
        float v = bf2f(z1[(row0 + r) * 128 + c]) * scale1[c] + shift1[c];
        tile[r][c] = v > 0.f ? v : 0.f;
    }
    __syncthreads();
    int col = t & 63, rr = t >> 6;
    float bias = b2[col];
    float ls = 0.f, lq = 0.f;
    for (int r = rr; r < 16; r += 4) {
        float acc = bias;
#pragma unroll 16
        for (int k = 0; k < 128; ++k) acc = fmaf(tile[r][k], sW[k][col], acc);
        z2[(row0 + r) * 64 + col] = acc;
        ls += acc; lq += acc * acc;
    }
    rs[rr][col] = ls; rq[rr][col] = lq;
    __syncthreads();
    if (rr == 0) {
        atomicAdd(&sum2[col], rs[0][col] + rs[1][col] + rs[2][col] + rs[3][col]);
        atomicAdd(&sq2[col], rq[0][col] + rq[1][col] + rq[2][col] + rq[3][col]);
    }
}

// ---------------- final: sigmoid(relu(bn(z2)) @ W3 + b3) ----------------
__global__ __launch_bounds__(64) void final_kernel(
    const float* __restrict__ z2, const float* __restrict__ scale2, const float* __restrict__ shift2,
    const float* __restrict__ W3, const float* __restrict__ b3, float* __restrict__ out)
{
    __shared__ float sh[64][65];
    __shared__ float sw[64];
    int t = threadIdx.x; // 64
    size_t row0 = (size_t)blockIdx.x * 64;
    sw[t] = W3[t];
    for (int j = 0; j < 64; ++j) {
        float v = z2[(row0 + j) * 64 + t] * scale2[t] + shift2[t];
        sh[j][t] = v > 0.f ? v : 0.f;
    }
    __syncthreads();
    float acc = b3[0];
#pragma unroll 16
    for (int k = 0; k < 64; ++k) acc = fmaf(sh[t][k], sw[k], acc);
    out[row0 + t] = 1.f / (1.f + __expf(-acc));
}

extern "C" void kernel_launch(void* const* d_in, const int* in_sizes, int n_in,
                              void* d_out, int out_size, void* d_ws, size_t ws_size,
                              hipStream_t stream) {
    const float* x_c      = (const float*)d_in[0];
    const float* x_p      = (const float*)d_in[1];
    const int*   e_src_cp = (const int*)d_in[2];
    const int*   e_dst_cp = (const int*)d_in[3];
    const int*   e_src_pp = (const int*)d_in[4];
    const int*   e_dst_pp = (const int*)d_in[5];
    const float* W_c      = (const float*)d_in[6];
    const float* b_c      = (const float*)d_in[7];
    const float* W_p      = (const float*)d_in[8];
    const float* b_p      = (const float*)d_in[9];
    const float* a_src_cp = (const float*)d_in[10];
    const float* a_dst_cp = (const float*)d_in[11];
    const float* a_src_pp = (const float*)d_in[12];
    const float* a_dst_pp = (const float*)d_in[13];
    const float* Wk       = (const float*)d_in[14];
    const float* bk       = (const float*)d_in[15];
    const float* q_sem    = (const float*)d_in[16];
    const float* W1       = (const float*)d_in[17];
    const float* b1       = (const float*)d_in[18];
    const float* g1       = (const float*)d_in[19];
    const float* be1      = (const float*)d_in[20];
    const float* W2       = (const float*)d_in[21];
    const float* b2       = (const float*)d_in[22];
    const float* g2       = (const float*)d_in[23];
    const float* be2      = (const float*)d_in[24];
    const float* W3       = (const float*)d_in[25];
    const float* b3       = (const float*)d_in[26];

    // ---- byte-offset workspace layout (total extent 214,408,192 B) ----
    char* ws = (char*)d_ws;
    u16*   h_p    = (u16*)  (ws +          0); // NP*128 bf16 = 51,200,000 B
    u16*   h_c    = (u16*)  (ws +  51200000); // NC*128 bf16 = 25,600,000 B
    float* al_c   = (float*)(ws +  76800000); // NC*8 f32
    float* al_dcp = (float*)(ws +  80000000); // NP*8 f32
    float* al_spp = (float*)(ws +  86400000);
    float* al_dpp = (float*)(ws +  92800000);
    float* s_pp   = (float*)(ws +  99200000); // NP*8 f32 (zeroed)
    float* s_cp   = (float*)(ws + 105600000); // NP*8 f32 (zeroed)
    float* small  = (float*)(ws + 112000000); // 2048 f32 (zeroed)
    float* outF   = (float*)(ws + 112008192); // NP*128 f32 accumulator (zeroed)

    float* ksum   = small;        // 256
    float* attn   = small + 256;  // 2
    float* sum1   = small + 384;  // 128
    float* sq1    = small + 512;  // 128
    float* sum2   = small + 640;  // 64
    float* sq2    = small + 704;  // 64
    float* scale1 = small + 768;  // 128
    float* shift1 = small + 896;  // 128
    float* scale2 = small + 1024; // 64
    float* shift2 = small + 1088; // 64

    // aliases over dead regions
    u16*   r_pp = h_p;            // relu(out_pp) bf16, after pp metapath (h_p dead)
    u16*   z1   = h_c;            // NP*128 bf16 (51.2 MB over h_c+al+s_pp, all dead by MLP1)
    float* z2   = (float*)ws;     // NP*64 f32 = h_p region (r_pp dead after MLP1)

    // one memset covers s_pp, s_cp, small, outF (contiguous)
    hipMemsetAsync(ws + 99200000, 0, 214408192 - 99200000, stream);

    // projections + fused logits
    proj_kernel<<<NC / 16, 256, 0, stream>>>(x_c, W_c, b_c, a_src_cp, nullptr, nullptr,
                                             h_c, al_c, nullptr, nullptr);
    proj_kernel<<<NP / 16, 256, 0, stream>>>(x_p, W_p, b_p, a_dst_cp, a_src_pp, a_dst_pp,
                                             h_p, al_dcp, al_spp, al_dpp);

    // ---- metapath pp (first, so h_p dies early) ----
    edge_pass1<<<(NE + 255) / 256, 256, 0, stream>>>(e_src_pp, e_dst_pp, al_spp, al_dpp, s_pp);
    edge_pass2<<<NE * 32 / 256, 256, 0, stream>>>(e_src_pp, e_dst_pp, al_spp, al_dpp, s_pp, h_p, outF);
    conv_relu_zero<<<NP * 128 / 1024, 256, 0, stream>>>(outF, r_pp);

    // ---- metapath cp (into the re-zeroed accumulator) ----
    edge_pass1<<<(NE + 255) / 256, 256, 0, stream>>>(e_src_cp, e_dst_cp, al_c, al_dcp, s_cp);
    edge_pass2<<<NE * 32 / 256, 256, 0, stream>>>(e_src_cp, e_dst_cp, al_c, al_dcp, s_cp, h_c, outF);

    // semantic attention
    {
        dim3 g(NP / 16, 2);
        sem_kernel<<<g, 256, 0, stream>>>(outF, r_pp, Wk, bk, ksum);
    }
    attn_kernel<<<1, 64, 0, stream>>>(ksum, q_sem, attn);

    // MLP + BN
    mlp1_kernel<<<NP / 16, 256, 0, stream>>>(outF, r_pp, attn, W1, b1, z1, sum1, sq1);
    bn_fin<<<1, 128, 0, stream>>>(sum1, sq1, g1, be1, scale1, shift1, 128, 1.f / (float)NP);
    mlp2_kernel<<<NP / 16, 256, 0, stream>>>(z1, scale1, shift1, W2, b2, z2, sum2, sq2);
    bn_fin<<<1, 128, 0, stream>>>(sum2, sq2, g2, be2, scale2, shift2, 64, 1.f / (float)NP);
    final_kernel<<<NP / 64, 64, 0, stream>>>(z2, scale2, shift2, W3, b3, (float*)d_out);
}

// Round 3
// 2142.528 us; speedup vs baseline: 2.7465x; 2.7465x over previous
//
#include <hip/hip_runtime.h>
#include <hip/hip_bf16.h>

#define NC 100000
#define NP 200000
#define NE 1000000
#define NB_SCAN 196  // ceil(NP/1024)

typedef unsigned short u16;
typedef unsigned int u32;

__device__ __forceinline__ float bf2f(u16 v) {
    union { u32 u; float f; } c; c.u = ((u32)v) << 16; return c.f;
}
__device__ __forceinline__ u16 f2bf(float f) {
    union { float f; u32 u; } c; c.f = f;
    u32 u = c.u;
    return (u16)((u + 0x7FFFu + ((u >> 16) & 1u)) >> 16); // RNE
}

// ---------------- projection + fused per-head logits ----------------
__global__ __launch_bounds__(256) void proj_kernel(
    const float* __restrict__ x, const float* __restrict__ W, const float* __restrict__ b,
    const float* __restrict__ a0, const float* __restrict__ a1, const float* __restrict__ a2,
    u16* __restrict__ h, float* __restrict__ l0, float* __restrict__ l1, float* __restrict__ l2)
{
    __shared__ float sW[64][128];   // 32 KB
    __shared__ float sx[16][64];    // 4 KB
    int t = threadIdx.x;
    for (int i = t; i < 64 * 128; i += 256) sW[i >> 7][i & 127] = W[i];
    size_t row0 = (size_t)blockIdx.x * 16;
    for (int i = t; i < 16 * 64; i += 256) {
        int r = i >> 6, c = i & 63;
        sx[r][c] = x[(row0 + r) * 64 + c];
    }
    __syncthreads();
    int col = t & 127;
    int rr = t >> 7;
    int head = col >> 4;
    float bias = b[col];
    float av0 = a0[col];
    float av1 = a1 ? a1[col] : 0.f;
    float av2 = a2 ? a2[col] : 0.f;
    for (int r = rr; r < 16; r += 2) {
        float acc = bias;
#pragma unroll
        for (int k = 0; k < 64; ++k) acc = fmaf(sx[r][k], sW[k][col], acc);
        size_t gr = row0 + r;
        h[gr * 128 + col] = f2bf(acc);
        float p0 = acc * av0, p1 = acc * av1, p2 = acc * av2;
#pragma unroll
        for (int off = 8; off >= 1; off >>= 1) {
            p0 += __shfl_xor(p0, off, 64);
            p1 += __shfl_xor(p1, off, 64);
            p2 += __shfl_xor(p2, off, 64);
        }
        if ((col & 15) == 0) {
            l0[gr * 8 + head] = p0;
            if (l1) l1[gr * 8 + head] = p1;
            if (l2) l2[gr * 8 + head] = p2;
        }
    }
}

// ---------------- CSR build ----------------
__global__ __launch_bounds__(256) void hist_kernel(const int* __restrict__ edst, int* __restrict__ cnt)
{
    int e = blockIdx.x * 256 + threadIdx.x;
    if (e < NE) atomicAdd(&cnt[edst[e]], 1);
}

// per-block sums of 1024 counts
__global__ __launch_bounds__(256) void scan_phaseB(const int* __restrict__ cnt, int* __restrict__ bsums)
{
    __shared__ int red[256];
    int t = threadIdx.x;
    int base = blockIdx.x * 1024 + t * 4;
    int s = 0;
#pragma unroll
    for (int j = 0; j < 4; ++j) { int i = base + j; if (i < NP) s += cnt[i]; }
    red[t] = s;
    __syncthreads();
    for (int off = 128; off >= 1; off >>= 1) {
        if (t < off) red[t] += red[t + off];
        __syncthreads();
    }
    if (t == 0) bsums[blockIdx.x] = red[0];
}

// exclusive scan of NB_SCAN block sums (single block)
__global__ __launch_bounds__(256) void scan_phaseC(int* __restrict__ bsums, int* __restrict__ row_ptr)
{
    __shared__ int sdata[256];
    int t = threadIdx.x;
    int v = (t < NB_SCAN) ? bsums[t] : 0;
    sdata[t] = v;
    __syncthreads();
    for (int off = 1; off < 256; off <<= 1) {
        int x = (t >= off) ? sdata[t - off] : 0;
        __syncthreads();
        sdata[t] += x;
        __syncthreads();
    }
    if (t < NB_SCAN) bsums[t] = sdata[t] - v; // exclusive
    if (t == 0) row_ptr[NP] = NE;
}

// write row_ptr + cursor
__global__ __launch_bounds__(256) void scan_phaseD(const int* __restrict__ cnt, const int* __restrict__ bsums,
                                                   int* __restrict__ row_ptr, int* __restrict__ cursor)
{
    __shared__ int sdata[256];
    int t = threadIdx.x;
    int base = blockIdx.x * 1024 + t * 4;
    int e[4];
    int s = 0;
#pragma unroll
    for (int j = 0; j < 4; ++j) {
        int i = base + j;
        e[j] = (i < NP) ? cnt[i] : 0;
        s += e[j];
    }
    sdata[t] = s;
    __syncthreads();
    for (int off = 1; off < 256; off <<= 1) {
        int x = (t >= off) ? sdata[t - off] : 0;
        __syncthreads();
        sdata[t] += x;
        __syncthreads();
    }
    int run = bsums[blockIdx.x] + sdata[t] - s; // exclusive prefix for this thread's chunk
#pragma unroll
    for (int j = 0; j < 4; ++j) {
        int i = base + j;
        if (i < NP) { row_ptr[i] = run; cursor[i] = run; }
        run += e[j];
    }
}

__global__ __launch_bounds__(256) void scatter_kernel(const int* __restrict__ esrc, const int* __restrict__ edst,
                                                      int* __restrict__ cursor, int* __restrict__ perm)
{
    int e = blockIdx.x * 256 + threadIdx.x;
    if (e >= NE) return;
    int pos = atomicAdd(&cursor[edst[e]], 1);
    perm[pos] = esrc[e];
}

// ---------------- gather aggregation: one wave per dst node ----------------
// sweep 1: softmax denominators for all 8 heads; sweep 2: weighted sum of h_src rows.
__global__ __launch_bounds__(256) void gather_kernel(
    const int* __restrict__ row_ptr, const int* __restrict__ perm,
    const float* __restrict__ als, const float* __restrict__ ald,
    const u16* __restrict__ hs, float* __restrict__ out)
{
    int d = blockIdx.x * 4 + (threadIdx.x >> 6);
    if (d >= NP) return;
    int lane = threadIdx.x & 63;
    int beg = row_ptr[d], end = row_ptr[d + 1];
    int myh = lane >> 3;
    float aldh[8];
#pragma unroll
    for (int h = 0; h < 8; ++h) aldh[h] = ald[(size_t)d * 8 + h];
    float dsum[8] = {0.f, 0.f, 0.f, 0.f, 0.f, 0.f, 0.f, 0.f};
    for (int e = beg + lane; e < end; e += 64) {
        int src = perm[e];
        const float* ap = als + (size_t)src * 8;
#pragma unroll
        for (int h = 0; h < 8; ++h) {
            float a = ap[h] + aldh[h];
            a = a >= 0.f ? a : 0.2f * a;
            dsum[h] += __expf(a);
        }
    }
#pragma unroll
    for (int h = 0; h < 8; ++h) {
        float v = dsum[h];
#pragma unroll
        for (int off = 32; off >= 1; off >>= 1) v += __shfl_xor(v, off, 64);
        dsum[h] = v;
    }
    float ald_my = aldh[myh];
    float inv_my = 1.f / (dsum[myh] + 1e-16f);
    float acc0 = 0.f, acc1 = 0.f;
    for (int e = beg; e < end; ++e) {
        int src = perm[e]; // same address across wave -> broadcast
        float a = als[(size_t)src * 8 + myh] + ald_my;
        a = a >= 0.f ? a : 0.2f * a;
        float w = __expf(a) * inv_my;
        u32 hv = *(const u32*)(hs + (size_t)src * 128 + lane * 2);
        acc0 = fmaf(bf2f((u16)(hv & 0xFFFFu)), w, acc0);
        acc1 = fmaf(bf2f((u16)(hv >> 16)), w, acc1);
    }
    *(float2*)(out + (size_t)d * 128 + lane * 2) = make_float2(acc0, acc1);
}

// ---------------- convert relu(outF) -> bf16 ----------------
__global__ __launch_bounds__(256) void conv_relu(
    const float* __restrict__ outF, u16* __restrict__ r)
{
    size_t i = ((size_t)blockIdx.x * 256 + threadIdx.x) * 4;
    float4 v = *(const float4*)(outF + i);
    ushort4 o;
    o.x = f2bf(fmaxf(v.x, 0.f));
    o.y = f2bf(fmaxf(v.y, 0.f));
    o.z = f2bf(fmaxf(v.z, 0.f));
    o.w = f2bf(fmaxf(v.w, 0.f));
    *(ushort4*)(r + i) = o;
}

// ---------------- semantic attention ksum[m][c] = sum_n tanh(out_m @ Wk + bk) ----------------
__global__ __launch_bounds__(256) void sem_kernel(
    const float* __restrict__ outF, const u16* __restrict__ rpp,
    const float* __restrict__ Wk, const float* __restrict__ bk,
    float* __restrict__ ksum)
{
    __shared__ float sW[64][128];
    __shared__ float tile[16][64];
    __shared__ float red[128];
    int t = threadIdx.x;
    size_t row0 = (size_t)blockIdx.x * 16;
    int col = t & 127, rr = t >> 7;
    float bias = bk[col];
    float acc[8];
#pragma unroll
    for (int i = 0; i < 8; ++i) acc[i] = bias;
    for (int half = 0; half < 2; ++half) {
        for (int i = t; i < 64 * 128; i += 256)
            sW[i >> 7][i & 127] = Wk[(half * 64 + (i >> 7)) * 128 + (i & 127)];
        for (int i = t; i < 16 * 64; i += 256) {
            int r = i >> 6, c = i & 63;
            size_t idx = (row0 + r) * 128 + half * 64 + c;
            float v;
            if (blockIdx.y) v = bf2f(rpp[idx]);
            else { v = outF[idx]; v = v > 0.f ? v : 0.f; }
            tile[r][c] = v;
        }
        __syncthreads();
#pragma unroll
        for (int ri = 0; ri < 8; ++ri) {
            int r = rr + ri * 2;
            float a = acc[ri];
#pragma unroll
            for (int k = 0; k < 64; ++k) a = fmaf(tile[r][k], sW[k][col], a);
            acc[ri] = a;
        }
        __syncthreads();
    }
    float lsum = 0.f;
#pragma unroll
    for (int ri = 0; ri < 8; ++ri) lsum += tanhf(acc[ri]);
    if (rr == 1) red[col] = lsum;
    __syncthreads();
    if (rr == 0) atomicAdd(&ksum[blockIdx.y * 128 + col], lsum + red[col]);
}

// ---------------- semantic softmax (2 metapaths) ----------------
__global__ void attn_kernel(const float* __restrict__ ksum, const float* __restrict__ q,
                            float* __restrict__ attn)
{
    int t = threadIdx.x; // 64 threads
    float inv = 1.f / (float)NP;
    float v0 = (ksum[t] * inv) * q[t] + (ksum[64 + t] * inv) * q[64 + t];
    float v1 = (ksum[128 + t] * inv) * q[t] + (ksum[192 + t] * inv) * q[64 + t];
#pragma unroll
    for (int off = 32; off >= 1; off >>= 1) {
        v0 += __shfl_xor(v0, off, 64);
        v1 += __shfl_xor(v1, off, 64);
    }
    if (t == 0) {
        float mx = fmaxf(v0, v1);
        float e0 = __expf(v0 - mx), e1 = __expf(v1 - mx);
        float is = 1.f / (e0 + e1);
        attn[0] = e0 * is;
        attn[1] = e1 * is;
    }
}

// ---------------- MLP1: z1 = (a0*relu(out_cp) + a1*r_pp) @ W1 + b1 (+ col stats) ----------------
__global__ __launch_bounds__(256) void mlp1_kernel(
    const float* __restrict__ outF, const u16* __restrict__ rpp, const float* __restrict__ attn,
    const float* __restrict__ W1, const float* __restrict__ b1,
    u16* __restrict__ z1, float* __restrict__ sum1, float* __restrict__ sq1)
{
    __shared__ float sW[64][128];
    __shared__ float tile[16][64];
    __shared__ float rs[128], rq[128];
    int t = threadIdx.x;
    float a0 = attn[0], a1 = attn[1];
    size_t row0 = (size_t)blockIdx.x * 16;
    int col = t & 127, rr = t >> 7;
    float bias = b1[col];
    float acc[8];
#pragma unroll
    for (int i = 0; i < 8; ++i) acc[i] = bias;
    for (int half = 0; half < 2; ++half) {
        for (int i = t; i < 64 * 128; i += 256)
            sW[i >> 7][i & 127] = W1[(half * 64 + (i >> 7)) * 128 + (i & 127)];
        for (int i = t; i < 16 * 64; i += 256) {
            int r = i >> 6, c = i & 63;
            size_t idx = (row0 + r) * 128 + half * 64 + c;
            float vc = outF[idx]; vc = vc > 0.f ? vc : 0.f;
            float vp = bf2f(rpp[idx]);
            tile[r][c] = a0 * vc + a1 * vp;
        }
        __syncthreads();
#pragma unroll
        for (int ri = 0; ri < 8; ++ri) {
            int r = rr + ri * 2;
            float a = acc[ri];
#pragma unroll
            for (int k = 0; k < 64; ++k) a = fmaf(tile[r][k], sW[k][col], a);
            acc[ri] = a;
        }
        __syncthreads();
    }
    float ls = 0.f, lq = 0.f;
#pragma unroll
    for (int ri = 0; ri < 8; ++ri) {
        int r = rr + ri * 2;
        float a = acc[ri];
        z1[(row0 + r) * 128 + col] = f2bf(a);
        ls += a; lq += a * a;
    }
    if (rr == 1) { rs[col] = ls; rq[col] = lq; }
    __syncthreads();
    if (rr == 0) {
        atomicAdd(&sum1[col], ls + rs[col]);
        atomicAdd(&sq1[col], lq + rq[col]);
    }
}

// ---------------- BN finalize ----------------
__global__ void bn_fin(const float* __restrict__ sum, const float* __restrict__ sq,
                       const float* __restrict__ g, const float* __restrict__ be,
                       float* __restrict__ scale, float* __restrict__ shift, int C, float invN)
{
    int c = threadIdx.x;
    if (c >= C) return;
    float mu = sum[c] * invN;
    float var = sq[c] * invN - mu * mu;
    float sc = g[c] * rsqrtf(var + 1e-5f);
    scale[c] = sc;
    shift[c] = be[c] - mu * sc;
}

// ---------------- MLP2: z2 = relu(bn(z1)) @ W2 + b2 (+ col stats) ----------------
__global__ __launch_bounds__(256) void mlp2_kernel(
    const u16* __restrict__ z1, const float* __restrict__ scale1, const float* __restrict__ shift1,
    const float* __restrict__ W2, const float* __restrict__ b2,
    float* __restrict__ z2, float* __restrict__ sum2, float* __restrict__ sq2)
{
    __shared__ float sW[128][64];
    __shared__ float tile[16][128];
    __shared__ float rs[4][64], rq[4][64];
    int t = threadIdx.x;
    for (int i = t; i < 128 * 64; i += 256) sW[i >> 6][i & 63] = W2[i];
    size_t row0 = (size_t)blockIdx.x * 16;
    for (int i = t; i < 16 * 128; i += 256) {
        int r = i >> 7, c = i & 127;
        float v = bf2f(z1[(row0 + r) * 128 + c]) * scale1[c] + shift1[c];
        tile[r][c] = v > 0.f ? v : 0.f;
    }
    __syncthreads();
    int col = t & 63, rr = t >> 6;
    float bias = b2[col];
    float ls = 0.f, lq = 0.f;
    for (int r = rr; r < 16; r += 4) {
        float acc = bias;
#pragma unroll 16
        for (int k = 0; k < 128; ++k) acc = fmaf(tile[r][k], sW[k][col], acc);
        z2[(row0 + r) * 64 + col] = acc;
        ls += acc; lq += acc * acc;
    }
    rs[rr][col] = ls; rq[rr][col] = lq;
    __syncthreads();
    if (rr == 0) {
        atomicAdd(&sum2[col], rs[0][col] + rs[1][col] + rs[2][col] + rs[3][col]);
        atomicAdd(&sq2[col], rq[0][col] + rq[1][col] + rq[2][col] + rq[3][col]);
    }
}

// ---------------- final: sigmoid(relu(bn(z2)) @ W3 + b3) ----------------
__global__ __launch_bounds__(64) void final_kernel(
    const float* __restrict__ z2, const float* __restrict__ scale2, const float* __restrict__ shift2,
    const float* __restrict__ W3, const float* __restrict__ b3, float* __restrict__ out)
{
    __shared__ float sh[64][65];
    __shared__ float sw[64];
    int t = threadIdx.x; // 64
    size_t row0 = (size_t)blockIdx.x * 64;
    sw[t] = W3[t];
    for (int j = 0; j < 64; ++j) {
        float v = z2[(row0 + j) * 64 + t] * scale2[t] + shift2[t];
        sh[j][t] = v > 0.f ? v : 0.f;
    }
    __syncthreads();
    float acc = b3[0];
#pragma unroll 16
    for (int k = 0; k < 64; ++k) acc = fmaf(sh[t][k], sw[k], acc);
    out[row0 + t] = 1.f / (1.f + __expf(-acc));
}

extern "C" void kernel_launch(void* const* d_in, const int* in_sizes, int n_in,
                              void* d_out, int out_size, void* d_ws, size_t ws_size,
                              hipStream_t stream) {
    const float* x_c      = (const float*)d_in[0];
    const float* x_p      = (const float*)d_in[1];
    const int*   e_src_cp = (const int*)d_in[2];
    const int*   e_dst_cp = (const int*)d_in[3];
    const int*   e_src_pp = (const int*)d_in[4];
    const int*   e_dst_pp = (const int*)d_in[5];
    const float* W_c      = (const float*)d_in[6];
    const float* b_c      = (const float*)d_in[7];
    const float* W_p      = (const float*)d_in[8];
    const float* b_p      = (const float*)d_in[9];
    const float* a_src_cp = (const float*)d_in[10];
    const float* a_dst_cp = (const float*)d_in[11];
    const float* a_src_pp = (const float*)d_in[12];
    const float* a_dst_pp = (const float*)d_in[13];
    const float* Wk       = (const float*)d_in[14];
    const float* bk       = (const float*)d_in[15];
    const float* q_sem    = (const float*)d_in[16];
    const float* W1       = (const float*)d_in[17];
    const float* b1       = (const float*)d_in[18];
    const float* g1       = (const float*)d_in[19];
    const float* be1      = (const float*)d_in[20];
    const float* W2       = (const float*)d_in[21];
    const float* b2       = (const float*)d_in[22];
    const float* g2       = (const float*)d_in[23];
    const float* be2      = (const float*)d_in[24];
    const float* W3       = (const float*)d_in[25];
    const float* b3       = (const float*)d_in[26];

    // ---- byte-offset workspace layout (extent 207,209,472 B; 214,408,192 proved OK) ----
    char* ws = (char*)d_ws;
    u16*   h_p    = (u16*)  (ws +          0); // 51,200,000
    u16*   h_c    = (u16*)  (ws +  51200000);  // 25,600,000
    float* al_c   = (float*)(ws +  76800000);  //  3,200,000
    float* al_dcp = (float*)(ws +  80000000);  //  6,400,000
    float* al_spp = (float*)(ws +  86400000);
    float* al_dpp = (float*)(ws +  92800000);
    int*   row_ptr= (int*)  (ws +  99200000);  // (NP+1)*4, padded to 800,256
    int*   cnt    = (int*)  (ws + 100000256);  // NP*4 (doubles as cursor)
    int*   bsums  = (int*)  (ws + 100800256);  // 1024
    int*   perm   = (int*)  (ws + 100801280);  // NE*4 = 4,000,000
    float* outF   = (float*)(ws + 104801280);  // NP*128*4 = 102,400,000
    float* small  = (float*)(ws + 207201280);  // 8192

    float* ksum   = small;        // 256
    float* attn   = small + 256;  // 2
    float* sum1   = small + 384;  // 128
    float* sq1    = small + 512;  // 128
    float* sum2   = small + 640;  // 64
    float* sq2    = small + 704;  // 64
    float* scale1 = small + 768;  // 128
    float* shift1 = small + 896;  // 128
    float* scale2 = small + 1024; // 64
    float* shift2 = small + 1088; // 64

    // aliases over dead regions (CSR buffers + h tables are dead by MLP time)
    u16*   r_pp = h_p;           // relu(out_pp) bf16 after pp metapath
    u16*   z1   = h_c;           // bf16 NP*128 spans [51.2M,102.4M): overlaps only dead CSR bufs
    float* z2   = (float*)ws;    // f32 NP*64 spans [0,51.2M): r_pp dead by MLP2

    hipMemsetAsync(small, 0, 8192, stream);

    // projections + fused logits
    proj_kernel<<<NC / 16, 256, 0, stream>>>(x_c, W_c, b_c, a_src_cp, nullptr, nullptr,
                                             h_c, al_c, nullptr, nullptr);
    proj_kernel<<<NP / 16, 256, 0, stream>>>(x_p, W_p, b_p, a_dst_cp, a_src_pp, a_dst_pp,
                                             h_p, al_dcp, al_spp, al_dpp);

    const int GE = (NE + 255) / 256;

    // ---- metapath pp (first, so h_p dies early) ----
    hipMemsetAsync(cnt, 0, NP * 4, stream);
    hist_kernel<<<GE, 256, 0, stream>>>(e_dst_pp, cnt);
    scan_phaseB<<<NB_SCAN, 256, 0, stream>>>(cnt, bsums);
    scan_phaseC<<<1, 256, 0, stream>>>(bsums, row_ptr);
    scan_phaseD<<<NB_SCAN, 256, 0, stream>>>(cnt, bsums, row_ptr, cnt); // cnt becomes cursor
    scatter_kernel<<<GE, 256, 0, stream>>>(e_src_pp, e_dst_pp, cnt, perm);
    gather_kernel<<<NP / 4, 256, 0, stream>>>(row_ptr, perm, al_spp, al_dpp, h_p, outF);
    conv_relu<<<NP * 128 / 1024, 256, 0, stream>>>(outF, r_pp);

    // ---- metapath cp ----
    hipMemsetAsync(cnt, 0, NP * 4, stream);
    hist_kernel<<<GE, 256, 0, stream>>>(e_dst_cp, cnt);
    scan_phaseB<<<NB_SCAN, 256, 0, stream>>>(cnt, bsums);
    scan_phaseC<<<1, 256, 0, stream>>>(bsums, row_ptr);
    scan_phaseD<<<NB_SCAN, 256, 0, stream>>>(cnt, bsums, row_ptr, cnt);
    scatter_kernel<<<GE, 256, 0, stream>>>(e_src_cp, e_dst_cp, cnt, perm);
    gather_kernel<<<NP / 4, 256, 0, stream>>>(row_ptr, perm, al_c, al_dcp, h_c, outF);

    // semantic attention
    {
        dim3 g(NP / 16, 2);
        sem_kernel<<<g, 256, 0, stream>>>(outF, r_pp, Wk, bk, ksum);
    }
    attn_kernel<<<1, 64, 0, stream>>>(ksum, q_sem, attn);

    // MLP + BN
    mlp1_kernel<<<NP / 16, 256, 0, stream>>>(outF, r_pp, attn, W1, b1, z1, sum1, sq1);
    bn_fin<<<1, 128, 0, stream>>>(sum1, sq1, g1, be1, scale1, shift1, 128, 1.f / (float)NP);
    mlp2_kernel<<<NP / 16, 256, 0, stream>>>(z1, scale1, shift1, W2, b2, z2, sum2, sq2);
    bn_fin<<<1, 128, 0, stream>>>(sum2, sq2, g2, be2, scale2, shift2, 64, 1.f / (float)NP);
    final_kernel<<<NP / 64, 64, 0, stream>>>(z2, scale2, shift2, W3, b3, (float*)d_out);
}

// Round 4
// 933.522 us; speedup vs baseline: 6.3036x; 2.2951x over previous
//
#include <hip/hip_runtime.h>
#include <hip/hip_bf16.h>

#define NC 100000
#define NP 200000
#define NE 1000000
#define NB_SCAN 196  // ceil(NP/1024)

typedef unsigned short u16;
typedef unsigned int u32;
typedef __attribute__((ext_vector_type(8))) short short8v;  // 8 bf16 (4 VGPRs)
typedef __attribute__((ext_vector_type(4))) float f32x4;

__device__ __forceinline__ float bf2f(u16 v) {
    union { u32 u; float f; } c; c.u = ((u32)v) << 16; return c.f;
}
__device__ __forceinline__ u16 f2bf(float f) {
    union { float f; u32 u; } c; c.f = f;
    u32 u = c.u;
    return (u16)((u + 0x7FFFu + ((u >> 16) & 1u)) >> 16); // RNE
}
__device__ __forceinline__ u32 pack2(float lo, float hi) {
    return (u32)f2bf(lo) | ((u32)f2bf(hi) << 16);
}
__device__ __forceinline__ float tanh_fast(float x) {
    return 1.f - 2.f / (__expf(2.f * x) + 1.f);
}

// ================= proj: h[N,128] = bf16(x[N,64] @ W + b) via MFMA =================
__global__ __launch_bounds__(256) void proj_mfma(
    const float* __restrict__ x, const float* __restrict__ W, const float* __restrict__ b,
    u16* __restrict__ h, int N)
{
    __shared__ alignas(16) u16 sBT[128 * 72];  // [n][k] padded K=64->72
    __shared__ alignas(16) u16 sA[64 * 72];
    int t = threadIdx.x;
    // B stage: W[64][128] f32 -> bf16 sBT[n][k]
    for (int i = t; i < 128 * 8; i += 256) {
        int n = i & 127, kb = i >> 7;   // kb: 8 blocks of 8 k
        u32 p[4];
#pragma unroll
        for (int j = 0; j < 4; ++j)
            p[j] = pack2(W[(kb * 8 + 2 * j) * 128 + n], W[(kb * 8 + 2 * j + 1) * 128 + n]);
        *(uint4*)(&sBT[n * 72 + kb * 8]) = make_uint4(p[0], p[1], p[2], p[3]);
    }
    size_t row0 = (size_t)blockIdx.x * 64;
    for (int i = t; i < 64 * 8; i += 256) {
        int r = i >> 3, c8 = (i & 7) * 8;
        u32 p[4];
        if (row0 + r < (size_t)N) {
            const float* src = x + (row0 + r) * 64 + c8;
            float4 v0 = *(const float4*)src;
            float4 v1 = *(const float4*)(src + 4);
            p[0] = pack2(v0.x, v0.y); p[1] = pack2(v0.z, v0.w);
            p[2] = pack2(v1.x, v1.y); p[3] = pack2(v1.z, v1.w);
        } else { p[0] = p[1] = p[2] = p[3] = 0; }
        *(uint4*)(&sA[r * 72 + c8]) = make_uint4(p[0], p[1], p[2], p[3]);
    }
    __syncthreads();
    int wave = t >> 6, lane = t & 63;
    int fr = lane & 15, fq = lane >> 4;
    const u16* pA = sA + (wave * 16 + fr) * 72 + fq * 8;
    const u16* pB = sBT + fr * 72 + fq * 8;
    f32x4 acc[8];
#pragma unroll
    for (int nt = 0; nt < 8; ++nt) { float bb = b[nt * 16 + fr]; acc[nt] = (f32x4){bb, bb, bb, bb}; }
#pragma unroll
    for (int ks = 0; ks < 2; ++ks) {
        short8v a = *(const short8v*)(pA + ks * 32);
#pragma unroll
        for (int nt = 0; nt < 8; ++nt) {
            short8v bv = *(const short8v*)(pB + nt * 16 * 72 + ks * 32);
            acc[nt] = __builtin_amdgcn_mfma_f32_16x16x32_bf16(a, bv, acc[nt], 0, 0, 0);
        }
    }
    size_t rbase = row0 + wave * 16 + fq * 4;
#pragma unroll
    for (int nt = 0; nt < 8; ++nt) {
        int col = nt * 16 + fr;
#pragma unroll
        for (int rg = 0; rg < 4; ++rg) {
            size_t rr = rbase + rg;
            if (rr < (size_t)N) h[rr * 128 + col] = f2bf(acc[nt][rg]);
        }
    }
}

// ================= per-head attention logits from bf16 h =================
// 8 lanes per row; lane's head = t&7; l[row*8+head] = sum_d h[row,head*16+d]*a[head*16+d]
__global__ __launch_bounds__(256) void logit_kernel(
    const u16* __restrict__ h, const float* __restrict__ a0, const float* __restrict__ a1,
    const float* __restrict__ a2, float* __restrict__ l0, float* __restrict__ l1,
    float* __restrict__ l2, int N)
{
    int t = threadIdx.x;
    int head = t & 7;
    size_t row = (size_t)blockIdx.x * 32 + (t >> 3);
    if (row >= (size_t)N) return;
    float av0[16], av1[16], av2[16];
#pragma unroll
    for (int j = 0; j < 16; ++j) {
        av0[j] = a0[head * 16 + j];
        av1[j] = a1 ? a1[head * 16 + j] : 0.f;
        av2[j] = a2 ? a2[head * 16 + j] : 0.f;
    }
    const u16* hp = h + row * 128 + head * 16;
    uint4 u0_ = *(const uint4*)hp;
    uint4 u1_ = *(const uint4*)(hp + 8);
    u32 uu[8] = {u0_.x, u0_.y, u0_.z, u0_.w, u1_.x, u1_.y, u1_.z, u1_.w};
    float p0 = 0.f, p1 = 0.f, p2 = 0.f;
#pragma unroll
    for (int j = 0; j < 8; ++j) {
        float lo = bf2f((u16)(uu[j] & 0xFFFFu));
        float hi = bf2f((u16)(uu[j] >> 16));
        p0 += lo * av0[2 * j] + hi * av0[2 * j + 1];
        p1 += lo * av1[2 * j] + hi * av1[2 * j + 1];
        p2 += lo * av2[2 * j] + hi * av2[2 * j + 1];
    }
    l0[row * 8 + head] = p0;
    if (l1) l1[row * 8 + head] = p1;
    if (l2) l2[row * 8 + head] = p2;
}

// ================= CSR build =================
__global__ __launch_bounds__(256) void hist_kernel(const int* __restrict__ edst, int* __restrict__ cnt)
{
    int e = blockIdx.x * 256 + threadIdx.x;
    if (e < NE) atomicAdd(&cnt[edst[e]], 1);
}

__global__ __launch_bounds__(256) void scan_phaseB(const int* __restrict__ cnt, int* __restrict__ bsums)
{
    __shared__ int red[256];
    int t = threadIdx.x;
    int base = blockIdx.x * 1024 + t * 4;
    int s = 0;
#pragma unroll
    for (int j = 0; j < 4; ++j) { int i = base + j; if (i < NP) s += cnt[i]; }
    red[t] = s;
    __syncthreads();
    for (int off = 128; off >= 1; off >>= 1) {
        if (t < off) red[t] += red[t + off];
        __syncthreads();
    }
    if (t == 0) bsums[blockIdx.x] = red[0];
}

__global__ __launch_bounds__(256) void scan_phaseC(int* __restrict__ bsums, int* __restrict__ row_ptr)
{
    __shared__ int sdata[256];
    int t = threadIdx.x;
    int v = (t < NB_SCAN) ? bsums[t] : 0;
    sdata[t] = v;
    __syncthreads();
    for (int off = 1; off < 256; off <<= 1) {
        int x = (t >= off) ? sdata[t - off] : 0;
        __syncthreads();
        sdata[t] += x;
        __syncthreads();
    }
    if (t < NB_SCAN) bsums[t] = sdata[t] - v; // exclusive
    if (t == 0) row_ptr[NP] = NE;
}

__global__ __launch_bounds__(256) void scan_phaseD(const int* __restrict__ cnt, const int* __restrict__ bsums,
                                                   int* __restrict__ row_ptr, int* __restrict__ cursor)
{
    __shared__ int sdata[256];
    int t = threadIdx.x;
    int base = blockIdx.x * 1024 + t * 4;
    int e[4];
    int s = 0;
#pragma unroll
    for (int j = 0; j < 4; ++j) {
        int i = base + j;
        e[j] = (i < NP) ? cnt[i] : 0;
        s += e[j];
    }
    sdata[t] = s;
    __syncthreads();
    for (int off = 1; off < 256; off <<= 1) {
        int x = (t >= off) ? sdata[t - off] : 0;
        __syncthreads();
        sdata[t] += x;
        __syncthreads();
    }
    int run = bsums[blockIdx.x] + sdata[t] - s;
#pragma unroll
    for (int j = 0; j < 4; ++j) {
        int i = base + j;
        if (i < NP) { row_ptr[i] = run; cursor[i] = run; }
        run += e[j];
    }
}

__global__ __launch_bounds__(256) void scatter_kernel(const int* __restrict__ esrc, const int* __restrict__ edst,
                                                      int* __restrict__ cursor, int* __restrict__ perm)
{
    int e = blockIdx.x * 256 + threadIdx.x;
    if (e >= NE) return;
    int pos = atomicAdd(&cursor[edst[e]], 1);
    perm[pos] = esrc[e];
}

// ================= gather aggregation: one wave per dst node =================
__global__ __launch_bounds__(256) void gather_kernel(
    const int* __restrict__ row_ptr, const int* __restrict__ perm,
    const float* __restrict__ als, const float* __restrict__ ald,
    const u16* __restrict__ hs, float* __restrict__ out)
{
    int d = blockIdx.x * 4 + (threadIdx.x >> 6);
    if (d >= NP) return;
    int lane = threadIdx.x & 63;
    int beg = row_ptr[d], end = row_ptr[d + 1];
    int myh = lane >> 3;
    float aldh[8];
#pragma unroll
    for (int h = 0; h < 8; ++h) aldh[h] = ald[(size_t)d * 8 + h];
    float dsum[8] = {0.f, 0.f, 0.f, 0.f, 0.f, 0.f, 0.f, 0.f};
    for (int e = beg + lane; e < end; e += 64) {
        int src = perm[e];
        const float* ap = als + (size_t)src * 8;
#pragma unroll
        for (int h = 0; h < 8; ++h) {
            float a = ap[h] + aldh[h];
            a = a >= 0.f ? a : 0.2f * a;
            dsum[h] += __expf(a);
        }
    }
#pragma unroll
    for (int h = 0; h < 8; ++h) {
        float v = dsum[h];
#pragma unroll
        for (int off = 32; off >= 1; off >>= 1) v += __shfl_xor(v, off, 64);
        dsum[h] = v;
    }
    float ald_my = aldh[myh];
    float inv_my = 1.f / (dsum[myh] + 1e-16f);
    float acc0 = 0.f, acc1 = 0.f;
    for (int e = beg; e < end; ++e) {
        int src = perm[e];
        float a = als[(size_t)src * 8 + myh] + ald_my;
        a = a >= 0.f ? a : 0.2f * a;
        float w = __expf(a) * inv_my;
        u32 hv = *(const u32*)(hs + (size_t)src * 128 + lane * 2);
        acc0 = fmaf(bf2f((u16)(hv & 0xFFFFu)), w, acc0);
        acc1 = fmaf(bf2f((u16)(hv >> 16)), w, acc1);
    }
    *(float2*)(out + (size_t)d * 128 + lane * 2) = make_float2(acc0, acc1);
}

// ================= convert relu(outF) -> bf16 =================
__global__ __launch_bounds__(256) void conv_relu(
    const float* __restrict__ outF, u16* __restrict__ r)
{
    size_t i = ((size_t)blockIdx.x * 256 + threadIdx.x) * 4;
    float4 v = *(const float4*)(outF + i);
    ushort4 o;
    o.x = f2bf(fmaxf(v.x, 0.f));
    o.y = f2bf(fmaxf(v.y, 0.f));
    o.z = f2bf(fmaxf(v.z, 0.f));
    o.w = f2bf(fmaxf(v.w, 0.f));
    *(ushort4*)(r + i) = o;
}

// ================= sem: per-block col-sums of tanh(out_m @ Wk + bk) =================
// blockIdx.y==0: cp from f32 outF (relu applied); ==1: pp from bf16 rpp
__global__ __launch_bounds__(256) void sem_mfma(
    const float* __restrict__ outF, const u16* __restrict__ rpp,
    const float* __restrict__ Wk, const float* __restrict__ bk,
    float* __restrict__ part)   // [2][3125][128]
{
    __shared__ alignas(16) u16 sBT[128 * 136];
    __shared__ alignas(16) u16 sA[64 * 136];
    __shared__ float red[4][128];
    int t = threadIdx.x;
    for (int i = t; i < 128 * 16; i += 256) {
        int n = i & 127, kb = i >> 7;
        u32 p[4];
#pragma unroll
        for (int j = 0; j < 4; ++j)
            p[j] = pack2(Wk[(kb * 8 + 2 * j) * 128 + n], Wk[(kb * 8 + 2 * j + 1) * 128 + n]);
        *(uint4*)(&sBT[n * 136 + kb * 8]) = make_uint4(p[0], p[1], p[2], p[3]);
    }
    size_t row0 = (size_t)blockIdx.x * 64;
    if (blockIdx.y == 0) {
        for (int i = t; i < 64 * 16; i += 256) {
            int r = i >> 4, c8 = (i & 15) * 8;
            const float* src = outF + (row0 + r) * 128 + c8;
            float4 v0 = *(const float4*)src;
            float4 v1 = *(const float4*)(src + 4);
            uint4 o = make_uint4(pack2(fmaxf(v0.x, 0.f), fmaxf(v0.y, 0.f)),
                                 pack2(fmaxf(v0.z, 0.f), fmaxf(v0.w, 0.f)),
                                 pack2(fmaxf(v1.x, 0.f), fmaxf(v1.y, 0.f)),
                                 pack2(fmaxf(v1.z, 0.f), fmaxf(v1.w, 0.f)));
            *(uint4*)(&sA[r * 136 + c8]) = o;
        }
    } else {
        for (int i = t; i < 64 * 16; i += 256) {
            int r = i >> 4, c8 = (i & 15) * 8;
            *(uint4*)(&sA[r * 136 + c8]) = *(const uint4*)(rpp + (row0 + r) * 128 + c8);
        }
    }
    __syncthreads();
    int wave = t >> 6, lane = t & 63;
    int fr = lane & 15, fq = lane >> 4;
    const u16* pA = sA + (wave * 16 + fr) * 136 + fq * 8;
    const u16* pB = sBT + fr * 136 + fq * 8;
    f32x4 acc[8];
#pragma unroll
    for (int nt = 0; nt < 8; ++nt) { float bb = bk[nt * 16 + fr]; acc[nt] = (f32x4){bb, bb, bb, bb}; }
#pragma unroll
    for (int ks = 0; ks < 4; ++ks) {
        short8v a = *(const short8v*)(pA + ks * 32);
#pragma unroll
        for (int nt = 0; nt < 8; ++nt) {
            short8v bv = *(const short8v*)(pB + nt * 16 * 136 + ks * 32);
            acc[nt] = __builtin_amdgcn_mfma_f32_16x16x32_bf16(a, bv, acc[nt], 0, 0, 0);
        }
    }
#pragma unroll
    for (int nt = 0; nt < 8; ++nt) {
        f32x4 v = acc[nt];
        float s = tanh_fast(v[0]) + tanh_fast(v[1]) + tanh_fast(v[2]) + tanh_fast(v[3]);
        s += __shfl_xor(s, 16, 64);
        s += __shfl_xor(s, 32, 64);
        if (lane < 16) red[wave][nt * 16 + lane] = s;
    }
    __syncthreads();
    if (t < 128) {
        float s = red[0][t] + red[1][t] + red[2][t] + red[3][t];
        part[((size_t)blockIdx.y * gridDim.x + blockIdx.x) * 128 + t] = s;
    }
}

// ================= sem partial-dot: vsum[m] = sum_i sum_c part[m][i][c]*q[c] =================
__global__ __launch_bounds__(256) void sem_dot(const float* __restrict__ part,
                                               const float* __restrict__ q, float* __restrict__ vsum)
{
    __shared__ float sq_[128];
    __shared__ float red[256];
    int t = threadIdx.x;
    if (t < 128) sq_[t] = q[t];
    __syncthreads();
    int c = t & 127, m = t >> 7;
    int i0 = blockIdx.x * 98;
    int i1 = i0 + 98; if (i1 > 3125) i1 = 3125;
    float acc = 0.f;
    for (int i = i0; i < i1; ++i)
        acc += part[((size_t)m * 3125 + i) * 128 + c] * sq_[c];
    red[t] = acc;
    __syncthreads();
    for (int off = 64; off >= 1; off >>= 1) {
        if ((t & 127) < off) red[t] += red[t + off];
        __syncthreads();
    }
    if ((t & 127) == 0) atomicAdd(&vsum[m], red[t]);
}

__global__ void attn2_kernel(const float* __restrict__ vsum, float* __restrict__ attn)
{
    if (threadIdx.x == 0) {
        float v0 = vsum[0] / (float)NP, v1 = vsum[1] / (float)NP;
        float mx = fmaxf(v0, v1);
        float e0 = __expf(v0 - mx), e1 = __expf(v1 - mx);
        float is = 1.f / (e0 + e1);
        attn[0] = e0 * is;
        attn[1] = e1 * is;
    }
}

// ================= MLP1: z1 = (a0*relu(out_cp) + a1*r_pp) @ W1 + b1, bf16 out + BN partials =================
__global__ __launch_bounds__(256) void mlp1_mfma(
    const float* __restrict__ outF, const u16* __restrict__ rpp, const float* __restrict__ attn,
    const float* __restrict__ W1, const float* __restrict__ b1,
    u16* __restrict__ z1, float* __restrict__ pS, float* __restrict__ pQ)
{
    __shared__ alignas(16) u16 sBT[128 * 136];
    __shared__ alignas(16) u16 sA[64 * 136];
    __shared__ float redS[4][128];
    __shared__ float redQ[4][128];
    int t = threadIdx.x;
    float a0 = attn[0], a1 = attn[1];
    for (int i = t; i < 128 * 16; i += 256) {
        int n = i & 127, kb = i >> 7;
        u32 p[4];
#pragma unroll
        for (int j = 0; j < 4; ++j)
            p[j] = pack2(W1[(kb * 8 + 2 * j) * 128 + n], W1[(kb * 8 + 2 * j + 1) * 128 + n]);
        *(uint4*)(&sBT[n * 136 + kb * 8]) = make_uint4(p[0], p[1], p[2], p[3]);
    }
    size_t row0 = (size_t)blockIdx.x * 64;
    for (int i = t; i < 64 * 16; i += 256) {
        int r = i >> 4, c8 = (i & 15) * 8;
        size_t g = (row0 + r) * 128 + c8;
        float4 v0 = *(const float4*)(outF + g);
        float4 v1 = *(const float4*)(outF + g + 4);
        uint4 up = *(const uint4*)(rpp + g);
        u32 uu[4] = {up.x, up.y, up.z, up.w};
        float f[8] = {fmaxf(v0.x, 0.f), fmaxf(v0.y, 0.f), fmaxf(v0.z, 0.f), fmaxf(v0.w, 0.f),
                      fmaxf(v1.x, 0.f), fmaxf(v1.y, 0.f), fmaxf(v1.z, 0.f), fmaxf(v1.w, 0.f)};
        u32 p[4];
#pragma unroll
        for (int j = 0; j < 4; ++j) {
            float lo = a0 * f[2 * j]     + a1 * bf2f((u16)(uu[j] & 0xFFFFu));
            float hi = a0 * f[2 * j + 1] + a1 * bf2f((u16)(uu[j] >> 16));
            p[j] = pack2(lo, hi);
        }
        *(uint4*)(&sA[r * 136 + c8]) = make_uint4(p[0], p[1], p[2], p[3]);
    }
    __syncthreads();
    int wave = t >> 6, lane = t & 63;
    int fr = lane & 15, fq = lane >> 4;
    const u16* pA = sA + (wave * 16 + fr) * 136 + fq * 8;
    const u16* pB = sBT + fr * 136 + fq * 8;
    f32x4 acc[8];
#pragma unroll
    for (int nt = 0; nt < 8; ++nt) { float bb = b1[nt * 16 + fr]; acc[nt] = (f32x4){bb, bb, bb, bb}; }
#pragma unroll
    for (int ks = 0; ks < 4; ++ks) {
        short8v a = *(const short8v*)(pA + ks * 32);
#pragma unroll
        for (int nt = 0; nt < 8; ++nt) {
            short8v bv = *(const short8v*)(pB + nt * 16 * 136 + ks * 32);
            acc[nt] = __builtin_amdgcn_mfma_f32_16x16x32_bf16(a, bv, acc[nt], 0, 0, 0);
        }
    }
    size_t rbase = row0 + wave * 16 + fq * 4;
#pragma unroll
    for (int nt = 0; nt < 8; ++nt) {
        f32x4 v = acc[nt];
        int col = nt * 16 + fr;
#pragma unroll
        for (int rg = 0; rg < 4; ++rg)
            z1[(rbase + rg) * 128 + col] = f2bf(v[rg]);
        float s = v[0] + v[1] + v[2] + v[3];
        float qq = v[0] * v[0] + v[1] * v[1] + v[2] * v[2] + v[3] * v[3];
        s += __shfl_xor(s, 16, 64);  s += __shfl_xor(s, 32, 64);
        qq += __shfl_xor(qq, 16, 64); qq += __shfl_xor(qq, 32, 64);
        if (lane < 16) { redS[wave][col] = s; redQ[wave][col] = qq; }
    }
    __syncthreads();
    if (t < 128) {
        pS[(size_t)blockIdx.x * 128 + t] = redS[0][t] + redS[1][t] + redS[2][t] + redS[3][t];
        pQ[(size_t)blockIdx.x * 128 + t] = redQ[0][t] + redQ[1][t] + redQ[2][t] + redQ[3][t];
    }
}

// ================= reduce BN partials [3125][C] -> sum/sq =================
__global__ __launch_bounds__(256) void stat_reduce(
    const float* __restrict__ pS, const float* __restrict__ pQ,
    float* __restrict__ sum, float* __restrict__ sq, int C)
{
    __shared__ float redS[256], redQ[256];
    int t = threadIdx.x;
    int c = t & (C - 1);
    int sub = t / C;
    int stride = 256 / C;
    int i0 = blockIdx.x * 125, i1 = i0 + 125;
    float s = 0.f, q = 0.f;
    for (int i = i0 + sub; i < i1; i += stride) {
        s += pS[(size_t)i * C + c];
        q += pQ[(size_t)i * C + c];
    }
    redS[t] = s; redQ[t] = q;
    __syncthreads();
    if (t < C) {
        for (int k = 1; k < stride; ++k) { s += redS[t + k * C]; q += redQ[t + k * C]; }
        atomicAdd(&sum[c], s);
        atomicAdd(&sq[c], q);
    }
}

// ================= BN finalize =================
__global__ void bn_fin(const float* __restrict__ sum, const float* __restrict__ sq,
                       const float* __restrict__ g, const float* __restrict__ be,
                       float* __restrict__ scale, float* __restrict__ shift, int C, float invN)
{
    int c = threadIdx.x;
    if (c >= C) return;
    float mu = sum[c] * invN;
    float var = sq[c] * invN - mu * mu;
    float sc = g[c] * rsqrtf(var + 1e-5f);
    scale[c] = sc;
    shift[c] = be[c] - mu * sc;
}

// ================= MLP2: z2 = relu(bn(z1)) @ W2 + b2, f32 out + BN partials =================
__global__ __launch_bounds__(256) void mlp2_mfma(
    const u16* __restrict__ z1, const float* __restrict__ scale1, const float* __restrict__ shift1,
    const float* __restrict__ W2, const float* __restrict__ b2,
    float* __restrict__ z2, float* __restrict__ pS, float* __restrict__ pQ)
{
    __shared__ alignas(16) u16 sBT[64 * 136];
    __shared__ alignas(16) u16 sA[64 * 136];
    __shared__ float sSc[128], sSh[128];
    __shared__ float redS[4][64], redQ[4][64];
    int t = threadIdx.x;
    if (t < 128) { sSc[t] = scale1[t]; sSh[t] = shift1[t]; }
    for (int i = t; i < 64 * 16; i += 256) {
        int n = i & 63, kb = i >> 6;
        u32 p[4];
#pragma unroll
        for (int j = 0; j < 4; ++j)
            p[j] = pack2(W2[(kb * 8 + 2 * j) * 64 + n], W2[(kb * 8 + 2 * j + 1) * 64 + n]);
        *(uint4*)(&sBT[n * 136 + kb * 8]) = make_uint4(p[0], p[1], p[2], p[3]);
    }
    __syncthreads();
    size_t row0 = (size_t)blockIdx.x * 64;
    for (int i = t; i < 64 * 16; i += 256) {
        int r = i >> 4, c8 = (i & 15) * 8;
        uint4 up = *(const uint4*)(z1 + (row0 + r) * 128 + c8);
        u32 uu[4] = {up.x, up.y, up.z, up.w};
        u32 p[4];
#pragma unroll
        for (int j = 0; j < 4; ++j) {
            int c = c8 + 2 * j;
            float lo = fmaxf(bf2f((u16)(uu[j] & 0xFFFFu)) * sSc[c] + sSh[c], 0.f);
            float hi = fmaxf(bf2f((u16)(uu[j] >> 16)) * sSc[c + 1] + sSh[c + 1], 0.f);
            p[j] = pack2(lo, hi);
        }
        *(uint4*)(&sA[r * 136 + c8]) = make_uint4(p[0], p[1], p[2], p[3]);
    }
    __syncthreads();
    int wave = t >> 6, lane = t & 63;
    int fr = lane & 15, fq = lane >> 4;
    const u16* pA = sA + (wave * 16 + fr) * 136 + fq * 8;
    const u16* pB = sBT + fr * 136 + fq * 8;
    f32x4 acc[4];
#pragma unroll
    for (int nt = 0; nt < 4; ++nt) { float bb = b2[nt * 16 + fr]; acc[nt] = (f32x4){bb, bb, bb, bb}; }
#pragma unroll
    for (int ks = 0; ks < 4; ++ks) {
        short8v a = *(const short8v*)(pA + ks * 32);
#pragma unroll
        for (int nt = 0; nt < 4; ++nt) {
            short8v bv = *(const short8v*)(pB + nt * 16 * 136 + ks * 32);
            acc[nt] = __builtin_amdgcn_mfma_f32_16x16x32_bf16(a, bv, acc[nt], 0, 0, 0);
        }
    }
    size_t rbase = row0 + wave * 16 + fq * 4;
#pragma unroll
    for (int nt = 0; nt < 4; ++nt) {
        f32x4 v = acc[nt];
        int col = nt * 16 + fr;
#pragma unroll
        for (int rg = 0; rg < 4; ++rg)
            z2[(rbase + rg) * 64 + col] = v[rg];
        float s = v[0] + v[1] + v[2] + v[3];
        float qq = v[0] * v[0] + v[1] * v[1] + v[2] * v[2] + v[3] * v[3];
        s += __shfl_xor(s, 16, 64);  s += __shfl_xor(s, 32, 64);
        qq += __shfl_xor(qq, 16, 64); qq += __shfl_xor(qq, 32, 64);
        if (lane < 16) { redS[wave][col] = s; redQ[wave][col] = qq; }
    }
    __syncthreads();
    if (t < 64) {
        pS[(size_t)blockIdx.x * 64 + t] = redS[0][t] + redS[1][t] + redS[2][t] + redS[3][t];
        pQ[(size_t)blockIdx.x * 64 + t] = redQ[0][t] + redQ[1][t] + redQ[2][t] + redQ[3][t];
    }
}

// ================= final: sigmoid(relu(bn(z2)) @ W3 + b3) =================
__global__ __launch_bounds__(64) void final_kernel(
    const float* __restrict__ z2, const float* __restrict__ scale2, const float* __restrict__ shift2,
    const float* __restrict__ W3, const float* __restrict__ b3, float* __restrict__ out)
{
    __shared__ float sh[64][65];
    __shared__ float sw[64];
    int t = threadIdx.x; // 64
    size_t row0 = (size_t)blockIdx.x * 64;
    sw[t] = W3[t];
    for (int j = 0; j < 64; ++j) {
        float v = z2[(row0 + j) * 64 + t] * scale2[t] + shift2[t];
        sh[j][t] = v > 0.f ? v : 0.f;
    }
    __syncthreads();
    float acc = b3[0];
#pragma unroll 16
    for (int k = 0; k < 64; ++k) acc = fmaf(sh[t][k], sw[k], acc);
    out[row0 + t] = 1.f / (1.f + __expf(-acc));
}

extern "C" void kernel_launch(void* const* d_in, const int* in_sizes, int n_in,
                              void* d_out, int out_size, void* d_ws, size_t ws_size,
                              hipStream_t stream) {
    const float* x_c      = (const float*)d_in[0];
    const float* x_p      = (const float*)d_in[1];
    const int*   e_src_cp = (const int*)d_in[2];
    const int*   e_dst_cp = (const int*)d_in[3];
    const int*   e_src_pp = (const int*)d_in[4];
    const int*   e_dst_pp = (const int*)d_in[5];
    const float* W_c      = (const float*)d_in[6];
    const float* b_c      = (const float*)d_in[7];
    const float* W_p      = (const float*)d_in[8];
    const float* b_p      = (const float*)d_in[9];
    const float* a_src_cp = (const float*)d_in[10];
    const float* a_dst_cp = (const float*)d_in[11];
    const float* a_src_pp = (const float*)d_in[12];
    const float* a_dst_pp = (const float*)d_in[13];
    const float* Wk       = (const float*)d_in[14];
    const float* bk       = (const float*)d_in[15];
    const float* q_sem    = (const float*)d_in[16];
    const float* W1       = (const float*)d_in[17];
    const float* b1       = (const float*)d_in[18];
    const float* g1       = (const float*)d_in[19];
    const float* be1      = (const float*)d_in[20];
    const float* W2       = (const float*)d_in[21];
    const float* b2       = (const float*)d_in[22];
    const float* g2       = (const float*)d_in[23];
    const float* be2      = (const float*)d_in[24];
    const float* W3       = (const float*)d_in[25];
    const float* b3       = (const float*)d_in[26];

    // ---- byte-offset workspace layout (extent 213,609,472 B; 214,408,192 proven OK) ----
    char* ws = (char*)d_ws;
    u16*   h_p    = (u16*)  (ws +          0); // 51,200,000
    u16*   h_c    = (u16*)  (ws +  51200000);  // 25,600,000
    float* al_c   = (float*)(ws +  76800000);  //  3,200,000
    float* al_dcp = (float*)(ws +  80000000);  //  6,400,000
    float* al_spp = (float*)(ws +  86400000);
    float* al_dpp = (float*)(ws +  92800000);
    int*   row_ptr= (int*)  (ws +  99200000);  // (NP+1)*4 padded
    int*   cnt    = (int*)  (ws + 100000256);  // NP*4 (doubles as cursor)
    int*   bsums  = (int*)  (ws + 100800256);  // 1024
    int*   perm   = (int*)  (ws + 100801280);  // NE*4
    float* outF   = (float*)(ws + 104801280);  // NP*128*4 = 102,400,000
    float* semPart= (float*)(ws + 207201280);  // 2*3125*128*4 = 3,200,000
    float* statS  = (float*)(ws + 210401280);  // 3125*128*4 = 1,600,000
    float* statQ  = (float*)(ws + 212001280);  // 1,600,000
    float* small  = (float*)(ws + 213601280);  // 8192

    float* vsum   = small;        // 2
    float* attn   = small + 64;   // 2
    float* sum1   = small + 128;  // 128
    float* sq1    = small + 256;  // 128
    float* sum2   = small + 384;  // 64
    float* sq2    = small + 448;  // 64
    float* scale1 = small + 512;  // 128
    float* shift1 = small + 640;  // 128
    float* scale2 = small + 768;  // 64
    float* shift2 = small + 832;  // 64

    // aliases over dead regions
    u16*   r_pp = h_p;           // relu(out_pp) bf16 after pp metapath (h_p dead)
    u16*   z1   = h_c;           // bf16 NP*128 spans [51.2M,102.4M): h_c/al/CSR dead by MLP1
    float* z2   = (float*)ws;    // f32 NP*64 spans [0,51.2M): r_pp dead by MLP2

    hipMemsetAsync(small, 0, 8192, stream);

    // projections (MFMA) + per-head logits
    proj_mfma<<<(NC + 63) / 64, 256, 0, stream>>>(x_c, W_c, b_c, h_c, NC);
    proj_mfma<<<NP / 64, 256, 0, stream>>>(x_p, W_p, b_p, h_p, NP);
    logit_kernel<<<(NC + 31) / 32, 256, 0, stream>>>(h_c, a_src_cp, nullptr, nullptr,
                                                     al_c, nullptr, nullptr, NC);
    logit_kernel<<<NP / 32, 256, 0, stream>>>(h_p, a_dst_cp, a_src_pp, a_dst_pp,
                                              al_dcp, al_spp, al_dpp, NP);

    const int GE = (NE + 255) / 256;

    // ---- metapath pp (first, so h_p dies early) ----
    hipMemsetAsync(cnt, 0, NP * 4, stream);
    hist_kernel<<<GE, 256, 0, stream>>>(e_dst_pp, cnt);
    scan_phaseB<<<NB_SCAN, 256, 0, stream>>>(cnt, bsums);
    scan_phaseC<<<1, 256, 0, stream>>>(bsums, row_ptr);
    scan_phaseD<<<NB_SCAN, 256, 0, stream>>>(cnt, bsums, row_ptr, cnt);
    scatter_kernel<<<GE, 256, 0, stream>>>(e_src_pp, e_dst_pp, cnt, perm);
    gather_kernel<<<NP / 4, 256, 0, stream>>>(row_ptr, perm, al_spp, al_dpp, h_p, outF);
    conv_relu<<<NP * 128 / 1024, 256, 0, stream>>>(outF, r_pp);

    // ---- metapath cp ----
    hipMemsetAsync(cnt, 0, NP * 4, stream);
    hist_kernel<<<GE, 256, 0, stream>>>(e_dst_cp, cnt);
    scan_phaseB<<<NB_SCAN, 256, 0, stream>>>(cnt, bsums);
    scan_phaseC<<<1, 256, 0, stream>>>(bsums, row_ptr);
    scan_phaseD<<<NB_SCAN, 256, 0, stream>>>(cnt, bsums, row_ptr, cnt);
    scatter_kernel<<<GE, 256, 0, stream>>>(e_src_cp, e_dst_cp, cnt, perm);
    gather_kernel<<<NP / 4, 256, 0, stream>>>(row_ptr, perm, al_c, al_dcp, h_c, outF);

    // semantic attention
    {
        dim3 gs(NP / 64, 2);
        sem_mfma<<<gs, 256, 0, stream>>>(outF, r_pp, Wk, bk, semPart);
    }
    sem_dot<<<32, 256, 0, stream>>>(semPart, q_sem, vsum);
    attn2_kernel<<<1, 64, 0, stream>>>(vsum, attn);

    // MLP + BN
    mlp1_mfma<<<NP / 64, 256, 0, stream>>>(outF, r_pp, attn, W1, b1, z1, statS, statQ);
    stat_reduce<<<25, 256, 0, stream>>>(statS, statQ, sum1, sq1, 128);
    bn_fin<<<1, 128, 0, stream>>>(sum1, sq1, g1, be1, scale1, shift1, 128, 1.f / (float)NP);
    mlp2_mfma<<<NP / 64, 256, 0, stream>>>(z1, scale1, shift1, W2, b2, z2, statS, statQ);
    stat_reduce<<<25, 256, 0, stream>>>(statS, statQ, sum2, sq2, 64);
    bn_fin<<<1, 128, 0, stream>>>(sum2, sq2, g2, be2, scale2, shift2, 64, 1.f / (float)NP);
    final_kernel<<<NP / 64, 64, 0, stream>>>(z2, scale2, shift2, W3, b3, (float*)d_out);
}

// Round 5
// 830.154 us; speedup vs baseline: 7.0885x; 1.1245x over previous
//
#include <hip/hip_runtime.h>
#include <hip/hip_bf16.h>

#define NC 100000
#define NP 200000
#define NE 1000000
#define NB_SCAN 196  // ceil(NP/1024)

typedef unsigned short u16;
typedef unsigned int u32;
typedef __attribute__((ext_vector_type(8))) short short8v;  // 8 bf16 (4 VGPRs)
typedef __attribute__((ext_vector_type(4))) float f32x4;

__device__ __forceinline__ float bf2f(u16 v) {
    union { u32 u; float f; } c; c.u = ((u32)v) << 16; return c.f;
}
__device__ __forceinline__ u16 f2bf(float f) {
    union { float f; u32 u; } c; c.f = f;
    u32 u = c.u;
    return (u16)((u + 0x7FFFu + ((u >> 16) & 1u)) >> 16); // RNE
}
__device__ __forceinline__ u32 pack2(float lo, float hi) {
    return (u32)f2bf(lo) | ((u32)f2bf(hi) << 16);
}
__device__ __forceinline__ float tanh_fast(float x) {
    return 1.f - 2.f / (__expf(2.f * x) + 1.f);
}

// ================= proj: h[N,128] = bf16(x[N,64] @ W + b) via MFMA =================
__global__ __launch_bounds__(256) void proj_mfma(
    const float* __restrict__ x, const float* __restrict__ W, const float* __restrict__ b,
    u16* __restrict__ h, int N)
{
    __shared__ alignas(16) u16 sBT[128 * 72];  // [n][k] padded K=64->72
    __shared__ alignas(16) u16 sA[64 * 72];
    int t = threadIdx.x;
    for (int i = t; i < 128 * 8; i += 256) {
        int n = i & 127, kb = i >> 7;
        u32 p[4];
#pragma unroll
        for (int j = 0; j < 4; ++j)
            p[j] = pack2(W[(kb * 8 + 2 * j) * 128 + n], W[(kb * 8 + 2 * j + 1) * 128 + n]);
        *(uint4*)(&sBT[n * 72 + kb * 8]) = make_uint4(p[0], p[1], p[2], p[3]);
    }
    size_t row0 = (size_t)blockIdx.x * 64;
    for (int i = t; i < 64 * 8; i += 256) {
        int r = i >> 3, c8 = (i & 7) * 8;
        u32 p[4];
        if (row0 + r < (size_t)N) {
            const float* src = x + (row0 + r) * 64 + c8;
            float4 v0 = *(const float4*)src;
            float4 v1 = *(const float4*)(src + 4);
            p[0] = pack2(v0.x, v0.y); p[1] = pack2(v0.z, v0.w);
            p[2] = pack2(v1.x, v1.y); p[3] = pack2(v1.z, v1.w);
        } else { p[0] = p[1] = p[2] = p[3] = 0; }
        *(uint4*)(&sA[r * 72 + c8]) = make_uint4(p[0], p[1], p[2], p[3]);
    }
    __syncthreads();
    int wave = t >> 6, lane = t & 63;
    int fr = lane & 15, fq = lane >> 4;
    const u16* pA = sA + (wave * 16 + fr) * 72 + fq * 8;
    const u16* pB = sBT + fr * 72 + fq * 8;
    f32x4 acc[8];
#pragma unroll
    for (int nt = 0; nt < 8; ++nt) { float bb = b[nt * 16 + fr]; acc[nt] = (f32x4){bb, bb, bb, bb}; }
#pragma unroll
    for (int ks = 0; ks < 2; ++ks) {
        short8v a = *(const short8v*)(pA + ks * 32);
#pragma unroll
        for (int nt = 0; nt < 8; ++nt) {
            short8v bv = *(const short8v*)(pB + nt * 16 * 72 + ks * 32);
            acc[nt] = __builtin_amdgcn_mfma_f32_16x16x32_bf16(a, bv, acc[nt], 0, 0, 0);
        }
    }
    size_t rbase = row0 + wave * 16 + fq * 4;
#pragma unroll
    for (int nt = 0; nt < 8; ++nt) {
        int col = nt * 16 + fr;
#pragma unroll
        for (int rg = 0; rg < 4; ++rg) {
            size_t rr = rbase + rg;
            if (rr < (size_t)N) h[rr * 128 + col] = f2bf(acc[nt][rg]);
        }
    }
}

// ================= per-head attention logits from bf16 h =================
__global__ __launch_bounds__(256) void logit_kernel(
    const u16* __restrict__ h, const float* __restrict__ a0, const float* __restrict__ a1,
    const float* __restrict__ a2, float* __restrict__ l0, float* __restrict__ l1,
    float* __restrict__ l2, int N)
{
    int t = threadIdx.x;
    int head = t & 7;
    size_t row = (size_t)blockIdx.x * 32 + (t >> 3);
    if (row >= (size_t)N) return;
    float av0[16], av1[16], av2[16];
#pragma unroll
    for (int j = 0; j < 16; ++j) {
        av0[j] = a0[head * 16 + j];
        av1[j] = a1 ? a1[head * 16 + j] : 0.f;
        av2[j] = a2 ? a2[head * 16 + j] : 0.f;
    }
    const u16* hp = h + row * 128 + head * 16;
    uint4 u0_ = *(const uint4*)hp;
    uint4 u1_ = *(const uint4*)(hp + 8);
    u32 uu[8] = {u0_.x, u0_.y, u0_.z, u0_.w, u1_.x, u1_.y, u1_.z, u1_.w};
    float p0 = 0.f, p1 = 0.f, p2 = 0.f;
#pragma unroll
    for (int j = 0; j < 8; ++j) {
        float lo = bf2f((u16)(uu[j] & 0xFFFFu));
        float hi = bf2f((u16)(uu[j] >> 16));
        p0 += lo * av0[2 * j] + hi * av0[2 * j + 1];
        p1 += lo * av1[2 * j] + hi * av1[2 * j + 1];
        p2 += lo * av2[2 * j] + hi * av2[2 * j + 1];
    }
    l0[row * 8 + head] = p0;
    if (l1) l1[row * 8 + head] = p1;
    if (l2) l2[row * 8 + head] = p2;
}

// ================= CSR build =================
__global__ __launch_bounds__(256) void hist_kernel(const int* __restrict__ edst, int* __restrict__ cnt)
{
    int e = blockIdx.x * 256 + threadIdx.x;
    if (e < NE) atomicAdd(&cnt[edst[e]], 1);
}

__global__ __launch_bounds__(256) void scan_phaseB(const int* __restrict__ cnt, int* __restrict__ bsums)
{
    __shared__ int red[256];
    int t = threadIdx.x;
    int base = blockIdx.x * 1024 + t * 4;
    int s = 0;
#pragma unroll
    for (int j = 0; j < 4; ++j) { int i = base + j; if (i < NP) s += cnt[i]; }
    red[t] = s;
    __syncthreads();
    for (int off = 128; off >= 1; off >>= 1) {
        if (t < off) red[t] += red[t + off];
        __syncthreads();
    }
    if (t == 0) bsums[blockIdx.x] = red[0];
}

__global__ __launch_bounds__(256) void scan_phaseC(int* __restrict__ bsums, int* __restrict__ row_ptr)
{
    __shared__ int sdata[256];
    int t = threadIdx.x;
    int v = (t < NB_SCAN) ? bsums[t] : 0;
    sdata[t] = v;
    __syncthreads();
    for (int off = 1; off < 256; off <<= 1) {
        int x = (t >= off) ? sdata[t - off] : 0;
        __syncthreads();
        sdata[t] += x;
        __syncthreads();
    }
    if (t < NB_SCAN) bsums[t] = sdata[t] - v; // exclusive
    if (t == 0) row_ptr[NP] = NE;
}

__global__ __launch_bounds__(256) void scan_phaseD(const int* __restrict__ cnt, const int* __restrict__ bsums,
                                                   int* __restrict__ row_ptr, int* __restrict__ cursor)
{
    __shared__ int sdata[256];
    int t = threadIdx.x;
    int base = blockIdx.x * 1024 + t * 4;
    int e[4];
    int s = 0;
#pragma unroll
    for (int j = 0; j < 4; ++j) {
        int i = base + j;
        e[j] = (i < NP) ? cnt[i] : 0;
        s += e[j];
    }
    sdata[t] = s;
    __syncthreads();
    for (int off = 1; off < 256; off <<= 1) {
        int x = (t >= off) ? sdata[t - off] : 0;
        __syncthreads();
        sdata[t] += x;
        __syncthreads();
    }
    int run = bsums[blockIdx.x] + sdata[t] - s;
#pragma unroll
    for (int j = 0; j < 4; ++j) {
        int i = base + j;
        if (i < NP) { row_ptr[i] = run; cursor[i] = run; }
        run += e[j];
    }
}

__global__ __launch_bounds__(256) void scatter_kernel(const int* __restrict__ esrc, const int* __restrict__ edst,
                                                      int* __restrict__ cursor, int* __restrict__ perm)
{
    int e = blockIdx.x * 256 + threadIdx.x;
    if (e >= NE) return;
    int pos = atomicAdd(&cursor[edst[e]], 1);
    perm[pos] = esrc[e];
}

// ================= gather aggregation: one wave per dst, single pass =================
// acc = sum_e exp(leaky(al_e)) * h_src ; normalize by scalar at end; write relu'd bf16.
__global__ __launch_bounds__(256) void gather_kernel(
    const int* __restrict__ row_ptr, const int* __restrict__ perm,
    const float* __restrict__ als, const float* __restrict__ ald,
    const u16* __restrict__ hs, u16* __restrict__ out)
{
    int d = blockIdx.x * 4 + (threadIdx.x >> 6);
    int lane = threadIdx.x & 63;
    int head = lane >> 3;   // channels 2*lane, 2*lane+1 belong to head (2*lane)>>4 = lane>>3
    int beg = row_ptr[d], end = row_ptr[d + 1];
    float ald_h = ald[(size_t)d * 8 + head];
    float dsum = 0.f, acc0 = 0.f, acc1 = 0.f;
    for (int e = beg; e < end; ++e) {
        int src = perm[e];                       // uniform across wave -> broadcast
        float a = als[(size_t)src * 8 + head] + ald_h;
        a = a >= 0.f ? a : 0.2f * a;
        float w = __expf(a);
        dsum += w;
        u32 hv = *(const u32*)(hs + (size_t)src * 128 + lane * 2);
        acc0 = fmaf(bf2f((u16)(hv & 0xFFFFu)), w, acc0);
        acc1 = fmaf(bf2f((u16)(hv >> 16)), w, acc1);
    }
    float inv = 1.f / (dsum + 1e-16f);
    *(u32*)(out + (size_t)d * 128 + lane * 2) =
        pack2(fmaxf(acc0 * inv, 0.f), fmaxf(acc1 * inv, 0.f));
}

// ================= sem: per-block col-sums of tanh(r_m @ Wk + bk) =================
__global__ __launch_bounds__(256) void sem_mfma(
    const u16* __restrict__ r0, const u16* __restrict__ r1,
    const float* __restrict__ Wk, const float* __restrict__ bk,
    float* __restrict__ part)   // [2][3125][128]
{
    __shared__ alignas(16) u16 sBT[128 * 136];
    __shared__ alignas(16) u16 sA[64 * 136];
    __shared__ float red[4][128];
    int t = threadIdx.x;
    const u16* src = blockIdx.y ? r1 : r0;
    for (int i = t; i < 128 * 16; i += 256) {
        int n = i & 127, kb = i >> 7;
        u32 p[4];
#pragma unroll
        for (int j = 0; j < 4; ++j)
            p[j] = pack2(Wk[(kb * 8 + 2 * j) * 128 + n], Wk[(kb * 8 + 2 * j + 1) * 128 + n]);
        *(uint4*)(&sBT[n * 136 + kb * 8]) = make_uint4(p[0], p[1], p[2], p[3]);
    }
    size_t row0 = (size_t)blockIdx.x * 64;
    for (int i = t; i < 64 * 16; i += 256) {
        int r = i >> 4, c8 = (i & 15) * 8;
        *(uint4*)(&sA[r * 136 + c8]) = *(const uint4*)(src + (row0 + r) * 128 + c8);
    }
    __syncthreads();
    int wave = t >> 6, lane = t & 63;
    int fr = lane & 15, fq = lane >> 4;
    const u16* pA = sA + (wave * 16 + fr) * 136 + fq * 8;
    const u16* pB = sBT + fr * 136 + fq * 8;
    f32x4 acc[8];
#pragma unroll
    for (int nt = 0; nt < 8; ++nt) { float bb = bk[nt * 16 + fr]; acc[nt] = (f32x4){bb, bb, bb, bb}; }
#pragma unroll
    for (int ks = 0; ks < 4; ++ks) {
        short8v a = *(const short8v*)(pA + ks * 32);
#pragma unroll
        for (int nt = 0; nt < 8; ++nt) {
            short8v bv = *(const short8v*)(pB + nt * 16 * 136 + ks * 32);
            acc[nt] = __builtin_amdgcn_mfma_f32_16x16x32_bf16(a, bv, acc[nt], 0, 0, 0);
        }
    }
#pragma unroll
    for (int nt = 0; nt < 8; ++nt) {
        f32x4 v = acc[nt];
        float s = tanh_fast(v[0]) + tanh_fast(v[1]) + tanh_fast(v[2]) + tanh_fast(v[3]);
        s += __shfl_xor(s, 16, 64);
        s += __shfl_xor(s, 32, 64);
        if (lane < 16) red[wave][nt * 16 + lane] = s;
    }
    __syncthreads();
    if (t < 128) {
        float s = red[0][t] + red[1][t] + red[2][t] + red[3][t];
        part[((size_t)blockIdx.y * gridDim.x + blockIdx.x) * 128 + t] = s;
    }
}

// ================= sem partial-dot =================
__global__ __launch_bounds__(256) void sem_dot(const float* __restrict__ part,
                                               const float* __restrict__ q, float* __restrict__ vsum)
{
    __shared__ float sq_[128];
    __shared__ float red[256];
    int t = threadIdx.x;
    if (t < 128) sq_[t] = q[t];
    __syncthreads();
    int c = t & 127, m = t >> 7;
    int i0 = blockIdx.x * 98;
    int i1 = i0 + 98; if (i1 > 3125) i1 = 3125;
    float acc = 0.f;
    for (int i = i0; i < i1; ++i)
        acc += part[((size_t)m * 3125 + i) * 128 + c] * sq_[c];
    red[t] = acc;
    __syncthreads();
    for (int off = 64; off >= 1; off >>= 1) {
        if ((t & 127) < off) red[t] += red[t + off];
        __syncthreads();
    }
    if ((t & 127) == 0) atomicAdd(&vsum[m], red[t]);
}

__global__ void attn2_kernel(const float* __restrict__ vsum, float* __restrict__ attn)
{
    if (threadIdx.x == 0) {
        float v0 = vsum[0] / (float)NP, v1 = vsum[1] / (float)NP;
        float mx = fmaxf(v0, v1);
        float e0 = __expf(v0 - mx), e1 = __expf(v1 - mx);
        float is = 1.f / (e0 + e1);
        attn[0] = e0 * is;
        attn[1] = e1 * is;
    }
}

// ================= MLP1: z1 = (a0*r_cp + a1*r_pp) @ W1 + b1, bf16 out + BN partials =================
__global__ __launch_bounds__(256) void mlp1_mfma(
    const u16* __restrict__ rcp, const u16* __restrict__ rpp, const float* __restrict__ attn,
    const float* __restrict__ W1, const float* __restrict__ b1,
    u16* __restrict__ z1, float* __restrict__ pS, float* __restrict__ pQ)
{
    __shared__ alignas(16) u16 sBT[128 * 136];
    __shared__ alignas(16) u16 sA[64 * 136];
    __shared__ float redS[4][128];
    __shared__ float redQ[4][128];
    int t = threadIdx.x;
    float a0 = attn[0], a1 = attn[1];
    for (int i = t; i < 128 * 16; i += 256) {
        int n = i & 127, kb = i >> 7;
        u32 p[4];
#pragma unroll
        for (int j = 0; j < 4; ++j)
            p[j] = pack2(W1[(kb * 8 + 2 * j) * 128 + n], W1[(kb * 8 + 2 * j + 1) * 128 + n]);
        *(uint4*)(&sBT[n * 136 + kb * 8]) = make_uint4(p[0], p[1], p[2], p[3]);
    }
    size_t row0 = (size_t)blockIdx.x * 64;
    for (int i = t; i < 64 * 16; i += 256) {
        int r = i >> 4, c8 = (i & 15) * 8;
        size_t g = (row0 + r) * 128 + c8;
        uint4 uc = *(const uint4*)(rcp + g);
        uint4 up = *(const uint4*)(rpp + g);
        u32 uuc[4] = {uc.x, uc.y, uc.z, uc.w};
        u32 uup[4] = {up.x, up.y, up.z, up.w};
        u32 p[4];
#pragma unroll
        for (int j = 0; j < 4; ++j) {
            float lo = a0 * bf2f((u16)(uuc[j] & 0xFFFFu)) + a1 * bf2f((u16)(uup[j] & 0xFFFFu));
            float hi = a0 * bf2f((u16)(uuc[j] >> 16))     + a1 * bf2f((u16)(uup[j] >> 16));
            p[j] = pack2(lo, hi);
        }
        *(uint4*)(&sA[r * 136 + c8]) = make_uint4(p[0], p[1], p[2], p[3]);
    }
    __syncthreads();
    int wave = t >> 6, lane = t & 63;
    int fr = lane & 15, fq = lane >> 4;
    const u16* pA = sA + (wave * 16 + fr) * 136 + fq * 8;
    const u16* pB = sBT + fr * 136 + fq * 8;
    f32x4 acc[8];
#pragma unroll
    for (int nt = 0; nt < 8; ++nt) { float bb = b1[nt * 16 + fr]; acc[nt] = (f32x4){bb, bb, bb, bb}; }
#pragma unroll
    for (int ks = 0; ks < 4; ++ks) {
        short8v a = *(const short8v*)(pA + ks * 32);
#pragma unroll
        for (int nt = 0; nt < 8; ++nt) {
            short8v bv = *(const short8v*)(pB + nt * 16 * 136 + ks * 32);
            acc[nt] = __builtin_amdgcn_mfma_f32_16x16x32_bf16(a, bv, acc[nt], 0, 0, 0);
        }
    }
    size_t rbase = row0 + wave * 16 + fq * 4;
#pragma unroll
    for (int nt = 0; nt < 8; ++nt) {
        f32x4 v = acc[nt];
        int col = nt * 16 + fr;
#pragma unroll
        for (int rg = 0; rg < 4; ++rg)
            z1[(rbase + rg) * 128 + col] = f2bf(v[rg]);
        float s = v[0] + v[1] + v[2] + v[3];
        float qq = v[0] * v[0] + v[1] * v[1] + v[2] * v[2] + v[3] * v[3];
        s += __shfl_xor(s, 16, 64);  s += __shfl_xor(s, 32, 64);
        qq += __shfl_xor(qq, 16, 64); qq += __shfl_xor(qq, 32, 64);
        if (lane < 16) { redS[wave][col] = s; redQ[wave][col] = qq; }
    }
    __syncthreads();
    if (t < 128) {
        pS[(size_t)blockIdx.x * 128 + t] = redS[0][t] + redS[1][t] + redS[2][t] + redS[3][t];
        pQ[(size_t)blockIdx.x * 128 + t] = redQ[0][t] + redQ[1][t] + redQ[2][t] + redQ[3][t];
    }
}

// ================= reduce BN partials [3125][C] -> sum/sq =================
__global__ __launch_bounds__(256) void stat_reduce(
    const float* __restrict__ pS, const float* __restrict__ pQ,
    float* __restrict__ sum, float* __restrict__ sq, int C)
{
    __shared__ float redS[256], redQ[256];
    int t = threadIdx.x;
    int c = t & (C - 1);
    int sub = t / C;
    int stride = 256 / C;
    int i0 = blockIdx.x * 125, i1 = i0 + 125;
    float s = 0.f, q = 0.f;
    for (int i = i0 + sub; i < i1; i += stride) {
        s += pS[(size_t)i * C + c];
        q += pQ[(size_t)i * C + c];
    }
    redS[t] = s; redQ[t] = q;
    __syncthreads();
    if (t < C) {
        for (int k = 1; k < stride; ++k) { s += redS[t + k * C]; q += redQ[t + k * C]; }
        atomicAdd(&sum[c], s);
        atomicAdd(&sq[c], q);
    }
}

// ================= BN finalize =================
__global__ void bn_fin(const float* __restrict__ sum, const float* __restrict__ sq,
                       const float* __restrict__ g, const float* __restrict__ be,
                       float* __restrict__ scale, float* __restrict__ shift, int C, float invN)
{
    int c = threadIdx.x;
    if (c >= C) return;
    float mu = sum[c] * invN;
    float var = sq[c] * invN - mu * mu;
    float sc = g[c] * rsqrtf(var + 1e-5f);
    scale[c] = sc;
    shift[c] = be[c] - mu * sc;
}

// ================= MLP2: z2 = relu(bn(z1)) @ W2 + b2, f32 out + BN partials =================
__global__ __launch_bounds__(256) void mlp2_mfma(
    const u16* __restrict__ z1, const float* __restrict__ scale1, const float* __restrict__ shift1,
    const float* __restrict__ W2, const float* __restrict__ b2,
    float* __restrict__ z2, float* __restrict__ pS, float* __restrict__ pQ)
{
    __shared__ alignas(16) u16 sBT[64 * 136];
    __shared__ alignas(16) u16 sA[64 * 136];
    __shared__ float sSc[128], sSh[128];
    __shared__ float redS[4][64], redQ[4][64];
    int t = threadIdx.x;
    if (t < 128) { sSc[t] = scale1[t]; sSh[t] = shift1[t]; }
    for (int i = t; i < 64 * 16; i += 256) {
        int n = i & 63, kb = i >> 6;
        u32 p[4];
#pragma unroll
        for (int j = 0; j < 4; ++j)
            p[j] = pack2(W2[(kb * 8 + 2 * j) * 64 + n], W2[(kb * 8 + 2 * j + 1) * 64 + n]);
        *(uint4*)(&sBT[n * 136 + kb * 8]) = make_uint4(p[0], p[1], p[2], p[3]);
    }
    __syncthreads();
    size_t row0 = (size_t)blockIdx.x * 64;
    for (int i = t; i < 64 * 16; i += 256) {
        int r = i >> 4, c8 = (i & 15) * 8;
        uint4 up = *(const uint4*)(z1 + (row0 + r) * 128 + c8);
        u32 uu[4] = {up.x, up.y, up.z, up.w};
        u32 p[4];
#pragma unroll
        for (int j = 0; j < 4; ++j) {
            int c = c8 + 2 * j;
            float lo = fmaxf(bf2f((u16)(uu[j] & 0xFFFFu)) * sSc[c] + sSh[c], 0.f);
            float hi = fmaxf(bf2f((u16)(uu[j] >> 16)) * sSc[c + 1] + sSh[c + 1], 0.f);
            p[j] = pack2(lo, hi);
        }
        *(uint4*)(&sA[r * 136 + c8]) = make_uint4(p[0], p[1], p[2], p[3]);
    }
    __syncthreads();
    int wave = t >> 6, lane = t & 63;
    int fr = lane & 15, fq = lane >> 4;
    const u16* pA = sA + (wave * 16 + fr) * 136 + fq * 8;
    const u16* pB = sBT + fr * 136 + fq * 8;
    f32x4 acc[4];
#pragma unroll
    for (int nt = 0; nt < 4; ++nt) { float bb = b2[nt * 16 + fr]; acc[nt] = (f32x4){bb, bb, bb, bb}; }
#pragma unroll
    for (int ks = 0; ks < 4; ++ks) {
        short8v a = *(const short8v*)(pA + ks * 32);
#pragma unroll
        for (int nt = 0; nt < 4; ++nt) {
            short8v bv = *(const short8v*)(pB + nt * 16 * 136 + ks * 32);
            acc[nt] = __builtin_amdgcn_mfma_f32_16x16x32_bf16(a, bv, acc[nt], 0, 0, 0);
        }
    }
    size_t rbase = row0 + wave * 16 + fq * 4;
#pragma unroll
    for (int nt = 0; nt < 4; ++nt) {
        f32x4 v = acc[nt];
        int col = nt * 16 + fr;
#pragma unroll
        for (int rg = 0; rg < 4; ++rg)
            z2[(rbase + rg) * 64 + col] = v[rg];
        float s = v[0] + v[1] + v[2] + v[3];
        float qq = v[0] * v[0] + v[1] * v[1] + v[2] * v[2] + v[3] * v[3];
        s += __shfl_xor(s, 16, 64);  s += __shfl_xor(s, 32, 64);
        qq += __shfl_xor(qq, 16, 64); qq += __shfl_xor(qq, 32, 64);
        if (lane < 16) { redS[wave][col] = s; redQ[wave][col] = qq; }
    }
    __syncthreads();
    if (t < 64) {
        pS[(size_t)blockIdx.x * 64 + t] = redS[0][t] + redS[1][t] + redS[2][t] + redS[3][t];
        pQ[(size_t)blockIdx.x * 64 + t] = redQ[0][t] + redQ[1][t] + redQ[2][t] + redQ[3][t];
    }
}

// ================= final: sigmoid(relu(bn(z2)) @ W3 + b3) =================
__global__ __launch_bounds__(64) void final_kernel(
    const float* __restrict__ z2, const float* __restrict__ scale2, const float* __restrict__ shift2,
    const float* __restrict__ W3, const float* __restrict__ b3, float* __restrict__ out)
{
    __shared__ float sh[64][65];
    __shared__ float sw[64];
    int t = threadIdx.x; // 64
    size_t row0 = (size_t)blockIdx.x * 64;
    sw[t] = W3[t];
    for (int j = 0; j < 64; ++j) {
        float v = z2[(row0 + j) * 64 + t] * scale2[t] + shift2[t];
        sh[j][t] = v > 0.f ? v : 0.f;
    }
    __syncthreads();
    float acc = b3[0];
#pragma unroll 16
    for (int k = 0; k < 64; ++k) acc = fmaf(sh[t][k], sw[k], acc);
    out[row0 + t] = 1.f / (1.f + __expf(-acc));
}

extern "C" void kernel_launch(void* const* d_in, const int* in_sizes, int n_in,
                              void* d_out, int out_size, void* d_ws, size_t ws_size,
                              hipStream_t stream) {
    const float* x_c      = (const float*)d_in[0];
    const float* x_p      = (const float*)d_in[1];
    const int*   e_src_cp = (const int*)d_in[2];
    const int*   e_dst_cp = (const int*)d_in[3];
    const int*   e_src_pp = (const int*)d_in[4];
    const int*   e_dst_pp = (const int*)d_in[5];
    const float* W_c      = (const float*)d_in[6];
    const float* b_c      = (const float*)d_in[7];
    const float* W_p      = (const float*)d_in[8];
    const float* b_p      = (const float*)d_in[9];
    const float* a_src_cp = (const float*)d_in[10];
    const float* a_dst_cp = (const float*)d_in[11];
    const float* a_src_pp = (const float*)d_in[12];
    const float* a_dst_pp = (const float*)d_in[13];
    const float* Wk       = (const float*)d_in[14];
    const float* bk       = (const float*)d_in[15];
    const float* q_sem    = (const float*)d_in[16];
    const float* W1       = (const float*)d_in[17];
    const float* b1       = (const float*)d_in[18];
    const float* g1       = (const float*)d_in[19];
    const float* be1      = (const float*)d_in[20];
    const float* W2       = (const float*)d_in[21];
    const float* b2       = (const float*)d_in[22];
    const float* g2       = (const float*)d_in[23];
    const float* be2      = (const float*)d_in[24];
    const float* W3       = (const float*)d_in[25];
    const float* b3       = (const float*)d_in[26];

    // ---- byte-offset workspace layout (extent 213,609,472 B; proven OK) ----
    char* ws = (char*)d_ws;
    u16*   h_p    = (u16*)  (ws +          0); // 51,200,000
    u16*   h_c    = (u16*)  (ws +  51200000);  // 25,600,000
    float* al_c   = (float*)(ws +  76800000);  //  3,200,000
    float* al_dcp = (float*)(ws +  80000000);  //  6,400,000
    float* al_spp = (float*)(ws +  86400000);
    float* al_dpp = (float*)(ws +  92800000);
    int*   row_ptr= (int*)  (ws +  99200000);  // (NP+1)*4 padded
    int*   cnt    = (int*)  (ws + 100000256);  // NP*4 (doubles as cursor)
    int*   bsums  = (int*)  (ws + 100800256);  // 1024
    int*   perm   = (int*)  (ws + 100801280);  // NE*4
    u16*   r_pp   = (u16*)  (ws + 104801280);  // NP*128 bf16 = 51,200,000 (relu'd)
    u16*   r_cp   = (u16*)  (ws + 156001280);  // NP*128 bf16 = 51,200,000 (relu'd)
    float* semPart= (float*)(ws + 207201280);  // 2*3125*128*4 = 3,200,000
    float* statS  = (float*)(ws + 210401280);  // 1,600,000
    float* statQ  = (float*)(ws + 212001280);  // 1,600,000
    float* small  = (float*)(ws + 213601280);  // 8192

    float* vsum   = small;        // 2
    float* attn   = small + 64;   // 2
    float* sum1   = small + 128;  // 128
    float* sq1    = small + 256;  // 128
    float* sum2   = small + 384;  // 64
    float* sq2    = small + 448;  // 64
    float* scale1 = small + 512;  // 128
    float* shift1 = small + 640;  // 128
    float* scale2 = small + 768;  // 64
    float* shift2 = small + 832;  // 64

    // aliases over dead regions
    u16*   z1 = h_p;                    // bf16 NP*128 at [0,51.2M): h_p dead after pp-gather
    float* z2 = (float*)(ws + 51200000); // f32 NP*64 at [51.2M,102.4M): h_c/al/CSR dead by MLP2

    hipMemsetAsync(small, 0, 8192, stream);

    // projections (MFMA) + per-head logits
    proj_mfma<<<(NC + 63) / 64, 256, 0, stream>>>(x_c, W_c, b_c, h_c, NC);
    proj_mfma<<<NP / 64, 256, 0, stream>>>(x_p, W_p, b_p, h_p, NP);
    logit_kernel<<<(NC + 31) / 32, 256, 0, stream>>>(h_c, a_src_cp, nullptr, nullptr,
                                                     al_c, nullptr, nullptr, NC);
    logit_kernel<<<NP / 32, 256, 0, stream>>>(h_p, a_dst_cp, a_src_pp, a_dst_pp,
                                              al_dcp, al_spp, al_dpp, NP);

    const int GE = (NE + 255) / 256;

    // ---- metapath pp (first, so h_p dies early) ----
    hipMemsetAsync(cnt, 0, NP * 4, stream);
    hist_kernel<<<GE, 256, 0, stream>>>(e_dst_pp, cnt);
    scan_phaseB<<<NB_SCAN, 256, 0, stream>>>(cnt, bsums);
    scan_phaseC<<<1, 256, 0, stream>>>(bsums, row_ptr);
    scan_phaseD<<<NB_SCAN, 256, 0, stream>>>(cnt, bsums, row_ptr, cnt);
    scatter_kernel<<<GE, 256, 0, stream>>>(e_src_pp, e_dst_pp, cnt, perm);
    gather_kernel<<<NP / 4, 256, 0, stream>>>(row_ptr, perm, al_spp, al_dpp, h_p, r_pp);

    // ---- metapath cp ----
    hipMemsetAsync(cnt, 0, NP * 4, stream);
    hist_kernel<<<GE, 256, 0, stream>>>(e_dst_cp, cnt);
    scan_phaseB<<<NB_SCAN, 256, 0, stream>>>(cnt, bsums);
    scan_phaseC<<<1, 256, 0, stream>>>(bsums, row_ptr);
    scan_phaseD<<<NB_SCAN, 256, 0, stream>>>(cnt, bsums, row_ptr, cnt);
    scatter_kernel<<<GE, 256, 0, stream>>>(e_src_cp, e_dst_cp, cnt, perm);
    gather_kernel<<<NP / 4, 256, 0, stream>>>(row_ptr, perm, al_c, al_dcp, h_c, r_cp);

    // semantic attention
    {
        dim3 gs(NP / 64, 2);
        sem_mfma<<<gs, 256, 0, stream>>>(r_cp, r_pp, Wk, bk, semPart);
    }
    sem_dot<<<32, 256, 0, stream>>>(semPart, q_sem, vsum);
    attn2_kernel<<<1, 64, 0, stream>>>(vsum, attn);

    // MLP + BN
    mlp1_mfma<<<NP / 64, 256, 0, stream>>>(r_cp, r_pp, attn, W1, b1, z1, statS, statQ);
    stat_reduce<<<25, 256, 0, stream>>>(statS, statQ, sum1, sq1, 128);
    bn_fin<<<1, 128, 0, stream>>>(sum1, sq1, g1, be1, scale1, shift1, 128, 1.f / (float)NP);
    mlp2_mfma<<<NP / 64, 256, 0, stream>>>(z1, scale1, shift1, W2, b2, z2, statS, statQ);
    stat_reduce<<<25, 256, 0, stream>>>(statS, statQ, sum2, sq2, 64);
    bn_fin<<<1, 128, 0, stream>>>(sum2, sq2, g2, be2, scale2, shift2, 64, 1.f / (float)NP);
    final_kernel<<<NP / 64, 64, 0, stream>>>(z2, scale2, shift2, W3, b3, (float*)d_out);
}

// Round 6
// 667.797 us; speedup vs baseline: 8.8119x; 1.2431x over previous
//
#include <hip/hip_runtime.h>
#include <hip/hip_bf16.h>

#define NC 100000
#define NP 200000
#define NE 1000000
#define NN2 (2 * NP)      // combined dst-node space (pp then cp)
#define NBS2 196          // ceil(NN2/2048)

typedef unsigned short u16;
typedef unsigned int u32;
typedef __attribute__((ext_vector_type(8))) short short8v;  // 8 bf16 (4 VGPRs)
typedef __attribute__((ext_vector_type(4))) float f32x4;

__device__ __forceinline__ float bf2f(u16 v) {
    union { u32 u; float f; } c; c.u = ((u32)v) << 16; return c.f;
}
__device__ __forceinline__ u16 f2bf(float f) {
    union { float f; u32 u; } c; c.f = f;
    u32 u = c.u;
    return (u16)((u + 0x7FFFu + ((u >> 16) & 1u)) >> 16); // RNE
}
__device__ __forceinline__ u32 pack2(float lo, float hi) {
    return (u32)f2bf(lo) | ((u32)f2bf(hi) << 16);
}
__device__ __forceinline__ float tanh_fast(float x) {
    return 1.f - 2.f / (__expf(2.f * x) + 1.f);
}

// ================= proj (both node types): h = bf16(x @ W + b) via MFMA =================
__global__ __launch_bounds__(256) void proj_both(
    const float* __restrict__ x_c, const float* __restrict__ W_c, const float* __restrict__ b_c,
    const float* __restrict__ x_p, const float* __restrict__ W_p, const float* __restrict__ b_p,
    u16* __restrict__ out_c, u16* __restrict__ out_p)
{
    const float* x; const float* W; const float* b; u16* h; int N;
    if (blockIdx.y == 0) { x = x_c; W = W_c; b = b_c; h = out_c; N = NC; }
    else                 { x = x_p; W = W_p; b = b_p; h = out_p; N = NP; }
    size_t row0 = (size_t)blockIdx.x * 64;
    if (row0 >= (size_t)N) return;
    __shared__ alignas(16) u16 sBT[128 * 72];
    __shared__ alignas(16) u16 sA[64 * 72];
    int t = threadIdx.x;
    for (int i = t; i < 128 * 8; i += 256) {
        int n = i & 127, kb = i >> 7;
        u32 p[4];
#pragma unroll
        for (int j = 0; j < 4; ++j)
            p[j] = pack2(W[(kb * 8 + 2 * j) * 128 + n], W[(kb * 8 + 2 * j + 1) * 128 + n]);
        *(uint4*)(&sBT[n * 72 + kb * 8]) = make_uint4(p[0], p[1], p[2], p[3]);
    }
    for (int i = t; i < 64 * 8; i += 256) {
        int r = i >> 3, c8 = (i & 7) * 8;
        u32 p[4];
        if (row0 + r < (size_t)N) {
            const float* src = x + (row0 + r) * 64 + c8;
            float4 v0 = *(const float4*)src;
            float4 v1 = *(const float4*)(src + 4);
            p[0] = pack2(v0.x, v0.y); p[1] = pack2(v0.z, v0.w);
            p[2] = pack2(v1.x, v1.y); p[3] = pack2(v1.z, v1.w);
        } else { p[0] = p[1] = p[2] = p[3] = 0; }
        *(uint4*)(&sA[r * 72 + c8]) = make_uint4(p[0], p[1], p[2], p[3]);
    }
    __syncthreads();
    int wave = t >> 6, lane = t & 63;
    int fr = lane & 15, fq = lane >> 4;
    const u16* pA = sA + (wave * 16 + fr) * 72 + fq * 8;
    const u16* pB = sBT + fr * 72 + fq * 8;
    f32x4 acc[8];
#pragma unroll
    for (int nt = 0; nt < 8; ++nt) { float bb = b[nt * 16 + fr]; acc[nt] = (f32x4){bb, bb, bb, bb}; }
#pragma unroll
    for (int ks = 0; ks < 2; ++ks) {
        short8v a = *(const short8v*)(pA + ks * 32);
#pragma unroll
        for (int nt = 0; nt < 8; ++nt) {
            short8v bv = *(const short8v*)(pB + nt * 16 * 72 + ks * 32);
            acc[nt] = __builtin_amdgcn_mfma_f32_16x16x32_bf16(a, bv, acc[nt], 0, 0, 0);
        }
    }
    size_t rbase = row0 + wave * 16 + fq * 4;
#pragma unroll
    for (int nt = 0; nt < 8; ++nt) {
        int col = nt * 16 + fr;
#pragma unroll
        for (int rg = 0; rg < 4; ++rg) {
            size_t rr = rbase + rg;
            if (rr < (size_t)N) h[rr * 128 + col] = f2bf(acc[nt][rg]);
        }
    }
}

// ================= per-head attention logits (both node types) =================
__global__ __launch_bounds__(256) void logit_both(
    const u16* __restrict__ h_c, const float* __restrict__ a_cp_s, float* __restrict__ al_c,
    const u16* __restrict__ h_p, const float* __restrict__ a_cp_d,
    const float* __restrict__ a_pp_s, const float* __restrict__ a_pp_d,
    float* __restrict__ al_dcp, float* __restrict__ al_spp, float* __restrict__ al_dpp)
{
    int t = threadIdx.x;
    int head = t & 7;
    size_t row = (size_t)blockIdx.x * 32 + (t >> 3);
    if (blockIdx.y == 0) {
        if (row >= NC) return;
        const u16* hp = h_c + row * 128 + head * 16;
        uint4 u0_ = *(const uint4*)hp;
        uint4 u1_ = *(const uint4*)(hp + 8);
        u32 uu[8] = {u0_.x, u0_.y, u0_.z, u0_.w, u1_.x, u1_.y, u1_.z, u1_.w};
        float p0 = 0.f;
#pragma unroll
        for (int j = 0; j < 8; ++j) {
            float lo = bf2f((u16)(uu[j] & 0xFFFFu));
            float hi = bf2f((u16)(uu[j] >> 16));
            p0 += lo * a_cp_s[head * 16 + 2 * j] + hi * a_cp_s[head * 16 + 2 * j + 1];
        }
        al_c[row * 8 + head] = p0;
    } else {
        if (row >= NP) return;
        const u16* hp = h_p + row * 128 + head * 16;
        uint4 u0_ = *(const uint4*)hp;
        uint4 u1_ = *(const uint4*)(hp + 8);
        u32 uu[8] = {u0_.x, u0_.y, u0_.z, u0_.w, u1_.x, u1_.y, u1_.z, u1_.w};
        float p0 = 0.f, p1 = 0.f, p2 = 0.f;
#pragma unroll
        for (int j = 0; j < 8; ++j) {
            float lo = bf2f((u16)(uu[j] & 0xFFFFu));
            float hi = bf2f((u16)(uu[j] >> 16));
            p0 += lo * a_cp_d[head * 16 + 2 * j] + hi * a_cp_d[head * 16 + 2 * j + 1];
            p1 += lo * a_pp_s[head * 16 + 2 * j] + hi * a_pp_s[head * 16 + 2 * j + 1];
            p2 += lo * a_pp_d[head * 16 + 2 * j] + hi * a_pp_d[head * 16 + 2 * j + 1];
        }
        al_dcp[row * 8 + head] = p0;
        al_spp[row * 8 + head] = p1;
        al_dpp[row * 8 + head] = p2;
    }
}

// ================= combined CSR build over 2*NP dst nodes =================
__global__ __launch_bounds__(256) void hist2(const int* __restrict__ dpp, const int* __restrict__ dcp,
                                             int* __restrict__ cnt)
{
    int e = blockIdx.x * 256 + threadIdx.x;
    if (e >= NE) return;
    if (blockIdx.y == 0) atomicAdd(&cnt[dpp[e]], 1);
    else                 atomicAdd(&cnt[NP + dcp[e]], 1);
}

// per-block sums of 2048 counts
__global__ __launch_bounds__(256) void scan2_B(const int* __restrict__ cnt, int* __restrict__ bsums)
{
    __shared__ int red[256];
    int t = threadIdx.x;
    int base = blockIdx.x * 2048 + t * 8;
    int s = 0;
#pragma unroll
    for (int j = 0; j < 8; ++j) { int i = base + j; if (i < NN2) s += cnt[i]; }
    red[t] = s;
    __syncthreads();
    for (int off = 128; off >= 1; off >>= 1) {
        if (t < off) red[t] += red[t + off];
        __syncthreads();
    }
    if (t == 0) bsums[blockIdx.x] = red[0];
}

__global__ __launch_bounds__(256) void scan2_C(int* __restrict__ bsums, int* __restrict__ row_ptr)
{
    __shared__ int sdata[256];
    int t = threadIdx.x;
    int v = (t < NBS2) ? bsums[t] : 0;
    sdata[t] = v;
    __syncthreads();
    for (int off = 1; off < 256; off <<= 1) {
        int x = (t >= off) ? sdata[t - off] : 0;
        __syncthreads();
        sdata[t] += x;
        __syncthreads();
    }
    if (t < NBS2) bsums[t] = sdata[t] - v; // exclusive
    if (t == 0) row_ptr[NN2] = 2 * NE;
}

__global__ __launch_bounds__(256) void scan2_D(const int* __restrict__ cnt, const int* __restrict__ bsums,
                                               int* __restrict__ row_ptr, int* __restrict__ cursor)
{
    __shared__ int sdata[256];
    int t = threadIdx.x;
    int base = blockIdx.x * 2048 + t * 8;
    int e[8];
    int s = 0;
#pragma unroll
    for (int j = 0; j < 8; ++j) {
        int i = base + j;
        e[j] = (i < NN2) ? cnt[i] : 0;
        s += e[j];
    }
    sdata[t] = s;
    __syncthreads();
    for (int off = 1; off < 256; off <<= 1) {
        int x = (t >= off) ? sdata[t - off] : 0;
        __syncthreads();
        sdata[t] += x;
        __syncthreads();
    }
    int run = bsums[blockIdx.x] + sdata[t] - s;
#pragma unroll
    for (int j = 0; j < 8; ++j) {
        int i = base + j;
        if (i < NN2) { row_ptr[i] = run; cursor[i] = run; }
        run += e[j];
    }
}

__global__ __launch_bounds__(256) void scatter2(const int* __restrict__ spp, const int* __restrict__ dpp,
                                                const int* __restrict__ scp, const int* __restrict__ dcp,
                                                int* __restrict__ cursor, int* __restrict__ perm)
{
    int e = blockIdx.x * 256 + threadIdx.x;
    if (e >= NE) return;
    int d2, src;
    if (blockIdx.y == 0) { d2 = dpp[e];      src = spp[e]; }
    else                 { d2 = NP + dcp[e]; src = scp[e]; }
    int pos = atomicAdd(&cursor[d2], 1);
    perm[pos] = src;
}

// ================= gather: 16 lanes/dst (4 dsts/wave), perm preload + pipelined loads ======
// acc = sum_e exp(leaky(al_e)) * h_src; scalar-normalize; write relu'd bf16.
__global__ __launch_bounds__(256) void gather2(
    const int* __restrict__ row_ptr, const int* __restrict__ perm,
    const float* __restrict__ als_pp, const float* __restrict__ ald_pp,
    const float* __restrict__ als_cp, const float* __restrict__ ald_cp,
    const u16* __restrict__ h_p, const u16* __restrict__ h_c,
    u16* __restrict__ r_pp, u16* __restrict__ r_cp)
{
    int d2 = blockIdx.x * 16 + (threadIdx.x >> 4);
    int lane = threadIdx.x & 63;
    int l16 = lane & 15;
    int grp = lane & 48;
    int head = l16 >> 1;   // 8 channels per lane, aligned within one 16-ch head pair
    const float* als; const float* ald; const u16* hs; u16* out; int d;
    if (d2 < NP) { d = d2;      als = als_pp; ald = ald_pp; hs = h_p; out = r_pp; }
    else         { d = d2 - NP; als = als_cp; ald = ald_cp; hs = h_c; out = r_cp; }
    int beg = row_ptr[d2], end = row_ptr[d2 + 1];
    int n = end - beg;
    float ald_h = ald[(size_t)d * 8 + head];
    float dsum = 0.f;
    float acc[8] = {0.f, 0.f, 0.f, 0.f, 0.f, 0.f, 0.f, 0.f};
    for (int base = 0; base < n; base += 16) {
        int cnt = min(16, n - base);
        int my = (base + l16 < n) ? perm[beg + base + l16] : 0;
        int src = __shfl(my, grp, 64);
        float a_next = als[(size_t)src * 8 + head];
        uint4 hv_next = *(const uint4*)(hs + (size_t)src * 128 + l16 * 8);
        for (int j = 0; j < cnt; ++j) {
            float a_cur = a_next;
            uint4 hv = hv_next;
            if (j + 1 < cnt) {
                int s2 = __shfl(my, grp + j + 1, 64);
                a_next = als[(size_t)s2 * 8 + head];
                hv_next = *(const uint4*)(hs + (size_t)s2 * 128 + l16 * 8);
            }
            float a = a_cur + ald_h;
            a = a >= 0.f ? a : 0.2f * a;
            float w = __expf(a);
            dsum += w;
            u32 uu[4] = {hv.x, hv.y, hv.z, hv.w};
#pragma unroll
            for (int q = 0; q < 4; ++q) {
                acc[2 * q]     = fmaf(bf2f((u16)(uu[q] & 0xFFFFu)), w, acc[2 * q]);
                acc[2 * q + 1] = fmaf(bf2f((u16)(uu[q] >> 16)),     w, acc[2 * q + 1]);
            }
        }
    }
    float inv = 1.f / (dsum + 1e-16f);
    uint4 o;
    o.x = pack2(fmaxf(acc[0] * inv, 0.f), fmaxf(acc[1] * inv, 0.f));
    o.y = pack2(fmaxf(acc[2] * inv, 0.f), fmaxf(acc[3] * inv, 0.f));
    o.z = pack2(fmaxf(acc[4] * inv, 0.f), fmaxf(acc[5] * inv, 0.f));
    o.w = pack2(fmaxf(acc[6] * inv, 0.f), fmaxf(acc[7] * inv, 0.f));
    *(uint4*)(out + (size_t)d * 128 + l16 * 8) = o;
}

// ================= sem: per-block col-sums of tanh(r_m @ Wk + bk) =================
__global__ __launch_bounds__(256) void sem_mfma(
    const u16* __restrict__ r0, const u16* __restrict__ r1,
    const float* __restrict__ Wk, const float* __restrict__ bk,
    float* __restrict__ part)   // [2][3125][128]
{
    __shared__ alignas(16) u16 sBT[128 * 136];
    __shared__ alignas(16) u16 sA[64 * 136];
    __shared__ float red[4][128];
    int t = threadIdx.x;
    const u16* src = blockIdx.y ? r1 : r0;
    for (int i = t; i < 128 * 16; i += 256) {
        int n = i & 127, kb = i >> 7;
        u32 p[4];
#pragma unroll
        for (int j = 0; j < 4; ++j)
            p[j] = pack2(Wk[(kb * 8 + 2 * j) * 128 + n], Wk[(kb * 8 + 2 * j + 1) * 128 + n]);
        *(uint4*)(&sBT[n * 136 + kb * 8]) = make_uint4(p[0], p[1], p[2], p[3]);
    }
    size_t row0 = (size_t)blockIdx.x * 64;
    for (int i = t; i < 64 * 16; i += 256) {
        int r = i >> 4, c8 = (i & 15) * 8;
        *(uint4*)(&sA[r * 136 + c8]) = *(const uint4*)(src + (row0 + r) * 128 + c8);
    }
    __syncthreads();
    int wave = t >> 6, lane = t & 63;
    int fr = lane & 15, fq = lane >> 4;
    const u16* pA = sA + (wave * 16 + fr) * 136 + fq * 8;
    const u16* pB = sBT + fr * 136 + fq * 8;
    f32x4 acc[8];
#pragma unroll
    for (int nt = 0; nt < 8; ++nt) { float bb = bk[nt * 16 + fr]; acc[nt] = (f32x4){bb, bb, bb, bb}; }
#pragma unroll
    for (int ks = 0; ks < 4; ++ks) {
        short8v a = *(const short8v*)(pA + ks * 32);
#pragma unroll
        for (int nt = 0; nt < 8; ++nt) {
            short8v bv = *(const short8v*)(pB + nt * 16 * 136 + ks * 32);
            acc[nt] = __builtin_amdgcn_mfma_f32_16x16x32_bf16(a, bv, acc[nt], 0, 0, 0);
        }
    }
#pragma unroll
    for (int nt = 0; nt < 8; ++nt) {
        f32x4 v = acc[nt];
        float s = tanh_fast(v[0]) + tanh_fast(v[1]) + tanh_fast(v[2]) + tanh_fast(v[3]);
        s += __shfl_xor(s, 16, 64);
        s += __shfl_xor(s, 32, 64);
        if (lane < 16) red[wave][nt * 16 + lane] = s;
    }
    __syncthreads();
    if (t < 128) {
        float s = red[0][t] + red[1][t] + red[2][t] + red[3][t];
        part[((size_t)blockIdx.y * gridDim.x + blockIdx.x) * 128 + t] = s;
    }
}

// ================= sem partial-dot =================
__global__ __launch_bounds__(256) void sem_dot(const float* __restrict__ part,
                                               const float* __restrict__ q, float* __restrict__ vsum)
{
    __shared__ float sq_[128];
    __shared__ float red[256];
    int t = threadIdx.x;
    if (t < 128) sq_[t] = q[t];
    __syncthreads();
    int c = t & 127, m = t >> 7;
    int i0 = blockIdx.x * 98;
    int i1 = i0 + 98; if (i1 > 3125) i1 = 3125;
    float acc = 0.f;
    for (int i = i0; i < i1; ++i)
        acc += part[((size_t)m * 3125 + i) * 128 + c] * sq_[c];
    red[t] = acc;
    __syncthreads();
    for (int off = 64; off >= 1; off >>= 1) {
        if ((t & 127) < off) red[t] += red[t + off];
        __syncthreads();
    }
    if ((t & 127) == 0) atomicAdd(&vsum[m], red[t]);
}

__global__ void attn2_kernel(const float* __restrict__ vsum, float* __restrict__ attn)
{
    if (threadIdx.x == 0) {
        float v0 = vsum[0] / (float)NP, v1 = vsum[1] / (float)NP;
        float mx = fmaxf(v0, v1);
        float e0 = __expf(v0 - mx), e1 = __expf(v1 - mx);
        float is = 1.f / (e0 + e1);
        attn[0] = e0 * is;
        attn[1] = e1 * is;
    }
}

// ================= MLP1: z1 = (a0*r_cp + a1*r_pp) @ W1 + b1, bf16 out + BN partials =======
__global__ __launch_bounds__(256) void mlp1_mfma(
    const u16* __restrict__ rcp, const u16* __restrict__ rpp, const float* __restrict__ attn,
    const float* __restrict__ W1, const float* __restrict__ b1,
    u16* __restrict__ z1, float* __restrict__ pS, float* __restrict__ pQ)
{
    __shared__ alignas(16) u16 sBT[128 * 136];
    __shared__ alignas(16) u16 sA[64 * 136];
    __shared__ float redS[4][128];
    __shared__ float redQ[4][128];
    int t = threadIdx.x;
    float a0 = attn[0], a1 = attn[1];
    for (int i = t; i < 128 * 16; i += 256) {
        int n = i & 127, kb = i >> 7;
        u32 p[4];
#pragma unroll
        for (int j = 0; j < 4; ++j)
            p[j] = pack2(W1[(kb * 8 + 2 * j) * 128 + n], W1[(kb * 8 + 2 * j + 1) * 128 + n]);
        *(uint4*)(&sBT[n * 136 + kb * 8]) = make_uint4(p[0], p[1], p[2], p[3]);
    }
    size_t row0 = (size_t)blockIdx.x * 64;
    for (int i = t; i < 64 * 16; i += 256) {
        int r = i >> 4, c8 = (i & 15) * 8;
        size_t g = (row0 + r) * 128 + c8;
        uint4 uc = *(const uint4*)(rcp + g);
        uint4 up = *(const uint4*)(rpp + g);
        u32 uuc[4] = {uc.x, uc.y, uc.z, uc.w};
        u32 uup[4] = {up.x, up.y, up.z, up.w};
        u32 p[4];
#pragma unroll
        for (int j = 0; j < 4; ++j) {
            float lo = a0 * bf2f((u16)(uuc[j] & 0xFFFFu)) + a1 * bf2f((u16)(uup[j] & 0xFFFFu));
            float hi = a0 * bf2f((u16)(uuc[j] >> 16))     + a1 * bf2f((u16)(uup[j] >> 16));
            p[j] = pack2(lo, hi);
        }
        *(uint4*)(&sA[r * 136 + c8]) = make_uint4(p[0], p[1], p[2], p[3]);
    }
    __syncthreads();
    int wave = t >> 6, lane = t & 63;
    int fr = lane & 15, fq = lane >> 4;
    const u16* pA = sA + (wave * 16 + fr) * 136 + fq * 8;
    const u16* pB = sBT + fr * 136 + fq * 8;
    f32x4 acc[8];
#pragma unroll
    for (int nt = 0; nt < 8; ++nt) { float bb = b1[nt * 16 + fr]; acc[nt] = (f32x4){bb, bb, bb, bb}; }
#pragma unroll
    for (int ks = 0; ks < 4; ++ks) {
        short8v a = *(const short8v*)(pA + ks * 32);
#pragma unroll
        for (int nt = 0; nt < 8; ++nt) {
            short8v bv = *(const short8v*)(pB + nt * 16 * 136 + ks * 32);
            acc[nt] = __builtin_amdgcn_mfma_f32_16x16x32_bf16(a, bv, acc[nt], 0, 0, 0);
        }
    }
    size_t rbase = row0 + wave * 16 + fq * 4;
#pragma unroll
    for (int nt = 0; nt < 8; ++nt) {
        f32x4 v = acc[nt];
        int col = nt * 16 + fr;
#pragma unroll
        for (int rg = 0; rg < 4; ++rg)
            z1[(rbase + rg) * 128 + col] = f2bf(v[rg]);
        float s = v[0] + v[1] + v[2] + v[3];
        float qq = v[0] * v[0] + v[1] * v[1] + v[2] * v[2] + v[3] * v[3];
        s += __shfl_xor(s, 16, 64);  s += __shfl_xor(s, 32, 64);
        qq += __shfl_xor(qq, 16, 64); qq += __shfl_xor(qq, 32, 64);
        if (lane < 16) { redS[wave][col] = s; redQ[wave][col] = qq; }
    }
    __syncthreads();
    if (t < 128) {
        pS[(size_t)blockIdx.x * 128 + t] = redS[0][t] + redS[1][t] + redS[2][t] + redS[3][t];
        pQ[(size_t)blockIdx.x * 128 + t] = redQ[0][t] + redQ[1][t] + redQ[2][t] + redQ[3][t];
    }
}

// ================= reduce BN partials [3125][C] -> sum/sq =================
__global__ __launch_bounds__(256) void stat_reduce(
    const float* __restrict__ pS, const float* __restrict__ pQ,
    float* __restrict__ sum, float* __restrict__ sq, int C)
{
    __shared__ float redS[256], redQ[256];
    int t = threadIdx.x;
    int c = t & (C - 1);
    int sub = t / C;
    int stride = 256 / C;
    int i0 = blockIdx.x * 125, i1 = i0 + 125;
    float s = 0.f, q = 0.f;
    for (int i = i0 + sub; i < i1; i += stride) {
        s += pS[(size_t)i * C + c];
        q += pQ[(size_t)i * C + c];
    }
    redS[t] = s; redQ[t] = q;
    __syncthreads();
    if (t < C) {
        for (int k = 1; k < stride; ++k) { s += redS[t + k * C]; q += redQ[t + k * C]; }
        atomicAdd(&sum[c], s);
        atomicAdd(&sq[c], q);
    }
}

// ================= BN finalize =================
__global__ void bn_fin(const float* __restrict__ sum, const float* __restrict__ sq,
                       const float* __restrict__ g, const float* __restrict__ be,
                       float* __restrict__ scale, float* __restrict__ shift, int C, float invN)
{
    int c = threadIdx.x;
    if (c >= C) return;
    float mu = sum[c] * invN;
    float var = sq[c] * invN - mu * mu;
    float sc = g[c] * rsqrtf(var + 1e-5f);
    scale[c] = sc;
    shift[c] = be[c] - mu * sc;
}

// ================= MLP2: z2 = relu(bn(z1)) @ W2 + b2, f32 out + BN partials =================
__global__ __launch_bounds__(256) void mlp2_mfma(
    const u16* __restrict__ z1, const float* __restrict__ scale1, const float* __restrict__ shift1,
    const float* __restrict__ W2, const float* __restrict__ b2,
    float* __restrict__ z2, float* __restrict__ pS, float* __restrict__ pQ)
{
    __shared__ alignas(16) u16 sBT[64 * 136];
    __shared__ alignas(16) u16 sA[64 * 136];
    __shared__ float sSc[128], sSh[128];
    __shared__ float redS[4][64], redQ[4][64];
    int t = threadIdx.x;
    if (t < 128) { sSc[t] = scale1[t]; sSh[t] = shift1[t]; }
    for (int i = t; i < 64 * 16; i += 256) {
        int n = i & 63, kb = i >> 6;
        u32 p[4];
#pragma unroll
        for (int j = 0; j < 4; ++j)
            p[j] = pack2(W2[(kb * 8 + 2 * j) * 64 + n], W2[(kb * 8 + 2 * j + 1) * 64 + n]);
        *(uint4*)(&sBT[n * 136 + kb * 8]) = make_uint4(p[0], p[1], p[2], p[3]);
    }
    __syncthreads();
    size_t row0 = (size_t)blockIdx.x * 64;
    for (int i = t; i < 64 * 16; i += 256) {
        int r = i >> 4, c8 = (i & 15) * 8;
        uint4 up = *(const uint4*)(z1 + (row0 + r) * 128 + c8);
        u32 uu[4] = {up.x, up.y, up.z, up.w};
        u32 p[4];
#pragma unroll
        for (int j = 0; j < 4; ++j) {
            int c = c8 + 2 * j;
            float lo = fmaxf(bf2f((u16)(uu[j] & 0xFFFFu)) * sSc[c] + sSh[c], 0.f);
            float hi = fmaxf(bf2f((u16)(uu[j] >> 16)) * sSc[c + 1] + sSh[c + 1], 0.f);
            p[j] = pack2(lo, hi);
        }
        *(uint4*)(&sA[r * 136 + c8]) = make_uint4(p[0], p[1], p[2], p[3]);
    }
    __syncthreads();
    int wave = t >> 6, lane = t & 63;
    int fr = lane & 15, fq = lane >> 4;
    const u16* pA = sA + (wave * 16 + fr) * 136 + fq * 8;
    const u16* pB = sBT + fr * 136 + fq * 8;
    f32x4 acc[4];
#pragma unroll
    for (int nt = 0; nt < 4; ++nt) { float bb = b2[nt * 16 + fr]; acc[nt] = (f32x4){bb, bb, bb, bb}; }
#pragma unroll
    for (int ks = 0; ks < 4; ++ks) {
        short8v a = *(const short8v*)(pA + ks * 32);
#pragma unroll
        for (int nt = 0; nt < 4; ++nt) {
            short8v bv = *(const short8v*)(pB + nt * 16 * 136 + ks * 32);
            acc[nt] = __builtin_amdgcn_mfma_f32_16x16x32_bf16(a, bv, acc[nt], 0, 0, 0);
        }
    }
    size_t rbase = row0 + wave * 16 + fq * 4;
#pragma unroll
    for (int nt = 0; nt < 4; ++nt) {
        f32x4 v = acc[nt];
        int col = nt * 16 + fr;
#pragma unroll
        for (int rg = 0; rg < 4; ++rg)
            z2[(rbase + rg) * 64 + col] = v[rg];
        float s = v[0] + v[1] + v[2] + v[3];
        float qq = v[0] * v[0] + v[1] * v[1] + v[2] * v[2] + v[3] * v[3];
        s += __shfl_xor(s, 16, 64);  s += __shfl_xor(s, 32, 64);
        qq += __shfl_xor(qq, 16, 64); qq += __shfl_xor(qq, 32, 64);
        if (lane < 16) { redS[wave][col] = s; redQ[wave][col] = qq; }
    }
    __syncthreads();
    if (t < 64) {
        pS[(size_t)blockIdx.x * 64 + t] = redS[0][t] + redS[1][t] + redS[2][t] + redS[3][t];
        pQ[(size_t)blockIdx.x * 64 + t] = redQ[0][t] + redQ[1][t] + redQ[2][t] + redQ[3][t];
    }
}

// ================= final: sigmoid(relu(bn(z2)) @ W3 + b3) =================
__global__ __launch_bounds__(64) void final_kernel(
    const float* __restrict__ z2, const float* __restrict__ scale2, const float* __restrict__ shift2,
    const float* __restrict__ W3, const float* __restrict__ b3, float* __restrict__ out)
{
    __shared__ float sh[64][65];
    __shared__ float sw[64];
    int t = threadIdx.x; // 64
    size_t row0 = (size_t)blockIdx.x * 64;
    sw[t] = W3[t];
    for (int j = 0; j < 64; ++j) {
        float v = z2[(row0 + j) * 64 + t] * scale2[t] + shift2[t];
        sh[j][t] = v > 0.f ? v : 0.f;
    }
    __syncthreads();
    float acc = b3[0];
#pragma unroll 16
    for (int k = 0; k < 64; ++k) acc = fmaf(sh[t][k], sw[k], acc);
    out[row0 + t] = 1.f / (1.f + __expf(-acc));
}

extern "C" void kernel_launch(void* const* d_in, const int* in_sizes, int n_in,
                              void* d_out, int out_size, void* d_ws, size_t ws_size,
                              hipStream_t stream) {
    const float* x_c      = (const float*)d_in[0];
    const float* x_p      = (const float*)d_in[1];
    const int*   e_src_cp = (const int*)d_in[2];
    const int*   e_dst_cp = (const int*)d_in[3];
    const int*   e_src_pp = (const int*)d_in[4];
    const int*   e_dst_pp = (const int*)d_in[5];
    const float* W_c      = (const float*)d_in[6];
    const float* b_c      = (const float*)d_in[7];
    const float* W_p      = (const float*)d_in[8];
    const float* b_p      = (const float*)d_in[9];
    const float* a_src_cp = (const float*)d_in[10];
    const float* a_dst_cp = (const float*)d_in[11];
    const float* a_src_pp = (const float*)d_in[12];
    const float* a_dst_pp = (const float*)d_in[13];
    const float* Wk       = (const float*)d_in[14];
    const float* bk       = (const float*)d_in[15];
    const float* q_sem    = (const float*)d_in[16];
    const float* W1       = (const float*)d_in[17];
    const float* b1       = (const float*)d_in[18];
    const float* g1       = (const float*)d_in[19];
    const float* be1      = (const float*)d_in[20];
    const float* W2       = (const float*)d_in[21];
    const float* b2       = (const float*)d_in[22];
    const float* g2       = (const float*)d_in[23];
    const float* be2      = (const float*)d_in[24];
    const float* W3       = (const float*)d_in[25];
    const float* b3       = (const float*)d_in[26];

    // ---- byte-offset workspace layout (extent 212,809,472 B; 213,609,472 proven OK) ----
    char* ws = (char*)d_ws;
    u16*   h_p    = (u16*)  (ws +          0);  // 51,200,000
    u16*   h_c    = (u16*)  (ws +  51200000);   // 25,600,000
    float* al_c   = (float*)(ws +  76800000);   //  3,200,000
    float* al_dcp = (float*)(ws +  80000000);   //  6,400,000
    float* al_spp = (float*)(ws +  86400000);
    float* al_dpp = (float*)(ws +  92800000);
    int*   row_ptr= (int*)  (ws +  99200000);   // (2NP+1)*4 padded -> 100,800,256
    int*   cnt    = (int*)  (ws + 100800256);   // 2NP*4 = 1,600,000 (doubles as cursor)
    int*   bsums  = (int*)  (ws + 102400256);   // 1024
    int*   perm   = (int*)  (ws + 102401280);   // 2NE*4 = 8,000,000 -> 110,401,280
    u16*   r_pp   = (u16*)  (ws + 110401280);   // NP*128 bf16 = 51,200,000
    u16*   r_cp   = (u16*)  (ws + 161601280);   // NP*128 bf16 = 51,200,000 -> 212,801,280
    float* small  = (float*)(ws + 212801280);   // 8192

    // overlays on CSR region (dead after gather2):
    float* semPart= (float*)(ws +  99200000);   // 2*3125*128*4 = 3,200,000 (dead before mlp2)
    float* statS  = (float*)(ws + 102400000);   // 1,600,000
    float* statQ  = (float*)(ws + 104000000);   // 1,600,000

    float* vsum   = small;        // 2
    float* attn   = small + 64;   // 2
    float* sum1   = small + 128;  // 128
    float* sq1    = small + 256;  // 128
    float* sum2   = small + 384;  // 64
    float* sq2    = small + 448;  // 64
    float* scale1 = small + 512;  // 128
    float* shift1 = small + 640;  // 128
    float* scale2 = small + 768;  // 64
    float* shift2 = small + 832;  // 64

    // aliases over dead regions
    u16*   z1 = h_p;                     // bf16 NP*128 at [0,51.2M): h_p dead after gather
    float* z2 = (float*)(ws + 51200000); // f32 NP*64 at [51.2M,102.4M): h_c/al/CSR dead by MLP2

    hipMemsetAsync(small, 0, 8192, stream);
    hipMemsetAsync(cnt, 0, NN2 * 4, stream);

    // projections (MFMA) + per-head logits, both node types in one dispatch each
    {
        dim3 g(NP / 64, 2);
        proj_both<<<g, 256, 0, stream>>>(x_c, W_c, b_c, x_p, W_p, b_p, h_c, h_p);
    }
    {
        dim3 g(NP / 32, 2);
        logit_both<<<g, 256, 0, stream>>>(h_c, a_src_cp, al_c,
                                          h_p, a_dst_cp, a_src_pp, a_dst_pp,
                                          al_dcp, al_spp, al_dpp);
    }

    // ---- combined CSR over both metapaths (2*NP dst nodes, 2*NE edges) ----
    const int GE = (NE + 255) / 256;
    {
        dim3 g(GE, 2);
        hist2<<<g, 256, 0, stream>>>(e_dst_pp, e_dst_cp, cnt);
    }
    scan2_B<<<NBS2, 256, 0, stream>>>(cnt, bsums);
    scan2_C<<<1, 256, 0, stream>>>(bsums, row_ptr);
    scan2_D<<<NBS2, 256, 0, stream>>>(cnt, bsums, row_ptr, cnt); // cnt becomes cursor
    {
        dim3 g(GE, 2);
        scatter2<<<g, 256, 0, stream>>>(e_src_pp, e_dst_pp, e_src_cp, e_dst_cp, cnt, perm);
    }
    gather2<<<NN2 / 16, 256, 0, stream>>>(row_ptr, perm,
                                          al_spp, al_dpp, al_c, al_dcp,
                                          h_p, h_c, r_pp, r_cp);

    // semantic attention
    {
        dim3 gs(NP / 64, 2);
        sem_mfma<<<gs, 256, 0, stream>>>(r_cp, r_pp, Wk, bk, semPart);
    }
    sem_dot<<<32, 256, 0, stream>>>(semPart, q_sem, vsum);
    attn2_kernel<<<1, 64, 0, stream>>>(vsum, attn);

    // MLP + BN
    mlp1_mfma<<<NP / 64, 256, 0, stream>>>(r_cp, r_pp, attn, W1, b1, z1, statS, statQ);
    stat_reduce<<<25, 256, 0, stream>>>(statS, statQ, sum1, sq1, 128);
    bn_fin<<<1, 128, 0, stream>>>(sum1, sq1, g1, be1, scale1, shift1, 128, 1.f / (float)NP);
    mlp2_mfma<<<NP / 64, 256, 0, stream>>>(z1, scale1, shift1, W2, b2, z2, statS, statQ);
    stat_reduce<<<25, 256, 0, stream>>>(statS, statQ, sum2, sq2, 64);
    bn_fin<<<1, 128, 0, stream>>>(sum2, sq2, g2, be2, scale2, shift2, 64, 1.f / (float)NP);
    final_kernel<<<NP / 64, 64, 0, stream>>>(z2, scale2, shift2, W3, b3, (float*)d_out);
}

// Round 7
// 490.492 us; speedup vs baseline: 11.9972x; 1.3615x over previous
//
#include <hip/hip_runtime.h>
#include <hip/hip_bf16.h>

#define NC 100000
#define NP 200000
#define NE 1000000
#define NN2 (2 * NP)      // combined dst-node space (pp then cp)
#define NBUK 391          // ceil(NN2/1024)
#define ECHUNK 8192
#define NBLK_E 245        // ceil(2*NE/8192)

typedef unsigned short u16;
typedef unsigned int u32;
typedef unsigned long long u64;
typedef __attribute__((ext_vector_type(8))) short short8v;  // 8 bf16 (4 VGPRs)
typedef __attribute__((ext_vector_type(4))) float f32x4;

__device__ __forceinline__ float bf2f(u16 v) {
    union { u32 u; float f; } c; c.u = ((u32)v) << 16; return c.f;
}
__device__ __forceinline__ u16 f2bf(float f) {
    union { float f; u32 u; } c; c.f = f;
    u32 u = c.u;
    return (u16)((u + 0x7FFFu + ((u >> 16) & 1u)) >> 16); // RNE
}
__device__ __forceinline__ u32 pack2(float lo, float hi) {
    return (u32)f2bf(lo) | ((u32)f2bf(hi) << 16);
}
__device__ __forceinline__ float tanh_fast(float x) {
    return 1.f - 2.f / (__expf(2.f * x) + 1.f);
}

// ================= proj (both node types): h = bf16(x @ W + b) via MFMA =================
__global__ __launch_bounds__(256) void proj_both(
    const float* __restrict__ x_c, const float* __restrict__ W_c, const float* __restrict__ b_c,
    const float* __restrict__ x_p, const float* __restrict__ W_p, const float* __restrict__ b_p,
    u16* __restrict__ out_c, u16* __restrict__ out_p)
{
    const float* x; const float* W; const float* b; u16* h; int N;
    if (blockIdx.y == 0) { x = x_c; W = W_c; b = b_c; h = out_c; N = NC; }
    else                 { x = x_p; W = W_p; b = b_p; h = out_p; N = NP; }
    size_t row0 = (size_t)blockIdx.x * 64;
    if (row0 >= (size_t)N) return;
    __shared__ alignas(16) u16 sBT[128 * 72];
    __shared__ alignas(16) u16 sA[64 * 72];
    int t = threadIdx.x;
    for (int i = t; i < 128 * 8; i += 256) {
        int n = i & 127, kb = i >> 7;
        u32 p[4];
#pragma unroll
        for (int j = 0; j < 4; ++j)
            p[j] = pack2(W[(kb * 8 + 2 * j) * 128 + n], W[(kb * 8 + 2 * j + 1) * 128 + n]);
        *(uint4*)(&sBT[n * 72 + kb * 8]) = make_uint4(p[0], p[1], p[2], p[3]);
    }
    for (int i = t; i < 64 * 8; i += 256) {
        int r = i >> 3, c8 = (i & 7) * 8;
        u32 p[4];
        if (row0 + r < (size_t)N) {
            const float* src = x + (row0 + r) * 64 + c8;
            float4 v0 = *(const float4*)src;
            float4 v1 = *(const float4*)(src + 4);
            p[0] = pack2(v0.x, v0.y); p[1] = pack2(v0.z, v0.w);
            p[2] = pack2(v1.x, v1.y); p[3] = pack2(v1.z, v1.w);
        } else { p[0] = p[1] = p[2] = p[3] = 0; }
        *(uint4*)(&sA[r * 72 + c8]) = make_uint4(p[0], p[1], p[2], p[3]);
    }
    __syncthreads();
    int wave = t >> 6, lane = t & 63;
    int fr = lane & 15, fq = lane >> 4;
    const u16* pA = sA + (wave * 16 + fr) * 72 + fq * 8;
    const u16* pB = sBT + fr * 72 + fq * 8;
    f32x4 acc[8];
#pragma unroll
    for (int nt = 0; nt < 8; ++nt) { float bb = b[nt * 16 + fr]; acc[nt] = (f32x4){bb, bb, bb, bb}; }
#pragma unroll
    for (int ks = 0; ks < 2; ++ks) {
        short8v a = *(const short8v*)(pA + ks * 32);
#pragma unroll
        for (int nt = 0; nt < 8; ++nt) {
            short8v bv = *(const short8v*)(pB + nt * 16 * 72 + ks * 32);
            acc[nt] = __builtin_amdgcn_mfma_f32_16x16x32_bf16(a, bv, acc[nt], 0, 0, 0);
        }
    }
    size_t rbase = row0 + wave * 16 + fq * 4;
#pragma unroll
    for (int nt = 0; nt < 8; ++nt) {
        int col = nt * 16 + fr;
#pragma unroll
        for (int rg = 0; rg < 4; ++rg) {
            size_t rr = rbase + rg;
            if (rr < (size_t)N) h[rr * 128 + col] = f2bf(acc[nt][rg]);
        }
    }
}

// ================= per-head attention logits (both node types) =================
__global__ __launch_bounds__(256) void logit_both(
    const u16* __restrict__ h_c, const float* __restrict__ a_cp_s, float* __restrict__ al_c,
    const u16* __restrict__ h_p, const float* __restrict__ a_cp_d,
    const float* __restrict__ a_pp_s, const float* __restrict__ a_pp_d,
    float* __restrict__ al_dcp, float* __restrict__ al_spp, float* __restrict__ al_dpp)
{
    int t = threadIdx.x;
    int head = t & 7;
    size_t row = (size_t)blockIdx.x * 32 + (t >> 3);
    if (blockIdx.y == 0) {
        if (row >= NC) return;
        const u16* hp = h_c + row * 128 + head * 16;
        uint4 u0_ = *(const uint4*)hp;
        uint4 u1_ = *(const uint4*)(hp + 8);
        u32 uu[8] = {u0_.x, u0_.y, u0_.z, u0_.w, u1_.x, u1_.y, u1_.z, u1_.w};
        float p0 = 0.f;
#pragma unroll
        for (int j = 0; j < 8; ++j) {
            float lo = bf2f((u16)(uu[j] & 0xFFFFu));
            float hi = bf2f((u16)(uu[j] >> 16));
            p0 += lo * a_cp_s[head * 16 + 2 * j] + hi * a_cp_s[head * 16 + 2 * j + 1];
        }
        al_c[row * 8 + head] = p0;
    } else {
        if (row >= NP) return;
        const u16* hp = h_p + row * 128 + head * 16;
        uint4 u0_ = *(const uint4*)hp;
        uint4 u1_ = *(const uint4*)(hp + 8);
        u32 uu[8] = {u0_.x, u0_.y, u0_.z, u0_.w, u1_.x, u1_.y, u1_.z, u1_.w};
        float p0 = 0.f, p1 = 0.f, p2 = 0.f;
#pragma unroll
        for (int j = 0; j < 8; ++j) {
            float lo = bf2f((u16)(uu[j] & 0xFFFFu));
            float hi = bf2f((u16)(uu[j] >> 16));
            p0 += lo * a_cp_d[head * 16 + 2 * j] + hi * a_cp_d[head * 16 + 2 * j + 1];
            p1 += lo * a_pp_s[head * 16 + 2 * j] + hi * a_pp_s[head * 16 + 2 * j + 1];
            p2 += lo * a_pp_d[head * 16 + 2 * j] + hi * a_pp_d[head * 16 + 2 * j + 1];
        }
        al_dcp[row * 8 + head] = p0;
        al_spp[row * 8 + head] = p1;
        al_dpp[row * 8 + head] = p2;
    }
}

// ================= bucketed CSR build =================
// B1: per-block LDS bucket histogram -> global bucket counts
__global__ __launch_bounds__(256) void bhist(const int* __restrict__ dpp, const int* __restrict__ dcp,
                                             int* __restrict__ bcnt)
{
    __shared__ int h[NBUK];
    int t = threadIdx.x;
    for (int i = t; i < NBUK; i += 256) h[i] = 0;
    __syncthreads();
    int base = blockIdx.x * ECHUNK;
    int lim = min(ECHUNK, 2 * NE - base);
    for (int i = t; i < lim; i += 256) {
        int e = base + i;
        int d2 = (e < NE) ? dpp[e] : NP + dcp[e - NE];
        atomicAdd(&h[d2 >> 10], 1);
    }
    __syncthreads();
    for (int i = t; i < NBUK; i += 256) if (h[i]) atomicAdd(&bcnt[i], h[i]);
}

// B2: exclusive scan of bucket counts (512 threads, 1 block)
__global__ __launch_bounds__(512) void bscan(const int* __restrict__ bcnt, int* __restrict__ bbase,
                                             int* __restrict__ bcur, int* __restrict__ row_ptr)
{
    __shared__ int s[512];
    int t = threadIdx.x;
    int v = (t < NBUK) ? bcnt[t] : 0;
    s[t] = v;
    __syncthreads();
    for (int off = 1; off < 512; off <<= 1) {
        int x = (t >= off) ? s[t - off] : 0;
        __syncthreads();
        s[t] += x;
        __syncthreads();
    }
    if (t < NBUK) { bbase[t] = s[t] - v; bcur[t] = s[t] - v; }
    if (t == 0) { bbase[NBUK] = 2 * NE; row_ptr[NN2] = 2 * NE; }
}

// B3: place edges into bucket-contiguous pairs array (block-local runs)
__global__ __launch_bounds__(256) void bplace(
    const int* __restrict__ spp, const int* __restrict__ dpp,
    const int* __restrict__ scp, const int* __restrict__ dcp,
    int* __restrict__ bcur, u64* __restrict__ pairs)
{
    __shared__ int h[NBUK];
    __shared__ int rk[NBUK];
    int t = threadIdx.x;
    for (int i = t; i < NBUK; i += 256) h[i] = 0;
    __syncthreads();
    int base = blockIdx.x * ECHUNK;
    int lim = min(ECHUNK, 2 * NE - base);
    for (int i = t; i < lim; i += 256) {
        int e = base + i;
        int d2 = (e < NE) ? dpp[e] : NP + dcp[e - NE];
        atomicAdd(&h[d2 >> 10], 1);
    }
    __syncthreads();
    for (int i = t; i < NBUK; i += 256) {
        int c = h[i];
        h[i] = c ? atomicAdd(&bcur[i], c) : 0;
        rk[i] = 0;
    }
    __syncthreads();
    for (int i = t; i < lim; i += 256) {
        int e = base + i;
        int d2, src;
        if (e < NE) { d2 = dpp[e];      src = spp[e]; }
        else        { d2 = NP + dcp[e - NE]; src = scp[e - NE]; }
        int b = d2 >> 10;
        int r = atomicAdd(&rk[b], 1);
        pairs[h[b] + r] = ((u64)(u32)d2 << 32) | (u32)src;
    }
}

// B4: per-bucket counting sort (one block per bucket, LDS cursors) -> row_ptr + perm
__global__ __launch_bounds__(256) void bsort(
    const u64* __restrict__ pairs, const int* __restrict__ bbase,
    int* __restrict__ row_ptr, int* __restrict__ perm)
{
    __shared__ int cnt[1024];
    __shared__ int sc[256];
    int b = blockIdx.x, t = threadIdx.x;
    int beg = bbase[b], end = bbase[b + 1];
    for (int i = t; i < 1024; i += 256) cnt[i] = 0;
    __syncthreads();
    for (int i = beg + t; i < end; i += 256) {
        int d2 = (int)(pairs[i] >> 32);
        atomicAdd(&cnt[d2 & 1023], 1);
    }
    __syncthreads();
    int b4 = t * 4;
    int c0 = cnt[b4], c1 = cnt[b4 + 1], c2 = cnt[b4 + 2], c3 = cnt[b4 + 3];
    int s = c0 + c1 + c2 + c3;
    sc[t] = s;
    __syncthreads();
    for (int off = 1; off < 256; off <<= 1) {
        int x = (t >= off) ? sc[t - off] : 0;
        __syncthreads();
        sc[t] += x;
        __syncthreads();
    }
    int run = sc[t] - s; // exclusive prefix of this thread's 4 bins
    int o0 = run, o1 = run + c0, o2 = o1 + c1, o3 = o2 + c2;
    cnt[b4] = o0; cnt[b4 + 1] = o1; cnt[b4 + 2] = o2; cnt[b4 + 3] = o3;
    int gidx = b * 1024 + b4;
    if (gidx     < NN2) row_ptr[gidx]     = beg + o0;
    if (gidx + 1 < NN2) row_ptr[gidx + 1] = beg + o1;
    if (gidx + 2 < NN2) row_ptr[gidx + 2] = beg + o2;
    if (gidx + 3 < NN2) row_ptr[gidx + 3] = beg + o3;
    __syncthreads();
    for (int i = beg + t; i < end; i += 256) {
        u64 p = pairs[i];
        int d2 = (int)(p >> 32);
        int r = atomicAdd(&cnt[d2 & 1023], 1);
        perm[beg + r] = (int)(p & 0xFFFFFFFFull);
    }
}

// ================= gather: 16 lanes/dst (4 dsts/wave), perm preload + pipelined loads ======
__global__ __launch_bounds__(256) void gather2(
    const int* __restrict__ row_ptr, const int* __restrict__ perm,
    const float* __restrict__ als_pp, const float* __restrict__ ald_pp,
    const float* __restrict__ als_cp, const float* __restrict__ ald_cp,
    const u16* __restrict__ h_p, const u16* __restrict__ h_c,
    u16* __restrict__ r_pp, u16* __restrict__ r_cp)
{
    int d2 = blockIdx.x * 16 + (threadIdx.x >> 4);
    int lane = threadIdx.x & 63;
    int l16 = lane & 15;
    int grp = lane & 48;
    int head = l16 >> 1;
    const float* als; const float* ald; const u16* hs; u16* out; int d;
    if (d2 < NP) { d = d2;      als = als_pp; ald = ald_pp; hs = h_p; out = r_pp; }
    else         { d = d2 - NP; als = als_cp; ald = ald_cp; hs = h_c; out = r_cp; }
    int beg = row_ptr[d2], end = row_ptr[d2 + 1];
    int n = end - beg;
    float ald_h = ald[(size_t)d * 8 + head];
    float dsum = 0.f;
    float acc[8] = {0.f, 0.f, 0.f, 0.f, 0.f, 0.f, 0.f, 0.f};
    for (int base = 0; base < n; base += 16) {
        int cnt = min(16, n - base);
        int my = (base + l16 < n) ? perm[beg + base + l16] : 0;
        int src = __shfl(my, grp, 64);
        float a_next = als[(size_t)src * 8 + head];
        uint4 hv_next = *(const uint4*)(hs + (size_t)src * 128 + l16 * 8);
        for (int j = 0; j < cnt; ++j) {
            float a_cur = a_next;
            uint4 hv = hv_next;
            if (j + 1 < cnt) {
                int s2 = __shfl(my, grp + j + 1, 64);
                a_next = als[(size_t)s2 * 8 + head];
                hv_next = *(const uint4*)(hs + (size_t)s2 * 128 + l16 * 8);
            }
            float a = a_cur + ald_h;
            a = a >= 0.f ? a : 0.2f * a;
            float w = __expf(a);
            dsum += w;
            u32 uu[4] = {hv.x, hv.y, hv.z, hv.w};
#pragma unroll
            for (int q = 0; q < 4; ++q) {
                acc[2 * q]     = fmaf(bf2f((u16)(uu[q] & 0xFFFFu)), w, acc[2 * q]);
                acc[2 * q + 1] = fmaf(bf2f((u16)(uu[q] >> 16)),     w, acc[2 * q + 1]);
            }
        }
    }
    float inv = 1.f / (dsum + 1e-16f);
    uint4 o;
    o.x = pack2(fmaxf(acc[0] * inv, 0.f), fmaxf(acc[1] * inv, 0.f));
    o.y = pack2(fmaxf(acc[2] * inv, 0.f), fmaxf(acc[3] * inv, 0.f));
    o.z = pack2(fmaxf(acc[4] * inv, 0.f), fmaxf(acc[5] * inv, 0.f));
    o.w = pack2(fmaxf(acc[6] * inv, 0.f), fmaxf(acc[7] * inv, 0.f));
    *(uint4*)(out + (size_t)d * 128 + l16 * 8) = o;
}

// ================= sem: per-block col-sums of tanh(r_m @ Wk + bk) =================
__global__ __launch_bounds__(256) void sem_mfma(
    const u16* __restrict__ r0, const u16* __restrict__ r1,
    const float* __restrict__ Wk, const float* __restrict__ bk,
    float* __restrict__ part)   // [2][3125][128]
{
    __shared__ alignas(16) u16 sBT[128 * 136];
    __shared__ alignas(16) u16 sA[64 * 136];
    __shared__ float red[4][128];
    int t = threadIdx.x;
    const u16* src = blockIdx.y ? r1 : r0;
    for (int i = t; i < 128 * 16; i += 256) {
        int n = i & 127, kb = i >> 7;
        u32 p[4];
#pragma unroll
        for (int j = 0; j < 4; ++j)
            p[j] = pack2(Wk[(kb * 8 + 2 * j) * 128 + n], Wk[(kb * 8 + 2 * j + 1) * 128 + n]);
        *(uint4*)(&sBT[n * 136 + kb * 8]) = make_uint4(p[0], p[1], p[2], p[3]);
    }
    size_t row0 = (size_t)blockIdx.x * 64;
    for (int i = t; i < 64 * 16; i += 256) {
        int r = i >> 4, c8 = (i & 15) * 8;
        *(uint4*)(&sA[r * 136 + c8]) = *(const uint4*)(src + (row0 + r) * 128 + c8);
    }
    __syncthreads();
    int wave = t >> 6, lane = t & 63;
    int fr = lane & 15, fq = lane >> 4;
    const u16* pA = sA + (wave * 16 + fr) * 136 + fq * 8;
    const u16* pB = sBT + fr * 136 + fq * 8;
    f32x4 acc[8];
#pragma unroll
    for (int nt = 0; nt < 8; ++nt) { float bb = bk[nt * 16 + fr]; acc[nt] = (f32x4){bb, bb, bb, bb}; }
#pragma unroll
    for (int ks = 0; ks < 4; ++ks) {
        short8v a = *(const short8v*)(pA + ks * 32);
#pragma unroll
        for (int nt = 0; nt < 8; ++nt) {
            short8v bv = *(const short8v*)(pB + nt * 16 * 136 + ks * 32);
            acc[nt] = __builtin_amdgcn_mfma_f32_16x16x32_bf16(a, bv, acc[nt], 0, 0, 0);
        }
    }
#pragma unroll
    for (int nt = 0; nt < 8; ++nt) {
        f32x4 v = acc[nt];
        float s = tanh_fast(v[0]) + tanh_fast(v[1]) + tanh_fast(v[2]) + tanh_fast(v[3]);
        s += __shfl_xor(s, 16, 64);
        s += __shfl_xor(s, 32, 64);
        if (lane < 16) red[wave][nt * 16 + lane] = s;
    }
    __syncthreads();
    if (t < 128) {
        float s = red[0][t] + red[1][t] + red[2][t] + red[3][t];
        part[((size_t)blockIdx.y * gridDim.x + blockIdx.x) * 128 + t] = s;
    }
}

// ================= sem partial-dot =================
__global__ __launch_bounds__(256) void sem_dot(const float* __restrict__ part,
                                               const float* __restrict__ q, float* __restrict__ vsum)
{
    __shared__ float sq_[128];
    __shared__ float red[256];
    int t = threadIdx.x;
    if (t < 128) sq_[t] = q[t];
    __syncthreads();
    int c = t & 127, m = t >> 7;
    int i0 = blockIdx.x * 98;
    int i1 = i0 + 98; if (i1 > 3125) i1 = 3125;
    float acc = 0.f;
    for (int i = i0; i < i1; ++i)
        acc += part[((size_t)m * 3125 + i) * 128 + c] * sq_[c];
    red[t] = acc;
    __syncthreads();
    for (int off = 64; off >= 1; off >>= 1) {
        if ((t & 127) < off) red[t] += red[t + off];
        __syncthreads();
    }
    if ((t & 127) == 0) atomicAdd(&vsum[m], red[t]);
}

__global__ void attn2_kernel(const float* __restrict__ vsum, float* __restrict__ attn)
{
    if (threadIdx.x == 0) {
        float v0 = vsum[0] / (float)NP, v1 = vsum[1] / (float)NP;
        float mx = fmaxf(v0, v1);
        float e0 = __expf(v0 - mx), e1 = __expf(v1 - mx);
        float is = 1.f / (e0 + e1);
        attn[0] = e0 * is;
        attn[1] = e1 * is;
    }
}

// ================= MLP1: z1 = (a0*r_cp + a1*r_pp) @ W1 + b1, bf16 out + BN partials =======
__global__ __launch_bounds__(256) void mlp1_mfma(
    const u16* __restrict__ rcp, const u16* __restrict__ rpp, const float* __restrict__ attn,
    const float* __restrict__ W1, const float* __restrict__ b1,
    u16* __restrict__ z1, float* __restrict__ pS, float* __restrict__ pQ)
{
    __shared__ alignas(16) u16 sBT[128 * 136];
    __shared__ alignas(16) u16 sA[64 * 136];
    __shared__ float redS[4][128];
    __shared__ float redQ[4][128];
    int t = threadIdx.x;
    float a0 = attn[0], a1 = attn[1];
    for (int i = t; i < 128 * 16; i += 256) {
        int n = i & 127, kb = i >> 7;
        u32 p[4];
#pragma unroll
        for (int j = 0; j < 4; ++j)
            p[j] = pack2(W1[(kb * 8 + 2 * j) * 128 + n], W1[(kb * 8 + 2 * j + 1) * 128 + n]);
        *(uint4*)(&sBT[n * 136 + kb * 8]) = make_uint4(p[0], p[1], p[2], p[3]);
    }
    size_t row0 = (size_t)blockIdx.x * 64;
    for (int i = t; i < 64 * 16; i += 256) {
        int r = i >> 4, c8 = (i & 15) * 8;
        size_t g = (row0 + r) * 128 + c8;
        uint4 uc = *(const uint4*)(rcp + g);
        uint4 up = *(const uint4*)(rpp + g);
        u32 uuc[4] = {uc.x, uc.y, uc.z, uc.w};
        u32 uup[4] = {up.x, up.y, up.z, up.w};
        u32 p[4];
#pragma unroll
        for (int j = 0; j < 4; ++j) {
            float lo = a0 * bf2f((u16)(uuc[j] & 0xFFFFu)) + a1 * bf2f((u16)(uup[j] & 0xFFFFu));
            float hi = a0 * bf2f((u16)(uuc[j] >> 16))     + a1 * bf2f((u16)(uup[j] >> 16));
            p[j] = pack2(lo, hi);
        }
        *(uint4*)(&sA[r * 136 + c8]) = make_uint4(p[0], p[1], p[2], p[3]);
    }
    __syncthreads();
    int wave = t >> 6, lane = t & 63;
    int fr = lane & 15, fq = lane >> 4;
    const u16* pA = sA + (wave * 16 + fr) * 136 + fq * 8;
    const u16* pB = sBT + fr * 136 + fq * 8;
    f32x4 acc[8];
#pragma unroll
    for (int nt = 0; nt < 8; ++nt) { float bb = b1[nt * 16 + fr]; acc[nt] = (f32x4){bb, bb, bb, bb}; }
#pragma unroll
    for (int ks = 0; ks < 4; ++ks) {
        short8v a = *(const short8v*)(pA + ks * 32);
#pragma unroll
        for (int nt = 0; nt < 8; ++nt) {
            short8v bv = *(const short8v*)(pB + nt * 16 * 136 + ks * 32);
            acc[nt] = __builtin_amdgcn_mfma_f32_16x16x32_bf16(a, bv, acc[nt], 0, 0, 0);
        }
    }
    size_t rbase = row0 + wave * 16 + fq * 4;
#pragma unroll
    for (int nt = 0; nt < 8; ++nt) {
        f32x4 v = acc[nt];
        int col = nt * 16 + fr;
#pragma unroll
        for (int rg = 0; rg < 4; ++rg)
            z1[(rbase + rg) * 128 + col] = f2bf(v[rg]);
        float s = v[0] + v[1] + v[2] + v[3];
        float qq = v[0] * v[0] + v[1] * v[1] + v[2] * v[2] + v[3] * v[3];
        s += __shfl_xor(s, 16, 64);  s += __shfl_xor(s, 32, 64);
        qq += __shfl_xor(qq, 16, 64); qq += __shfl_xor(qq, 32, 64);
        if (lane < 16) { redS[wave][col] = s; redQ[wave][col] = qq; }
    }
    __syncthreads();
    if (t < 128) {
        pS[(size_t)blockIdx.x * 128 + t] = redS[0][t] + redS[1][t] + redS[2][t] + redS[3][t];
        pQ[(size_t)blockIdx.x * 128 + t] = redQ[0][t] + redQ[1][t] + redQ[2][t] + redQ[3][t];
    }
}

// ================= reduce BN partials [3125][C] -> sum/sq =================
__global__ __launch_bounds__(256) void stat_reduce(
    const float* __restrict__ pS, const float* __restrict__ pQ,
    float* __restrict__ sum, float* __restrict__ sq, int C)
{
    __shared__ float redS[256], redQ[256];
    int t = threadIdx.x;
    int c = t & (C - 1);
    int sub = t / C;
    int stride = 256 / C;
    int i0 = blockIdx.x * 125, i1 = i0 + 125;
    float s = 0.f, q = 0.f;
    for (int i = i0 + sub; i < i1; i += stride) {
        s += pS[(size_t)i * C + c];
        q += pQ[(size_t)i * C + c];
    }
    redS[t] = s; redQ[t] = q;
    __syncthreads();
    if (t < C) {
        for (int k = 1; k < stride; ++k) { s += redS[t + k * C]; q += redQ[t + k * C]; }
        atomicAdd(&sum[c], s);
        atomicAdd(&sq[c], q);
    }
}

// ================= BN finalize =================
__global__ void bn_fin(const float* __restrict__ sum, const float* __restrict__ sq,
                       const float* __restrict__ g, const float* __restrict__ be,
                       float* __restrict__ scale, float* __restrict__ shift, int C, float invN)
{
    int c = threadIdx.x;
    if (c >= C) return;
    float mu = sum[c] * invN;
    float var = sq[c] * invN - mu * mu;
    float sc = g[c] * rsqrtf(var + 1e-5f);
    scale[c] = sc;
    shift[c] = be[c] - mu * sc;
}

// ================= MLP2: z2 = relu(bn(z1)) @ W2 + b2, f32 out + BN partials =================
__global__ __launch_bounds__(256) void mlp2_mfma(
    const u16* __restrict__ z1, const float* __restrict__ scale1, const float* __restrict__ shift1,
    const float* __restrict__ W2, const float* __restrict__ b2,
    float* __restrict__ z2, float* __restrict__ pS, float* __restrict__ pQ)
{
    __shared__ alignas(16) u16 sBT[64 * 136];
    __shared__ alignas(16) u16 sA[64 * 136];
    __shared__ float sSc[128], sSh[128];
    __shared__ float redS[4][64], redQ[4][64];
    int t = threadIdx.x;
    if (t < 128) { sSc[t] = scale1[t]; sSh[t] = shift1[t]; }
    for (int i = t; i < 64 * 16; i += 256) {
        int n = i & 63, kb = i >> 6;
        u32 p[4];
#pragma unroll
        for (int j = 0; j < 4; ++j)
            p[j] = pack2(W2[(kb * 8 + 2 * j) * 64 + n], W2[(kb * 8 + 2 * j + 1) * 64 + n]);
        *(uint4*)(&sBT[n * 136 + kb * 8]) = make_uint4(p[0], p[1], p[2], p[3]);
    }
    __syncthreads();
    size_t row0 = (size_t)blockIdx.x * 64;
    for (int i = t; i < 64 * 16; i += 256) {
        int r = i >> 4, c8 = (i & 15) * 8;
        uint4 up = *(const uint4*)(z1 + (row0 + r) * 128 + c8);
        u32 uu[4] = {up.x, up.y, up.z, up.w};
        u32 p[4];
#pragma unroll
        for (int j = 0; j < 4; ++j) {
            int c = c8 + 2 * j;
            float lo = fmaxf(bf2f((u16)(uu[j] & 0xFFFFu)) * sSc[c] + sSh[c], 0.f);
            float hi = fmaxf(bf2f((u16)(uu[j] >> 16)) * sSc[c + 1] + sSh[c + 1], 0.f);
            p[j] = pack2(lo, hi);
        }
        *(uint4*)(&sA[r * 136 + c8]) = make_uint4(p[0], p[1], p[2], p[3]);
    }
    __syncthreads();
    int wave = t >> 6, lane = t & 63;
    int fr = lane & 15, fq = lane >> 4;
    const u16* pA = sA + (wave * 16 + fr) * 136 + fq * 8;
    const u16* pB = sBT + fr * 136 + fq * 8;
    f32x4 acc[4];
#pragma unroll
    for (int nt = 0; nt < 4; ++nt) { float bb = b2[nt * 16 + fr]; acc[nt] = (f32x4){bb, bb, bb, bb}; }
#pragma unroll
    for (int ks = 0; ks < 4; ++ks) {
        short8v a = *(const short8v*)(pA + ks * 32);
#pragma unroll
        for (int nt = 0; nt < 4; ++nt) {
            short8v bv = *(const short8v*)(pB + nt * 16 * 136 + ks * 32);
            acc[nt] = __builtin_amdgcn_mfma_f32_16x16x32_bf16(a, bv, acc[nt], 0, 0, 0);
        }
    }
    size_t rbase = row0 + wave * 16 + fq * 4;
#pragma unroll
    for (int nt = 0; nt < 4; ++nt) {
        f32x4 v = acc[nt];
        int col = nt * 16 + fr;
#pragma unroll
        for (int rg = 0; rg < 4; ++rg)
            z2[(rbase + rg) * 64 + col] = v[rg];
        float s = v[0] + v[1] + v[2] + v[3];
        float qq = v[0] * v[0] + v[1] * v[1] + v[2] * v[2] + v[3] * v[3];
        s += __shfl_xor(s, 16, 64);  s += __shfl_xor(s, 32, 64);
        qq += __shfl_xor(qq, 16, 64); qq += __shfl_xor(qq, 32, 64);
        if (lane < 16) { redS[wave][col] = s; redQ[wave][col] = qq; }
    }
    __syncthreads();
    if (t < 64) {
        pS[(size_t)blockIdx.x * 64 + t] = redS[0][t] + redS[1][t] + redS[2][t] + redS[3][t];
        pQ[(size_t)blockIdx.x * 64 + t] = redQ[0][t] + redQ[1][t] + redQ[2][t] + redQ[3][t];
    }
}

// ================= final: sigmoid(relu(bn(z2)) @ W3 + b3) =================
__global__ __launch_bounds__(64) void final_kernel(
    const float* __restrict__ z2, const float* __restrict__ scale2, const float* __restrict__ shift2,
    const float* __restrict__ W3, const float* __restrict__ b3, float* __restrict__ out)
{
    __shared__ float sh[64][65];
    __shared__ float sw[64];
    int t = threadIdx.x; // 64
    size_t row0 = (size_t)blockIdx.x * 64;
    sw[t] = W3[t];
    for (int j = 0; j < 64; ++j) {
        float v = z2[(row0 + j) * 64 + t] * scale2[t] + shift2[t];
        sh[j][t] = v > 0.f ? v : 0.f;
    }
    __syncthreads();
    float acc = b3[0];
#pragma unroll 16
    for (int k = 0; k < 64; ++k) acc = fmaf(sh[t][k], sw[k], acc);
    out[row0 + t] = 1.f / (1.f + __expf(-acc));
}

extern "C" void kernel_launch(void* const* d_in, const int* in_sizes, int n_in,
                              void* d_out, int out_size, void* d_ws, size_t ws_size,
                              hipStream_t stream) {
    const float* x_c      = (const float*)d_in[0];
    const float* x_p      = (const float*)d_in[1];
    const int*   e_src_cp = (const int*)d_in[2];
    const int*   e_dst_cp = (const int*)d_in[3];
    const int*   e_src_pp = (const int*)d_in[4];
    const int*   e_dst_pp = (const int*)d_in[5];
    const float* W_c      = (const float*)d_in[6];
    const float* b_c      = (const float*)d_in[7];
    const float* W_p      = (const float*)d_in[8];
    const float* b_p      = (const float*)d_in[9];
    const float* a_src_cp = (const float*)d_in[10];
    const float* a_dst_cp = (const float*)d_in[11];
    const float* a_src_pp = (const float*)d_in[12];
    const float* a_dst_pp = (const float*)d_in[13];
    const float* Wk       = (const float*)d_in[14];
    const float* bk       = (const float*)d_in[15];
    const float* q_sem    = (const float*)d_in[16];
    const float* W1       = (const float*)d_in[17];
    const float* b1       = (const float*)d_in[18];
    const float* g1       = (const float*)d_in[19];
    const float* be1      = (const float*)d_in[20];
    const float* W2       = (const float*)d_in[21];
    const float* b2       = (const float*)d_in[22];
    const float* g2       = (const float*)d_in[23];
    const float* be2      = (const float*)d_in[24];
    const float* W3       = (const float*)d_in[25];
    const float* b3       = (const float*)d_in[26];

    // ---- byte-offset workspace layout (extent 211,208,448 B; 212,809,472 proven OK) ----
    char* ws = (char*)d_ws;
    u16*   h_p    = (u16*)  (ws +          0);  // 51,200,000
    u16*   h_c    = (u16*)  (ws +  51200000);   // 25,600,000
    float* al_c   = (float*)(ws +  76800000);   //  3,200,000
    float* al_dcp = (float*)(ws +  80000000);   //  6,400,000
    float* al_spp = (float*)(ws +  86400000);
    float* al_dpp = (float*)(ws +  92800000);
    int*   row_ptr= (int*)  (ws +  99200000);   // (NN2+1)*4 padded -> 100,800,256
    int*   perm   = (int*)  (ws + 100800256);   // 2NE*4 = 8,000,000 -> 108,800,256
    u64*   pairs  = (u64*)  (ws + 108800256);   // 2NE*8 = 16,000,000 -> 124,800,256 [dead after bsort]
    int*   bcnt   = (int*)  (ws + 124800256);   // 392*4
    int*   bbase  = (int*)  (ws + 124801856);   // 392*4
    int*   bcur   = (int*)  (ws + 124803456);   // 392*4 -> 124,805,056
    u16*   r_pp   = (u16*)  (ws + 108800256);   // NP*128 bf16 (overlays pairs+bmeta, both dead)
    u16*   r_cp   = (u16*)  (ws + 160000256);   // NP*128 bf16 -> 211,200,256
    float* small  = (float*)(ws + 211200256);   // 8192 -> 211,208,448

    // overlays on CSR region (dead after gather2):
    float* semPart= (float*)(ws +  99200000);   // 2*3125*128*4 = 3,200,000 (dead before mlp2)
    float* statS  = (float*)(ws + 102400000);   // 1,600,000
    float* statQ  = (float*)(ws + 104000000);   // 1,600,000

    float* vsum   = small;        // 2
    float* attn   = small + 64;   // 2
    float* sum1   = small + 128;  // 128
    float* sq1    = small + 256;  // 128
    float* sum2   = small + 384;  // 64
    float* sq2    = small + 448;  // 64
    float* scale1 = small + 512;  // 128
    float* shift1 = small + 640;  // 128
    float* scale2 = small + 768;  // 64
    float* shift2 = small + 832;  // 64

    // aliases over dead regions
    u16*   z1 = h_p;                     // bf16 NP*128 at [0,51.2M): h_p dead after gather
    float* z2 = (float*)(ws + 51200000); // f32 NP*64 at [51.2M,102.4M): h_c/al/semPart dead by MLP2

    hipMemsetAsync(small, 0, 8192, stream);
    hipMemsetAsync(bcnt, 0, 1600, stream);

    // projections (MFMA) + per-head logits, both node types in one dispatch each
    {
        dim3 g(NP / 64, 2);
        proj_both<<<g, 256, 0, stream>>>(x_c, W_c, b_c, x_p, W_p, b_p, h_c, h_p);
    }
    {
        dim3 g(NP / 32, 2);
        logit_both<<<g, 256, 0, stream>>>(h_c, a_src_cp, al_c,
                                          h_p, a_dst_cp, a_src_pp, a_dst_pp,
                                          al_dcp, al_spp, al_dpp);
    }

    // ---- bucketed CSR over both metapaths (2*NP dst nodes, 2*NE edges) ----
    bhist<<<NBLK_E, 256, 0, stream>>>(e_dst_pp, e_dst_cp, bcnt);
    bscan<<<1, 512, 0, stream>>>(bcnt, bbase, bcur, row_ptr);
    bplace<<<NBLK_E, 256, 0, stream>>>(e_src_pp, e_dst_pp, e_src_cp, e_dst_cp, bcur, pairs);
    bsort<<<NBUK, 256, 0, stream>>>(pairs, bbase, row_ptr, perm);

    gather2<<<NN2 / 16, 256, 0, stream>>>(row_ptr, perm,
                                          al_spp, al_dpp, al_c, al_dcp,
                                          h_p, h_c, r_pp, r_cp);

    // semantic attention
    {
        dim3 gs(NP / 64, 2);
        sem_mfma<<<gs, 256, 0, stream>>>(r_cp, r_pp, Wk, bk, semPart);
    }
    sem_dot<<<32, 256, 0, stream>>>(semPart, q_sem, vsum);
    attn2_kernel<<<1, 64, 0, stream>>>(vsum, attn);

    // MLP + BN
    mlp1_mfma<<<NP / 64, 256, 0, stream>>>(r_cp, r_pp, attn, W1, b1, z1, statS, statQ);
    stat_reduce<<<25, 256, 0, stream>>>(statS, statQ, sum1, sq1, 128);
    bn_fin<<<1, 128, 0, stream>>>(sum1, sq1, g1, be1, scale1, shift1, 128, 1.f / (float)NP);
    mlp2_mfma<<<NP / 64, 256, 0, stream>>>(z1, scale1, shift1, W2, b2, z2, statS, statQ);
    stat_reduce<<<25, 256, 0, stream>>>(statS, statQ, sum2, sq2, 64);
    bn_fin<<<1, 128, 0, stream>>>(sum2, sq2, g2, be2, scale2, shift2, 64, 1.f / (float)NP);
    final_kernel<<<NP / 64, 64, 0, stream>>>(z2, scale2, shift2, W3, b3, (float*)d_out);
}

// Round 8
// 480.029 us; speedup vs baseline: 12.2587x; 1.0218x over previous
//
#include <hip/hip_runtime.h>
#include <hip/hip_bf16.h>

#define NC 100000
#define NP 200000
#define NE 1000000
#define NN2 (2 * NP)      // combined dst-node space (pp then cp)
#define NBUK 391          // ceil(NN2/1024)
#define ECHUNK 8192
#define NBLK_E 245        // ceil(2*NE/8192)

typedef unsigned short u16;
typedef unsigned int u32;
typedef unsigned long long u64;
typedef __attribute__((ext_vector_type(8))) short short8v;  // 8 bf16 (4 VGPRs)
typedef __attribute__((ext_vector_type(4))) float f32x4;

__device__ __forceinline__ float bf2f(u16 v) {
    union { u32 u; float f; } c; c.u = ((u32)v) << 16; return c.f;
}
__device__ __forceinline__ u16 f2bf(float f) {
    union { float f; u32 u; } c; c.f = f;
    u32 u = c.u;
    return (u16)((u + 0x7FFFu + ((u >> 16) & 1u)) >> 16); // RNE
}
__device__ __forceinline__ u32 pack2(float lo, float hi) {
    return (u32)f2bf(lo) | ((u32)f2bf(hi) << 16);
}
__device__ __forceinline__ float tanh_fast(float x) {
    return 1.f - 2.f / (__expf(2.f * x) + 1.f);
}

// ========== proj (both node types): h = bf16(x @ W + b) via MFMA, + fused logits ==========
__global__ __launch_bounds__(256) void proj_both(
    const float* __restrict__ x_c, const float* __restrict__ W_c, const float* __restrict__ b_c,
    const float* __restrict__ x_p, const float* __restrict__ W_p, const float* __restrict__ b_p,
    u16* __restrict__ out_c, u16* __restrict__ out_p,
    const float* __restrict__ a_cp_s,                                  // for customer h
    const float* __restrict__ a_cp_d, const float* __restrict__ a_pp_s,
    const float* __restrict__ a_pp_d,                                  // for product h
    float* __restrict__ al_c, float* __restrict__ al_dcp,
    float* __restrict__ al_spp, float* __restrict__ al_dpp)
{
    const float* x; const float* W; const float* b; u16* h; int N;
    int py = blockIdx.y;
    if (py == 0) { x = x_c; W = W_c; b = b_c; h = out_c; N = NC; }
    else         { x = x_p; W = W_p; b = b_p; h = out_p; N = NP; }
    size_t row0 = (size_t)blockIdx.x * 64;
    if (row0 >= (size_t)N) return;
    __shared__ alignas(16) u16 sBT[128 * 72];
    __shared__ alignas(16) u16 sA[64 * 72];
    __shared__ alignas(16) u16 hTile[64 * 136];
    __shared__ float aV[3][128];
    int t = threadIdx.x;
    if (t < 128) {
        aV[0][t] = py ? a_cp_d[t] : a_cp_s[t];
        aV[1][t] = py ? a_pp_s[t] : 0.f;
        aV[2][t] = py ? a_pp_d[t] : 0.f;
    }
    for (int i = t; i < 128 * 8; i += 256) {
        int n = i & 127, kb = i >> 7;
        u32 p[4];
#pragma unroll
        for (int j = 0; j < 4; ++j)
            p[j] = pack2(W[(kb * 8 + 2 * j) * 128 + n], W[(kb * 8 + 2 * j + 1) * 128 + n]);
        *(uint4*)(&sBT[n * 72 + kb * 8]) = make_uint4(p[0], p[1], p[2], p[3]);
    }
    for (int i = t; i < 64 * 8; i += 256) {
        int r = i >> 3, c8 = (i & 7) * 8;
        u32 p[4];
        if (row0 + r < (size_t)N) {
            const float* src = x + (row0 + r) * 64 + c8;
            float4 v0 = *(const float4*)src;
            float4 v1 = *(const float4*)(src + 4);
            p[0] = pack2(v0.x, v0.y); p[1] = pack2(v0.z, v0.w);
            p[2] = pack2(v1.x, v1.y); p[3] = pack2(v1.z, v1.w);
        } else { p[0] = p[1] = p[2] = p[3] = 0; }
        *(uint4*)(&sA[r * 72 + c8]) = make_uint4(p[0], p[1], p[2], p[3]);
    }
    __syncthreads();
    int wave = t >> 6, lane = t & 63;
    int fr = lane & 15, fq = lane >> 4;
    const u16* pA = sA + (wave * 16 + fr) * 72 + fq * 8;
    const u16* pB = sBT + fr * 72 + fq * 8;
    f32x4 acc[8];
#pragma unroll
    for (int nt = 0; nt < 8; ++nt) { float bb = b[nt * 16 + fr]; acc[nt] = (f32x4){bb, bb, bb, bb}; }
#pragma unroll
    for (int ks = 0; ks < 2; ++ks) {
        short8v a = *(const short8v*)(pA + ks * 32);
#pragma unroll
        for (int nt = 0; nt < 8; ++nt) {
            short8v bv = *(const short8v*)(pB + nt * 16 * 72 + ks * 32);
            acc[nt] = __builtin_amdgcn_mfma_f32_16x16x32_bf16(a, bv, acc[nt], 0, 0, 0);
        }
    }
    size_t rbase = row0 + wave * 16 + fq * 4;
    int lrow0 = wave * 16 + fq * 4;
#pragma unroll
    for (int nt = 0; nt < 8; ++nt) {
        int col = nt * 16 + fr;
#pragma unroll
        for (int rg = 0; rg < 4; ++rg) {
            size_t rr = rbase + rg;
            u16 hv = f2bf(acc[nt][rg]);
            if (rr < (size_t)N) h[rr * 128 + col] = hv;
            hTile[(lrow0 + rg) * 136 + col] = hv;
        }
    }
    __syncthreads();
    // fused per-head logits from the LDS h tile
    int row = t >> 2;
    size_t grow = row0 + row;
    if (grow < (size_t)N) {
#pragma unroll
        for (int hh = t & 3; hh < 8; hh += 4) {
            const u16* hp = &hTile[row * 136 + hh * 16];
            uint4 u0_ = *(const uint4*)hp;
            uint4 u1_ = *(const uint4*)(hp + 8);
            u32 uu[8] = {u0_.x, u0_.y, u0_.z, u0_.w, u1_.x, u1_.y, u1_.z, u1_.w};
            float p0 = 0.f, p1 = 0.f, p2 = 0.f;
#pragma unroll
            for (int j = 0; j < 8; ++j) {
                float lo = bf2f((u16)(uu[j] & 0xFFFFu));
                float hi = bf2f((u16)(uu[j] >> 16));
                int c = hh * 16 + 2 * j;
                p0 += lo * aV[0][c] + hi * aV[0][c + 1];
                p1 += lo * aV[1][c] + hi * aV[1][c + 1];
                p2 += lo * aV[2][c] + hi * aV[2][c + 1];
            }
            if (py == 0) {
                al_c[grow * 8 + hh] = p0;
            } else {
                al_dcp[grow * 8 + hh] = p0;
                al_spp[grow * 8 + hh] = p1;
                al_dpp[grow * 8 + hh] = p2;
            }
        }
    }
}

// ================= bucketed CSR build =================
__global__ __launch_bounds__(256) void bhist(const int* __restrict__ dpp, const int* __restrict__ dcp,
                                             int* __restrict__ bcnt)
{
    __shared__ int h[NBUK];
    int t = threadIdx.x;
    for (int i = t; i < NBUK; i += 256) h[i] = 0;
    __syncthreads();
    int base = blockIdx.x * ECHUNK;
    int lim = min(ECHUNK, 2 * NE - base);
    for (int i = t; i < lim; i += 256) {
        int e = base + i;
        int d2 = (e < NE) ? dpp[e] : NP + dcp[e - NE];
        atomicAdd(&h[d2 >> 10], 1);
    }
    __syncthreads();
    for (int i = t; i < NBUK; i += 256) if (h[i]) atomicAdd(&bcnt[i], h[i]);
}

__global__ __launch_bounds__(512) void bscan(const int* __restrict__ bcnt, int* __restrict__ bbase,
                                             int* __restrict__ bcur, int* __restrict__ row_ptr)
{
    __shared__ int s[512];
    int t = threadIdx.x;
    int v = (t < NBUK) ? bcnt[t] : 0;
    s[t] = v;
    __syncthreads();
    for (int off = 1; off < 512; off <<= 1) {
        int x = (t >= off) ? s[t - off] : 0;
        __syncthreads();
        s[t] += x;
        __syncthreads();
    }
    if (t < NBUK) { bbase[t] = s[t] - v; bcur[t] = s[t] - v; }
    if (t == 0) { bbase[NBUK] = 2 * NE; row_ptr[NN2] = 2 * NE; }
}

__global__ __launch_bounds__(256) void bplace(
    const int* __restrict__ spp, const int* __restrict__ dpp,
    const int* __restrict__ scp, const int* __restrict__ dcp,
    int* __restrict__ bcur, u64* __restrict__ pairs)
{
    __shared__ int h[NBUK];
    __shared__ int rk[NBUK];
    int t = threadIdx.x;
    for (int i = t; i < NBUK; i += 256) h[i] = 0;
    __syncthreads();
    int base = blockIdx.x * ECHUNK;
    int lim = min(ECHUNK, 2 * NE - base);
    for (int i = t; i < lim; i += 256) {
        int e = base + i;
        int d2 = (e < NE) ? dpp[e] : NP + dcp[e - NE];
        atomicAdd(&h[d2 >> 10], 1);
    }
    __syncthreads();
    for (int i = t; i < NBUK; i += 256) {
        int c = h[i];
        h[i] = c ? atomicAdd(&bcur[i], c) : 0;
        rk[i] = 0;
    }
    __syncthreads();
    for (int i = t; i < lim; i += 256) {
        int e = base + i;
        int d2, src;
        if (e < NE) { d2 = dpp[e];      src = spp[e]; }
        else        { d2 = NP + dcp[e - NE]; src = scp[e - NE]; }
        int b = d2 >> 10;
        int r = atomicAdd(&rk[b], 1);
        pairs[h[b] + r] = ((u64)(u32)d2 << 32) | (u32)src;
    }
}

__global__ __launch_bounds__(256) void bsort(
    const u64* __restrict__ pairs, const int* __restrict__ bbase,
    int* __restrict__ row_ptr, int* __restrict__ perm)
{
    __shared__ int cnt[1024];
    __shared__ int sc[256];
    int b = blockIdx.x, t = threadIdx.x;
    int beg = bbase[b], end = bbase[b + 1];
    for (int i = t; i < 1024; i += 256) cnt[i] = 0;
    __syncthreads();
    for (int i = beg + t; i < end; i += 256) {
        int d2 = (int)(pairs[i] >> 32);
        atomicAdd(&cnt[d2 & 1023], 1);
    }
    __syncthreads();
    int b4 = t * 4;
    int c0 = cnt[b4], c1 = cnt[b4 + 1], c2 = cnt[b4 + 2], c3 = cnt[b4 + 3];
    int s = c0 + c1 + c2 + c3;
    sc[t] = s;
    __syncthreads();
    for (int off = 1; off < 256; off <<= 1) {
        int x = (t >= off) ? sc[t - off] : 0;
        __syncthreads();
        sc[t] += x;
        __syncthreads();
    }
    int run = sc[t] - s;
    int o0 = run, o1 = run + c0, o2 = o1 + c1, o3 = o2 + c2;
    cnt[b4] = o0; cnt[b4 + 1] = o1; cnt[b4 + 2] = o2; cnt[b4 + 3] = o3;
    int gidx = b * 1024 + b4;
    if (gidx     < NN2) row_ptr[gidx]     = beg + o0;
    if (gidx + 1 < NN2) row_ptr[gidx + 1] = beg + o1;
    if (gidx + 2 < NN2) row_ptr[gidx + 2] = beg + o2;
    if (gidx + 3 < NN2) row_ptr[gidx + 3] = beg + o3;
    __syncthreads();
    for (int i = beg + t; i < end; i += 256) {
        u64 p = pairs[i];
        int d2 = (int)(p >> 32);
        int r = atomicAdd(&cnt[d2 & 1023], 1);
        perm[beg + r] = (int)(p & 0xFFFFFFFFull);
    }
}

// ===== gather: 16 lanes per dst, TWO interleaved dst-chains per lane group =====
__global__ __launch_bounds__(256) void gather2(
    const int* __restrict__ row_ptr, const int* __restrict__ perm,
    const float* __restrict__ als_pp, const float* __restrict__ ald_pp,
    const float* __restrict__ als_cp, const float* __restrict__ ald_cp,
    const u16* __restrict__ h_p, const u16* __restrict__ h_c,
    u16* __restrict__ r_pp, u16* __restrict__ r_cp)
{
    int g = blockIdx.x * 16 + (threadIdx.x >> 4);   // 16 groups/block, 2 dsts/group
    int lane = threadIdx.x & 63;
    int l16 = lane & 15;
    int grp = lane & 48;
    int head = l16 >> 1;
    int d2A = 2 * g;                                 // pairs never straddle NP (NP even)
    const float* als; const float* ald; const u16* hs; u16* out;
    int dA;
    if (d2A < NP) { dA = d2A;      als = als_pp; ald = ald_pp; hs = h_p; out = r_pp; }
    else          { dA = d2A - NP; als = als_cp; ald = ald_cp; hs = h_c; out = r_cp; }
    int dB = dA + 1;
    int begA = row_ptr[d2A];
    int begB = row_ptr[d2A + 1];
    int endB = row_ptr[d2A + 2];
    int nA = begB - begA, nB = endB - begB;
    float aldA = ald[(size_t)dA * 8 + head];
    float aldB = ald[(size_t)dB * 8 + head];
    float dsA = 0.f, dsB = 0.f;
    float accA[8] = {0.f, 0.f, 0.f, 0.f, 0.f, 0.f, 0.f, 0.f};
    float accB[8] = {0.f, 0.f, 0.f, 0.f, 0.f, 0.f, 0.f, 0.f};
    int nmax = max(nA, nB);
    for (int base = 0; base < nmax; base += 16) {
        int cA = min(nA - base, 16);
        int cB = min(nB - base, 16);
        int myA = (base + l16 < nA) ? perm[begA + base + l16] : 0;
        int myB = (base + l16 < nB) ? perm[begB + base + l16] : 0;
        float aA = 0.f, aB = 0.f;
        uint4 hA = make_uint4(0, 0, 0, 0), hB = make_uint4(0, 0, 0, 0);
        if (cA > 0) {
            int s = __shfl(myA, grp, 64);
            aA = als[(size_t)s * 8 + head];
            hA = *(const uint4*)(hs + (size_t)s * 128 + l16 * 8);
        }
        if (cB > 0) {
            int s = __shfl(myB, grp, 64);
            aB = als[(size_t)s * 8 + head];
            hB = *(const uint4*)(hs + (size_t)s * 128 + l16 * 8);
        }
        int cmax = max(cA, cB);
        for (int j = 0; j < cmax; ++j) {
            if (j < cA) {
                float ac = aA; uint4 hc = hA;
                if (j + 1 < cA) {
                    int s = __shfl(myA, grp + j + 1, 64);
                    aA = als[(size_t)s * 8 + head];
                    hA = *(const uint4*)(hs + (size_t)s * 128 + l16 * 8);
                }
                float a = ac + aldA;
                a = a >= 0.f ? a : 0.2f * a;
                float w = __expf(a);
                dsA += w;
                u32 uu[4] = {hc.x, hc.y, hc.z, hc.w};
#pragma unroll
                for (int q = 0; q < 4; ++q) {
                    accA[2 * q]     = fmaf(bf2f((u16)(uu[q] & 0xFFFFu)), w, accA[2 * q]);
                    accA[2 * q + 1] = fmaf(bf2f((u16)(uu[q] >> 16)),     w, accA[2 * q + 1]);
                }
            }
            if (j < cB) {
                float ac = aB; uint4 hc = hB;
                if (j + 1 < cB) {
                    int s = __shfl(myB, grp + j + 1, 64);
                    aB = als[(size_t)s * 8 + head];
                    hB = *(const uint4*)(hs + (size_t)s * 128 + l16 * 8);
                }
                float a = ac + aldB;
                a = a >= 0.f ? a : 0.2f * a;
                float w = __expf(a);
                dsB += w;
                u32 uu[4] = {hc.x, hc.y, hc.z, hc.w};
#pragma unroll
                for (int q = 0; q < 4; ++q) {
                    accB[2 * q]     = fmaf(bf2f((u16)(uu[q] & 0xFFFFu)), w, accB[2 * q]);
                    accB[2 * q + 1] = fmaf(bf2f((u16)(uu[q] >> 16)),     w, accB[2 * q + 1]);
                }
            }
        }
    }
    float invA = 1.f / (dsA + 1e-16f);
    float invB = 1.f / (dsB + 1e-16f);
    uint4 oA, oB;
    oA.x = pack2(fmaxf(accA[0] * invA, 0.f), fmaxf(accA[1] * invA, 0.f));
    oA.y = pack2(fmaxf(accA[2] * invA, 0.f), fmaxf(accA[3] * invA, 0.f));
    oA.z = pack2(fmaxf(accA[4] * invA, 0.f), fmaxf(accA[5] * invA, 0.f));
    oA.w = pack2(fmaxf(accA[6] * invA, 0.f), fmaxf(accA[7] * invA, 0.f));
    oB.x = pack2(fmaxf(accB[0] * invB, 0.f), fmaxf(accB[1] * invB, 0.f));
    oB.y = pack2(fmaxf(accB[2] * invB, 0.f), fmaxf(accB[3] * invB, 0.f));
    oB.z = pack2(fmaxf(accB[4] * invB, 0.f), fmaxf(accB[5] * invB, 0.f));
    oB.w = pack2(fmaxf(accB[6] * invB, 0.f), fmaxf(accB[7] * invB, 0.f));
    *(uint4*)(out + (size_t)dA * 128 + l16 * 8) = oA;
    *(uint4*)(out + (size_t)dB * 128 + l16 * 8) = oB;
}

// ================= sem: per-block col-sums of tanh(r_m @ Wk + bk) =================
__global__ __launch_bounds__(256) void sem_mfma(
    const u16* __restrict__ r0, const u16* __restrict__ r1,
    const float* __restrict__ Wk, const float* __restrict__ bk,
    float* __restrict__ part)   // [2][3125][128]
{
    __shared__ alignas(16) u16 sBT[128 * 136];
    __shared__ alignas(16) u16 sA[64 * 136];
    __shared__ float red[4][128];
    int t = threadIdx.x;
    const u16* src = blockIdx.y ? r1 : r0;
    for (int i = t; i < 128 * 16; i += 256) {
        int n = i & 127, kb = i >> 7;
        u32 p[4];
#pragma unroll
        for (int j = 0; j < 4; ++j)
            p[j] = pack2(Wk[(kb * 8 + 2 * j) * 128 + n], Wk[(kb * 8 + 2 * j + 1) * 128 + n]);
        *(uint4*)(&sBT[n * 136 + kb * 8]) = make_uint4(p[0], p[1], p[2], p[3]);
    }
    size_t row0 = (size_t)blockIdx.x * 64;
    for (int i = t; i < 64 * 16; i += 256) {
        int r = i >> 4, c8 = (i & 15) * 8;
        *(uint4*)(&sA[r * 136 + c8]) = *(const uint4*)(src + (row0 + r) * 128 + c8);
    }
    __syncthreads();
    int wave = t >> 6, lane = t & 63;
    int fr = lane & 15, fq = lane >> 4;
    const u16* pA = sA + (wave * 16 + fr) * 136 + fq * 8;
    const u16* pB = sBT + fr * 136 + fq * 8;
    f32x4 acc[8];
#pragma unroll
    for (int nt = 0; nt < 8; ++nt) { float bb = bk[nt * 16 + fr]; acc[nt] = (f32x4){bb, bb, bb, bb}; }
#pragma unroll
    for (int ks = 0; ks < 4; ++ks) {
        short8v a = *(const short8v*)(pA + ks * 32);
#pragma unroll
        for (int nt = 0; nt < 8; ++nt) {
            short8v bv = *(const short8v*)(pB + nt * 16 * 136 + ks * 32);
            acc[nt] = __builtin_amdgcn_mfma_f32_16x16x32_bf16(a, bv, acc[nt], 0, 0, 0);
        }
    }
#pragma unroll
    for (int nt = 0; nt < 8; ++nt) {
        f32x4 v = acc[nt];
        float s = tanh_fast(v[0]) + tanh_fast(v[1]) + tanh_fast(v[2]) + tanh_fast(v[3]);
        s += __shfl_xor(s, 16, 64);
        s += __shfl_xor(s, 32, 64);
        if (lane < 16) red[wave][nt * 16 + lane] = s;
    }
    __syncthreads();
    if (t < 128) {
        float s = red[0][t] + red[1][t] + red[2][t] + red[3][t];
        part[((size_t)blockIdx.y * gridDim.x + blockIdx.x) * 128 + t] = s;
    }
}

// ================= sem partial-dot =================
__global__ __launch_bounds__(256) void sem_dot(const float* __restrict__ part,
                                               const float* __restrict__ q, float* __restrict__ vsum)
{
    __shared__ float sq_[128];
    __shared__ float red[256];
    int t = threadIdx.x;
    if (t < 128) sq_[t] = q[t];
    __syncthreads();
    int c = t & 127, m = t >> 7;
    int i0 = blockIdx.x * 98;
    int i1 = i0 + 98; if (i1 > 3125) i1 = 3125;
    float acc = 0.f;
    for (int i = i0; i < i1; ++i)
        acc += part[((size_t)m * 3125 + i) * 128 + c] * sq_[c];
    red[t] = acc;
    __syncthreads();
    for (int off = 64; off >= 1; off >>= 1) {
        if ((t & 127) < off) red[t] += red[t + off];
        __syncthreads();
    }
    if ((t & 127) == 0) atomicAdd(&vsum[m], red[t]);
}

// ==== MLP1: z1 = (a0*r_cp + a1*r_pp) @ W1 + b1 (attn computed inline from vsum) ====
__global__ __launch_bounds__(256) void mlp1_mfma(
    const u16* __restrict__ rcp, const u16* __restrict__ rpp, const float* __restrict__ vsum,
    const float* __restrict__ W1, const float* __restrict__ b1,
    u16* __restrict__ z1, float* __restrict__ pS, float* __restrict__ pQ)
{
    __shared__ alignas(16) u16 sBT[128 * 136];
    __shared__ alignas(16) u16 sA[64 * 136];
    __shared__ float redS[4][128];
    __shared__ float redQ[4][128];
    int t = threadIdx.x;
    float v0 = vsum[0] * (1.f / (float)NP), v1 = vsum[1] * (1.f / (float)NP);
    float mx = fmaxf(v0, v1);
    float e0 = __expf(v0 - mx), e1 = __expf(v1 - mx);
    float is = 1.f / (e0 + e1);
    float a0 = e0 * is, a1 = e1 * is;
    for (int i = t; i < 128 * 16; i += 256) {
        int n = i & 127, kb = i >> 7;
        u32 p[4];
#pragma unroll
        for (int j = 0; j < 4; ++j)
            p[j] = pack2(W1[(kb * 8 + 2 * j) * 128 + n], W1[(kb * 8 + 2 * j + 1) * 128 + n]);
        *(uint4*)(&sBT[n * 136 + kb * 8]) = make_uint4(p[0], p[1], p[2], p[3]);
    }
    size_t row0 = (size_t)blockIdx.x * 64;
    for (int i = t; i < 64 * 16; i += 256) {
        int r = i >> 4, c8 = (i & 15) * 8;
        size_t gidx = (row0 + r) * 128 + c8;
        uint4 uc = *(const uint4*)(rcp + gidx);
        uint4 up = *(const uint4*)(rpp + gidx);
        u32 uuc[4] = {uc.x, uc.y, uc.z, uc.w};
        u32 uup[4] = {up.x, up.y, up.z, up.w};
        u32 p[4];
#pragma unroll
        for (int j = 0; j < 4; ++j) {
            float lo = a0 * bf2f((u16)(uuc[j] & 0xFFFFu)) + a1 * bf2f((u16)(uup[j] & 0xFFFFu));
            float hi = a0 * bf2f((u16)(uuc[j] >> 16))     + a1 * bf2f((u16)(uup[j] >> 16));
            p[j] = pack2(lo, hi);
        }
        *(uint4*)(&sA[r * 136 + c8]) = make_uint4(p[0], p[1], p[2], p[3]);
    }
    __syncthreads();
    int wave = t >> 6, lane = t & 63;
    int fr = lane & 15, fq = lane >> 4;
    const u16* pA = sA + (wave * 16 + fr) * 136 + fq * 8;
    const u16* pB = sBT + fr * 136 + fq * 8;
    f32x4 acc[8];
#pragma unroll
    for (int nt = 0; nt < 8; ++nt) { float bb = b1[nt * 16 + fr]; acc[nt] = (f32x4){bb, bb, bb, bb}; }
#pragma unroll
    for (int ks = 0; ks < 4; ++ks) {
        short8v a = *(const short8v*)(pA + ks * 32);
#pragma unroll
        for (int nt = 0; nt < 8; ++nt) {
            short8v bv = *(const short8v*)(pB + nt * 16 * 136 + ks * 32);
            acc[nt] = __builtin_amdgcn_mfma_f32_16x16x32_bf16(a, bv, acc[nt], 0, 0, 0);
        }
    }
    size_t rbase = row0 + wave * 16 + fq * 4;
#pragma unroll
    for (int nt = 0; nt < 8; ++nt) {
        f32x4 v = acc[nt];
        int col = nt * 16 + fr;
#pragma unroll
        for (int rg = 0; rg < 4; ++rg)
            z1[(rbase + rg) * 128 + col] = f2bf(v[rg]);
        float s = v[0] + v[1] + v[2] + v[3];
        float qq = v[0] * v[0] + v[1] * v[1] + v[2] * v[2] + v[3] * v[3];
        s += __shfl_xor(s, 16, 64);  s += __shfl_xor(s, 32, 64);
        qq += __shfl_xor(qq, 16, 64); qq += __shfl_xor(qq, 32, 64);
        if (lane < 16) { redS[wave][col] = s; redQ[wave][col] = qq; }
    }
    __syncthreads();
    if (t < 128) {
        pS[(size_t)blockIdx.x * 128 + t] = redS[0][t] + redS[1][t] + redS[2][t] + redS[3][t];
        pQ[(size_t)blockIdx.x * 128 + t] = redQ[0][t] + redQ[1][t] + redQ[2][t] + redQ[3][t];
    }
}

// ================= reduce BN partials [3125][C] -> sum/sq =================
__global__ __launch_bounds__(256) void stat_reduce(
    const float* __restrict__ pS, const float* __restrict__ pQ,
    float* __restrict__ sum, float* __restrict__ sq, int C)
{
    __shared__ float redS[256], redQ[256];
    int t = threadIdx.x;
    int c = t & (C - 1);
    int sub = t / C;
    int stride = 256 / C;
    int i0 = blockIdx.x * 125, i1 = i0 + 125;
    float s = 0.f, q = 0.f;
    for (int i = i0 + sub; i < i1; i += stride) {
        s += pS[(size_t)i * C + c];
        q += pQ[(size_t)i * C + c];
    }
    redS[t] = s; redQ[t] = q;
    __syncthreads();
    if (t < C) {
        for (int k = 1; k < stride; ++k) { s += redS[t + k * C]; q += redQ[t + k * C]; }
        atomicAdd(&sum[c], s);
        atomicAdd(&sq[c], q);
    }
}

// ===== MLP2: z2 = relu(bn(z1)) @ W2 + b2 (BN scale/shift computed inline) =====
__global__ __launch_bounds__(256) void mlp2_mfma(
    const u16* __restrict__ z1,
    const float* __restrict__ sum1, const float* __restrict__ sq1,
    const float* __restrict__ g1, const float* __restrict__ be1,
    const float* __restrict__ W2, const float* __restrict__ b2,
    float* __restrict__ z2, float* __restrict__ pS, float* __restrict__ pQ)
{
    __shared__ alignas(16) u16 sBT[64 * 136];
    __shared__ alignas(16) u16 sA[64 * 136];
    __shared__ float sSc[128], sSh[128];
    __shared__ float redS[4][64], redQ[4][64];
    int t = threadIdx.x;
    if (t < 128) {
        float mu = sum1[t] * (1.f / (float)NP);
        float var = sq1[t] * (1.f / (float)NP) - mu * mu;
        float sc = g1[t] * rsqrtf(var + 1e-5f);
        sSc[t] = sc;
        sSh[t] = be1[t] - mu * sc;
    }
    for (int i = t; i < 64 * 16; i += 256) {
        int n = i & 63, kb = i >> 6;
        u32 p[4];
#pragma unroll
        for (int j = 0; j < 4; ++j)
            p[j] = pack2(W2[(kb * 8 + 2 * j) * 64 + n], W2[(kb * 8 + 2 * j + 1) * 64 + n]);
        *(uint4*)(&sBT[n * 136 + kb * 8]) = make_uint4(p[0], p[1], p[2], p[3]);
    }
    __syncthreads();
    size_t row0 = (size_t)blockIdx.x * 64;
    for (int i = t; i < 64 * 16; i += 256) {
        int r = i >> 4, c8 = (i & 15) * 8;
        uint4 up = *(const uint4*)(z1 + (row0 + r) * 128 + c8);
        u32 uu[4] = {up.x, up.y, up.z, up.w};
        u32 p[4];
#pragma unroll
        for (int j = 0; j < 4; ++j) {
            int c = c8 + 2 * j;
            float lo = fmaxf(bf2f((u16)(uu[j] & 0xFFFFu)) * sSc[c] + sSh[c], 0.f);
            float hi = fmaxf(bf2f((u16)(uu[j] >> 16)) * sSc[c + 1] + sSh[c + 1], 0.f);
            p[j] = pack2(lo, hi);
        }
        *(uint4*)(&sA[r * 136 + c8]) = make_uint4(p[0], p[1], p[2], p[3]);
    }
    __syncthreads();
    int wave = t >> 6, lane = t & 63;
    int fr = lane & 15, fq = lane >> 4;
    const u16* pA = sA + (wave * 16 + fr) * 136 + fq * 8;
    const u16* pB = sBT + fr * 136 + fq * 8;
    f32x4 acc[4];
#pragma unroll
    for (int nt = 0; nt < 4; ++nt) { float bb = b2[nt * 16 + fr]; acc[nt] = (f32x4){bb, bb, bb, bb}; }
#pragma unroll
    for (int ks = 0; ks < 4; ++ks) {
        short8v a = *(const short8v*)(pA + ks * 32);
#pragma unroll
        for (int nt = 0; nt < 4; ++nt) {
            short8v bv = *(const short8v*)(pB + nt * 16 * 136 + ks * 32);
            acc[nt] = __builtin_amdgcn_mfma_f32_16x16x32_bf16(a, bv, acc[nt], 0, 0, 0);
        }
    }
    size_t rbase = row0 + wave * 16 + fq * 4;
#pragma unroll
    for (int nt = 0; nt < 4; ++nt) {
        f32x4 v = acc[nt];
        int col = nt * 16 + fr;
#pragma unroll
        for (int rg = 0; rg < 4; ++rg)
            z2[(rbase + rg) * 64 + col] = v[rg];
        float s = v[0] + v[1] + v[2] + v[3];
        float qq = v[0] * v[0] + v[1] * v[1] + v[2] * v[2] + v[3] * v[3];
        s += __shfl_xor(s, 16, 64);  s += __shfl_xor(s, 32, 64);
        qq += __shfl_xor(qq, 16, 64); qq += __shfl_xor(qq, 32, 64);
        if (lane < 16) { redS[wave][col] = s; redQ[wave][col] = qq; }
    }
    __syncthreads();
    if (t < 64) {
        pS[(size_t)blockIdx.x * 64 + t] = redS[0][t] + redS[1][t] + redS[2][t] + redS[3][t];
        pQ[(size_t)blockIdx.x * 64 + t] = redQ[0][t] + redQ[1][t] + redQ[2][t] + redQ[3][t];
    }
}

// ===== final: sigmoid(relu(bn(z2)) @ W3 + b3) (BN computed inline) =====
__global__ __launch_bounds__(64) void final_kernel(
    const float* __restrict__ z2,
    const float* __restrict__ sum2, const float* __restrict__ sq2,
    const float* __restrict__ g2, const float* __restrict__ be2,
    const float* __restrict__ W3, const float* __restrict__ b3, float* __restrict__ out)
{
    __shared__ float sh[64][65];
    __shared__ float sw[64];
    int t = threadIdx.x; // 64
    float mu = sum2[t] * (1.f / (float)NP);
    float var = sq2[t] * (1.f / (float)NP) - mu * mu;
    float sc = g2[t] * rsqrtf(var + 1e-5f);
    float sh2 = be2[t] - mu * sc;
    size_t row0 = (size_t)blockIdx.x * 64;
    sw[t] = W3[t];
    for (int j = 0; j < 64; ++j) {
        float v = z2[(row0 + j) * 64 + t] * sc + sh2;
        sh[j][t] = v > 0.f ? v : 0.f;
    }
    __syncthreads();
    float acc = b3[0];
#pragma unroll 16
    for (int k = 0; k < 64; ++k) acc = fmaf(sh[t][k], sw[k], acc);
    out[row0 + t] = 1.f / (1.f + __expf(-acc));
}

extern "C" void kernel_launch(void* const* d_in, const int* in_sizes, int n_in,
                              void* d_out, int out_size, void* d_ws, size_t ws_size,
                              hipStream_t stream) {
    const float* x_c      = (const float*)d_in[0];
    const float* x_p      = (const float*)d_in[1];
    const int*   e_src_cp = (const int*)d_in[2];
    const int*   e_dst_cp = (const int*)d_in[3];
    const int*   e_src_pp = (const int*)d_in[4];
    const int*   e_dst_pp = (const int*)d_in[5];
    const float* W_c      = (const float*)d_in[6];
    const float* b_c      = (const float*)d_in[7];
    const float* W_p      = (const float*)d_in[8];
    const float* b_p      = (const float*)d_in[9];
    const float* a_src_cp = (const float*)d_in[10];
    const float* a_dst_cp = (const float*)d_in[11];
    const float* a_src_pp = (const float*)d_in[12];
    const float* a_dst_pp = (const float*)d_in[13];
    const float* Wk       = (const float*)d_in[14];
    const float* bk       = (const float*)d_in[15];
    const float* q_sem    = (const float*)d_in[16];
    const float* W1       = (const float*)d_in[17];
    const float* b1       = (const float*)d_in[18];
    const float* g1       = (const float*)d_in[19];
    const float* be1      = (const float*)d_in[20];
    const float* W2       = (const float*)d_in[21];
    const float* b2       = (const float*)d_in[22];
    const float* g2       = (const float*)d_in[23];
    const float* be2      = (const float*)d_in[24];
    const float* W3       = (const float*)d_in[25];
    const float* b3       = (const float*)d_in[26];

    // ---- byte-offset workspace layout (extent 211,208,448 B; proven OK) ----
    char* ws = (char*)d_ws;
    u16*   h_p    = (u16*)  (ws +          0);  // 51,200,000
    u16*   h_c    = (u16*)  (ws +  51200000);   // 25,600,000
    float* al_c   = (float*)(ws +  76800000);   //  3,200,000
    float* al_dcp = (float*)(ws +  80000000);   //  6,400,000
    float* al_spp = (float*)(ws +  86400000);
    float* al_dpp = (float*)(ws +  92800000);
    int*   row_ptr= (int*)  (ws +  99200000);   // (NN2+1)*4 padded -> 100,800,256
    int*   perm   = (int*)  (ws + 100800256);   // 2NE*4 -> 108,800,256
    u64*   pairs  = (u64*)  (ws + 108800256);   // 2NE*8 -> 124,800,256 [dead after bsort]
    int*   bcnt   = (int*)  (ws + 124800256);   // 392*4
    int*   bbase  = (int*)  (ws + 124801856);   // 392*4
    int*   bcur   = (int*)  (ws + 124803456);   // 392*4
    u16*   r_pp   = (u16*)  (ws + 108800256);   // NP*128 bf16 (overlays pairs+bmeta, dead)
    u16*   r_cp   = (u16*)  (ws + 160000256);   // NP*128 bf16 -> 211,200,256
    float* small  = (float*)(ws + 211200256);   // 8192

    // overlays on CSR region (dead after gather2):
    float* semPart= (float*)(ws +  99200000);   // 3,200,000 (dead before mlp2)
    float* statS  = (float*)(ws + 102400000);   // 1,600,000
    float* statQ  = (float*)(ws + 104000000);   // 1,600,000

    float* vsum   = small;        // 2
    float* sum1   = small + 128;  // 128
    float* sq1    = small + 256;  // 128
    float* sum2   = small + 384;  // 64
    float* sq2    = small + 448;  // 64

    // aliases over dead regions
    u16*   z1 = h_p;                     // bf16 NP*128 at [0,51.2M): h_p dead after gather
    float* z2 = (float*)(ws + 51200000); // f32 NP*64 at [51.2M,102.4M)

    hipMemsetAsync(small, 0, 8192, stream);
    hipMemsetAsync(bcnt, 0, 1600, stream);

    // projections (MFMA) with fused per-head logits
    {
        dim3 g(NP / 64, 2);
        proj_both<<<g, 256, 0, stream>>>(x_c, W_c, b_c, x_p, W_p, b_p, h_c, h_p,
                                         a_src_cp, a_dst_cp, a_src_pp, a_dst_pp,
                                         al_c, al_dcp, al_spp, al_dpp);
    }

    // ---- bucketed CSR over both metapaths ----
    bhist<<<NBLK_E, 256, 0, stream>>>(e_dst_pp, e_dst_cp, bcnt);
    bscan<<<1, 512, 0, stream>>>(bcnt, bbase, bcur, row_ptr);
    bplace<<<NBLK_E, 256, 0, stream>>>(e_src_pp, e_dst_pp, e_src_cp, e_dst_cp, bcur, pairs);
    bsort<<<NBUK, 256, 0, stream>>>(pairs, bbase, row_ptr, perm);

    gather2<<<NN2 / 32, 256, 0, stream>>>(row_ptr, perm,
                                          al_spp, al_dpp, al_c, al_dcp,
                                          h_p, h_c, r_pp, r_cp);

    // semantic attention
    {
        dim3 gs(NP / 64, 2);
        sem_mfma<<<gs, 256, 0, stream>>>(r_cp, r_pp, Wk, bk, semPart);
    }
    sem_dot<<<32, 256, 0, stream>>>(semPart, q_sem, vsum);

    // MLP + BN
    mlp1_mfma<<<NP / 64, 256, 0, stream>>>(r_cp, r_pp, vsum, W1, b1, z1, statS, statQ);
    stat_reduce<<<25, 256, 0, stream>>>(statS, statQ, sum1, sq1, 128);
    mlp2_mfma<<<NP / 64, 256, 0, stream>>>(z1, sum1, sq1, g1, be1, W2, b2, z2, statS, statQ);
    stat_reduce<<<25, 256, 0, stream>>>(statS, statQ, sum2, sq2, 64);
    final_kernel<<<NP / 64, 64, 0, stream>>>(z2, sum2, sq2, g2, be2, W3, b3, (float*)d_out);
}